// Round 8
// baseline (877.579 us; speedup 1.0000x reference)
//
#include <hip/hip_runtime.h>
#include <math.h>

#define G 200
#define N0 512
#define NE 614400          // G*N0*6
#define EPG 3072           // edges per graph (slot-stable across layers)
#define K1 410
#define K2 328
#define K3 263
#define H 128
#define NT0 102400         // G*N0
#define NT1 82000          // G*K1
#define NT2 65600          // G*K2
#define NT3 52600          // G*K3

// fixed-point scales for deterministic integer aggregation
#define SCALE1 1048576.0f        // 2^20, layer-1 features (|x| <= ~6)
#define INV1   (1.0f / 1048576.0f)
#define SCALE2 262144.0f         // 2^18, layers 2/3 (messages <= ~300, agg <= ~8000)
#define INV2   (1.0f / 262144.0f)

#define DEAD 0xFFFFu
#define RPS (N0 + 1)             // rowptr stride per graph

static inline int cdiv(int a, int b) { return (a + b - 1) / b; }

// ---------------- layer 1 ----------------
__global__ void init_edges_kernel(const int* __restrict__ ei, int* __restrict__ cs, int* __restrict__ cd) {
    int e = blockIdx.x * blockDim.x + threadIdx.x;
    if (e >= NE) return;
    cs[e] = ei[e];
    cd[e] = ei[NE + e];
}

// per-graph LDS aggregation of the 6 input features (stride-8 padded rows).
// edges staged once into LDS (ushort2 local ids) -> inner loop is pure LDS.
// int fixed-point LDS atomics -> deterministic. Writes every output element.
__global__ __launch_bounds__(256) void agg6_lds_kernel(
    const float* __restrict__ x, const int* __restrict__ ei, int* __restrict__ agg) {
    __shared__ float xs[N0 * 8];
    __shared__ int   ag[N0 * 8];
    __shared__ ushort2 eloc[EPG];
    const int g = blockIdx.x;
    const int t = threadIdx.x;
    const int base = g * N0;
    const int e0 = g * EPG;
    for (int i = t; i < N0 * 8; i += 256) {
        int m = i >> 3, j = i & 7;
        xs[i] = (j < 6) ? x[(size_t)(base + m) * 6 + j] : 0.f;
        ag[i] = 0;
    }
    for (int i = t; i < EPG; i += 256) {
        eloc[i] = make_ushort2((unsigned short)(ei[e0 + i] - base),
                               (unsigned short)(ei[NE + e0 + i] - base));
    }
    __syncthreads();
    const int sub = t >> 3;   // 32 subgroups of 8 lanes; 32 edges per iteration
    const int f = t & 7;
#pragma unroll 4
    for (int e = sub; e < EPG; e += 32) {
        ushort2 p = eloc[e];
        if (f < 6) {
            float v = xs[p.x * 8 + f];
            atomicAdd(&ag[p.y * 8 + f], __float2int_rn(v * SCALE1));
        }
    }
    __syncthreads();
    for (int i = t; i < N0 * 6; i += 256) {
        int m = i / 6, j = i - m * 6;
        agg[(size_t)(base + m) * 6 + j] = ag[m * 8 + j];
    }
}

// 4 outputs per thread; per-output expression order identical to the original
// scalar version -> bit-exact h.
__global__ void conv1_kernel(const float* __restrict__ x, const int* __restrict__ agg6,
                             const float* __restrict__ Wrel, const float* __restrict__ Wroot,
                             const float* __restrict__ b, float* __restrict__ h) {
    int idx = blockIdx.x * blockDim.x + threadIdx.x;
    if (idx >= NT0 * 32) return;
    int node = idx >> 5, o4 = (idx & 31) * 4;
    float a[6], xv[6];
#pragma unroll
    for (int f = 0; f < 6; f++) {
        a[f] = (float)agg6[node * 6 + f] * INV1;
        xv[f] = x[node * 6 + f];
    }
    float4 r;
    float* rp = (float*)&r;
#pragma unroll
    for (int j = 0; j < 4; j++) {
        int o = o4 + j;
        float acc = b[o];
#pragma unroll
        for (int f = 0; f < 6; f++)
            acc += a[f] * Wrel[o * 6 + f] + xv[f] * Wroot[o * 6 + f];
        rp[j] = fmaxf(acc, 0.f);
    }
    *(float4*)(h + (size_t)node * H + o4) = r;
}

// ---------------- scoring / top-k / pooling ----------------
__global__ void score_kernel(const float* __restrict__ h, const float* __restrict__ w,
                             float* __restrict__ score, int n) {
    int gid = blockIdx.x * blockDim.x + threadIdx.x;
    int node = gid >> 6;
    int lane = gid & 63;
    if (node >= n) return;
    float2 hv = *(const float2*)(h + (size_t)node * H + lane * 2);
    float2 wv = *(const float2*)(w + lane * 2);
    float d = hv.x * wv.x + hv.y * wv.y;
    float n2 = wv.x * wv.x + wv.y * wv.y;
#pragma unroll
    for (int s = 32; s > 0; s >>= 1) {
        d += __shfl_xor(d, s);
        n2 += __shfl_xor(n2, s);
    }
    if (lane == 0) score[node] = tanhf(d / sqrtf(n2));
}

// one block (512 threads) per graph; register bitonic sort (descending,
// index-tiebreak = stable like jax.lax.top_k). Strides <64 via __shfl_xor
// (intra-wave), strides >=64 via LDS (6 of 45 stages). Writes perm + inv.
__global__ __launch_bounds__(512) void topk_kernel(const float* __restrict__ score, int n, int k,
                                                   int* __restrict__ perm, int* __restrict__ inv) {
    __shared__ float sv[512];
    __shared__ int si[512];
    const int g = blockIdx.x;
    const int t = threadIdx.x;
    float v = (t < n) ? score[g * n + t] : -INFINITY;
    int idx = t;
    for (int size = 2; size <= 512; size <<= 1) {
        const bool desc = ((t & size) == 0);
        for (int stride = size >> 1; stride > 0; stride >>= 1) {
            float pv; int pi;
            if (stride >= 64) {
                sv[t] = v; si[t] = idx;
                __syncthreads();
                pv = sv[t ^ stride]; pi = si[t ^ stride];
                __syncthreads();
            } else {
                pv = __shfl_xor(v, stride);
                pi = __shfl_xor(idx, stride);
            }
            const bool left = ((t & stride) == 0);
            const bool want_max = (desc == left);
            // total order: higher value first; equal values -> smaller index first
            const bool A = (v > pv) || (v == pv && idx < pi);
            if (want_max != A) { v = pv; idx = pi; }
        }
    }
    if (t < n) inv[g * n + t] = -1;
    __syncthreads();
    if (t < k) {
        perm[g * k + t] = g * n + idx;
        inv[g * n + idx] = g * k + t;
    }
}

__global__ void gather_pool_kernel(const float* __restrict__ h, const float* __restrict__ score,
                                   const int* __restrict__ perm, float* __restrict__ out, int nNew) {
    int idx = blockIdx.x * blockDim.x + threadIdx.x;
    int nn = idx >> 5;
    if (nn >= nNew) return;
    int fq = (idx & 31) * 4;
    int old = perm[nn];
    float s = score[old];
    float4 v = *(const float4*)(h + (size_t)old * H + fq);
    v.x *= s; v.y *= s; v.z *= s; v.w *= s;
    *(float4*)(out + (size_t)nn * H + fq) = v;
}

__global__ void remap_kernel(int* __restrict__ cs, int* __restrict__ cd, const int* __restrict__ inv) {
    int e = blockIdx.x * blockDim.x + threadIdx.x;
    if (e >= NE) return;
    int s = cs[e];
    if (s < 0) return;
    int d = cd[e];
    int ns = inv[s], nd = inv[d];
    if (ns < 0 || nd < 0) { cs[e] = -1; }
    else { cs[e] = ns; cd[e] = nd; }
}

// one block (512 threads) per graph; 4-way partitioned j-loop, LDS combine.
// deterministic: fixed partition of the k-sum.
__global__ __launch_bounds__(512) void readout_kernel(const float* __restrict__ h,
                                                      float* __restrict__ z, int k) {
    __shared__ float smax[4][128];
    __shared__ float ssum[4][128];
    const int g = blockIdx.x;
    const int t = threadIdx.x;
    const int f = t & 127;
    const int part = t >> 7;
    const float* p = h + (size_t)g * k * H + f;
    float mx = -INFINITY, sm = 0.f;
    for (int j = part; j < k; j += 4) {
        float v = p[(size_t)j * H];
        mx = fmaxf(mx, v);
        sm += v;
    }
    smax[part][f] = mx;
    ssum[part][f] = sm;
    __syncthreads();
    if (t < 128) {
        float m0 = fmaxf(fmaxf(smax[0][t], smax[1][t]), fmaxf(smax[2][t], smax[3][t]));
        float s0 = (ssum[0][t] + ssum[1][t]) + (ssum[2][t] + ssum[3][t]);
        z[g * 256 + t] += m0;
        z[g * 256 + 128 + t] += s0 / (float)k;
    }
}

// ---------------- CSR build (layers 2/3) ----------------
// one block per graph. Deterministic rowptr (atomic counts + scan); col
// placement order is scheduling-dependent but consumers sum INTs -> invariant.
__global__ __launch_bounds__(256) void build_csr_kernel(
    const int* __restrict__ cs, const int* __restrict__ cd, int n,
    int* __restrict__ rowptr, unsigned short* __restrict__ col) {
    __shared__ ushort2 eloc[EPG];
    __shared__ int cnt[N0];
    __shared__ int basep[N0];
    __shared__ int wsum[4];
    const int g = blockIdx.x;
    const int t = threadIdx.x;
    const int base = g * n;
    const int e0 = g * EPG;
    for (int i = t; i < n; i += 256) cnt[i] = 0;
    __syncthreads();
    for (int i = t; i < EPG; i += 256) {
        int s = cs[e0 + i];
        if (s < 0) {
            eloc[i] = make_ushort2(DEAD, DEAD);
        } else {
            ushort2 p = make_ushort2((unsigned short)(s - base),
                                     (unsigned short)(cd[e0 + i] - base));
            eloc[i] = p;
            atomicAdd(&cnt[p.y], 1);
        }
    }
    __syncthreads();
    // exclusive scan of cnt[0..n) : 2 elements per thread + shfl wave scan
    const int i0 = 2 * t, i1 = 2 * t + 1;
    const int a = (i0 < n) ? cnt[i0] : 0;
    const int b = (i1 < n) ? cnt[i1] : 0;
    const int p = a + b;
    const int lane = t & 63, w = t >> 6;
    int xv = p;
#pragma unroll
    for (int o = 1; o < 64; o <<= 1) {
        int y = __shfl_up(xv, o);
        if (lane >= o) xv += y;
    }
    if (lane == 63) wsum[w] = xv;
    __syncthreads();
    int woff = 0;
    for (int ww = 0; ww < w; ww++) woff += wsum[ww];
    const int incl = xv + woff;
    const int excl = incl - p;
    if (i0 < n) { basep[i0] = excl;     cnt[i0] = 0; rowptr[g * RPS + i0] = excl; }
    if (i1 < n) { basep[i1] = excl + a; cnt[i1] = 0; rowptr[g * RPS + i1] = excl + a; }
    if (t == 255) rowptr[g * RPS + n] = incl;   // total live edges
    __syncthreads();
    for (int i = t; i < EPG; i += 256) {
        ushort2 pe = eloc[i];
        if (pe.x != DEAD) {
            int pos = basep[pe.y] + atomicAdd(&cnt[pe.y], 1);
            col[e0 + pos] = pe.x;
        }
    }
}

// ---------------- layers 2/3 aggregation: CSR gather, no atomics ----------
// per-(graph, 16-feature-slice). h slice staged pre-quantized to int in LDS;
// each 16-lane subgroup sums its node's neighbors with register int adds.
// Deterministic: int addition is order-invariant.
__global__ __launch_bounds__(256) void agg_gather_kernel(
    const float* __restrict__ h, const int* __restrict__ rowptr,
    const unsigned short* __restrict__ col, int* __restrict__ agg, int n) {
    __shared__ int hsq[K1 * 16];
    __shared__ unsigned short colL[EPG];
    __shared__ int rp[N0 + 1];
    const int g = blockIdx.x;
    const int fq = blockIdx.y * 16;
    const int t = threadIdx.x;
    const int base = g * n;
    const int e0 = g * EPG;
    const int nf4 = n * 4;
    for (int i = t; i < nf4; i += 256) {
        int m = i >> 2, j = (i & 3) * 4;
        float4 v = *(const float4*)(h + (size_t)(base + m) * H + fq + j);
        int4 q;
        q.x = __float2int_rn(v.x * SCALE2);
        q.y = __float2int_rn(v.y * SCALE2);
        q.z = __float2int_rn(v.z * SCALE2);
        q.w = __float2int_rn(v.w * SCALE2);
        *(int4*)(hsq + m * 16 + j) = q;
    }
    {   // stage col as packed uints (coalesced)
        const unsigned int* src = (const unsigned int*)(col + e0);
        unsigned int* dst = (unsigned int*)colL;
        for (int i = t; i < EPG / 2; i += 256) dst[i] = src[i];
    }
    for (int i = t; i <= n; i += 256) rp[i] = rowptr[g * RPS + i];
    __syncthreads();
    const int sub = t >> 4;   // 16 subgroups of 16 lanes
    const int f = t & 15;
    for (int m = sub; m < n; m += 16) {
        int r0 = rp[m], r1 = rp[m + 1];
        int acc = 0;
        for (int r = r0; r < r1; r++) {
            int c = colL[r];
            acc += hsq[c * 16 + f];
        }
        agg[(size_t)(base + m) * H + fq + f] = acc;
    }
}

// out[i][o] = relu( sum_k agg[i][k]*Wrel[o][k] + sum_k hin[i][k]*Wroot[o][k] + b[o] )
// 64x128 tile, 128 threads, 8x8 micro-tile: 4 b128 LDS reads per 128 FLOP
// (0.5 B/FLOP) -> LDS read demand at full VALU = 128 B/cyc = LDS peak
// (previous 4x8 needed 192 B/cyc -> capped at ~67% VALU).
// 25.6 KB LDS -> 6 blocks/CU; grid ~5 blocks/CU fully co-resident.
// Per-output K order unchanged (kc asc, kk asc) -> bit-identical results.
__global__ __launch_bounds__(128) void conv_gemm_kernel(
    const int* __restrict__ agg, const float* __restrict__ hin,
    const float* __restrict__ Wrel, const float* __restrict__ Wroot,
    const float* __restrict__ bias, float* __restrict__ out, int M) {
    __shared__ float As[32][68];
    __shared__ float Bs[32][132];
    const int t = threadIdx.x;
    const int row0 = blockIdx.x * 64;
    const int tx = t & 15;
    const int ty = t >> 4;       // 0..7
    const int o4 = tx * 4;       // cols [o4,o4+4) and [64+o4,64+o4+4)
    const int r8 = ty * 8;       // rows [r8, r8+8)

    float acc[8][8];
#pragma unroll
    for (int i = 0; i < 8; i++)
#pragma unroll
        for (int j = 0; j < 8; j++) acc[i][j] = 0.f;

#pragma unroll 1
    for (int kc = 0; kc < 256; kc += 32) {
        const float* Wsrc = (kc < 128) ? (Wrel + kc) : (Wroot + (kc - 128));
#pragma unroll
        for (int i = 0; i < 4; i++) {
            int li = t + i * 128;        // 0..511
            int r = li >> 3, q = li & 7; // r 0..63, q 0..7
            int grow = row0 + r;
            float4 v = make_float4(0.f, 0.f, 0.f, 0.f);
            if (grow < M) {
                if (kc < 128) {
                    int4 iv = *(const int4*)(agg + (size_t)grow * H + kc + q * 4);
                    v.x = (float)iv.x * INV2;
                    v.y = (float)iv.y * INV2;
                    v.z = (float)iv.z * INV2;
                    v.w = (float)iv.w * INV2;
                } else {
                    v = *(const float4*)(hin + (size_t)grow * H + (kc - 128) + q * 4);
                }
            }
            As[q * 4 + 0][r] = v.x;
            As[q * 4 + 1][r] = v.y;
            As[q * 4 + 2][r] = v.z;
            As[q * 4 + 3][r] = v.w;
        }
#pragma unroll
        for (int i = 0; i < 8; i++) {
            int li = t + i * 128;
            int o = li >> 3, q = li & 7;
            float4 v = *(const float4*)(Wsrc + (size_t)o * H + q * 4);
            Bs[q * 4 + 0][o] = v.x;
            Bs[q * 4 + 1][o] = v.y;
            Bs[q * 4 + 2][o] = v.z;
            Bs[q * 4 + 3][o] = v.w;
        }
        __syncthreads();
#pragma unroll
        for (int kk = 0; kk < 32; kk++) {
            const float4 a0 = *(const float4*)&As[kk][r8];
            const float4 a1 = *(const float4*)&As[kk][r8 + 4];
            const float4 b0 = *(const float4*)&Bs[kk][o4];
            const float4 b1 = *(const float4*)&Bs[kk][64 + o4];
            float av[8] = {a0.x, a0.y, a0.z, a0.w, a1.x, a1.y, a1.z, a1.w};
            float bv[8] = {b0.x, b0.y, b0.z, b0.w, b1.x, b1.y, b1.z, b1.w};
#pragma unroll
            for (int ii = 0; ii < 8; ii++)
#pragma unroll
                for (int jj = 0; jj < 8; jj++)
                    acc[ii][jj] = fmaf(av[ii], bv[jj], acc[ii][jj]);
        }
        __syncthreads();
    }

#pragma unroll
    for (int ii = 0; ii < 8; ii++) {
        int grow = row0 + r8 + ii;
        if (grow < M) {
            float4 o0, o1;
            o0.x = fmaxf(acc[ii][0] + bias[o4 + 0], 0.f);
            o0.y = fmaxf(acc[ii][1] + bias[o4 + 1], 0.f);
            o0.z = fmaxf(acc[ii][2] + bias[o4 + 2], 0.f);
            o0.w = fmaxf(acc[ii][3] + bias[o4 + 3], 0.f);
            o1.x = fmaxf(acc[ii][4] + bias[64 + o4 + 0], 0.f);
            o1.y = fmaxf(acc[ii][5] + bias[64 + o4 + 1], 0.f);
            o1.z = fmaxf(acc[ii][6] + bias[64 + o4 + 2], 0.f);
            o1.w = fmaxf(acc[ii][7] + bias[64 + o4 + 3], 0.f);
            *(float4*)(out + (size_t)grow * H + o4) = o0;
            *(float4*)(out + (size_t)grow * H + 64 + o4) = o1;
        }
    }
}

// ---------------- head ----------------
__global__ void fc_kernel(const float* __restrict__ in, const float* __restrict__ W,
                          const float* __restrict__ b, float* __restrict__ out,
                          int Gn, int Kdim, int Odim) {
    int idx = blockIdx.x * blockDim.x + threadIdx.x;
    if (idx >= Gn * Odim) return;
    int g = idx / Odim, o = idx % Odim;
    float acc = b[o];
    for (int k = 0; k < Kdim; k++) acc += in[g * Kdim + k] * W[o * Kdim + k];
    out[idx] = acc;
}

__global__ void bn_relu_kernel(float* __restrict__ x, const float* __restrict__ gam,
                               const float* __restrict__ bet, int Gn, int Odim) {
    int o = threadIdx.x;
    if (o >= Odim) return;
    float m = 0.f, m2 = 0.f;
    for (int g = 0; g < Gn; g++) {
        float v = x[g * Odim + o];
        m += v;
        m2 += v * v;
    }
    m /= (float)Gn;
    float var = m2 / (float)Gn - m * m;
    float inv = 1.0f / sqrtf(var + 1e-5f);
    float ga = gam[o], be = bet[o];
    for (int g = 0; g < Gn; g++) {
        float v = (x[g * Odim + o] - m) * inv * ga + be;
        x[g * Odim + o] = fmaxf(v, 0.f);
    }
}

__global__ void head_kernel(const float* __restrict__ fc2, const float* __restrict__ W,
                            const float* __restrict__ b, float* __restrict__ out) {
    int g = blockIdx.x * blockDim.x + threadIdx.x;
    if (g >= G) return;
    float l0 = b[0], l1 = b[1];
    for (int k = 0; k < 64; k++) {
        float v = fc2[g * 64 + k];
        l0 += v * W[k];
        l1 += v * W[64 + k];
    }
    float mx = fmaxf(l0, l1);
    float e0 = expf(l0 - mx), e1 = expf(l1 - mx);
    float s = e0 + e1;
    out[g * 2 + 0] = e0 / s;
    out[g * 2 + 1] = e1 / s;
}

extern "C" void kernel_launch(void* const* d_in, const int* in_sizes, int n_in,
                              void* d_out, int out_size, void* d_ws, size_t ws_size,
                              hipStream_t stream) {
    (void)in_sizes; (void)n_in; (void)out_size; (void)ws_size;

    const float* x      = (const float*)d_in[0];
    const int*   ei     = (const int*)d_in[1];
    const float* Wrel1  = (const float*)d_in[2];
    const float* Wroot1 = (const float*)d_in[3];
    const float* b1     = (const float*)d_in[4];
    const float* Wrel2  = (const float*)d_in[5];
    const float* Wroot2 = (const float*)d_in[6];
    const float* b2     = (const float*)d_in[7];
    const float* Wrel3  = (const float*)d_in[8];
    const float* Wroot3 = (const float*)d_in[9];
    const float* b3     = (const float*)d_in[10];
    const float* pw1    = (const float*)d_in[11];
    const float* pw2    = (const float*)d_in[12];
    const float* pw3    = (const float*)d_in[13];
    const float* lin1w  = (const float*)d_in[14];
    const float* lin1b  = (const float*)d_in[15];
    const float* lin2w  = (const float*)d_in[16];
    const float* lin2b  = (const float*)d_in[17];
    const float* lin3w  = (const float*)d_in[18];
    const float* lin3b  = (const float*)d_in[19];
    const float* bn1g   = (const float*)d_in[20];
    const float* bn1b   = (const float*)d_in[21];
    const float* bn2g   = (const float*)d_in[22];
    const float* bn2b   = (const float*)d_in[23];

    float* bufA  = (float*)d_ws;                  // NT0*H floats
    float* bufB  = bufA + (size_t)NT0 * H;        // NT1*H floats (also agg6 scratch)
    float* score = bufB + (size_t)NT1 * H;        // NT0
    int*   perm  = (int*)(score + NT0);           // NT1
    int*   inv   = perm + NT1;                    // NT0
    int*   cs    = inv + NT0;                     // NE
    int*   cd    = cs + NE;                       // NE
    float* z     = (float*)(cd + NE);             // G*256
    float* f1    = z + G * 256;                   // G*128
    float* f2    = f1 + G * H;                    // G*64
    int*   rowp  = (int*)(f2 + G * 64);           // G*RPS ints
    unsigned short* col = (unsigned short*)(rowp + G * RPS);   // NE ushorts

    // ---- init ----
    hipMemsetAsync(z, 0, (size_t)G * 256 * sizeof(float), stream);
    init_edges_kernel<<<cdiv(NE, 256), 256, 0, stream>>>(ei, cs, cd);

    // ---- layer 1 ----
    agg6_lds_kernel<<<G, 256, 0, stream>>>(x, ei, (int*)bufB);
    conv1_kernel<<<cdiv(NT0 * 32, 256), 256, 0, stream>>>(x, (const int*)bufB, Wrel1, Wroot1, b1, bufA);
    score_kernel<<<cdiv(NT0 * 64, 256), 256, 0, stream>>>(bufA, pw1, score, NT0);
    topk_kernel<<<G, 512, 0, stream>>>(score, N0, K1, perm, inv);
    gather_pool_kernel<<<cdiv(NT1 * 32, 256), 256, 0, stream>>>(bufA, score, perm, bufB, NT1);
    remap_kernel<<<cdiv(NE, 256), 256, 0, stream>>>(cs, cd, inv);
    readout_kernel<<<G, 512, 0, stream>>>(bufB, z, K1);

    // ---- layer 2 ----
    build_csr_kernel<<<G, 256, 0, stream>>>(cs, cd, K1, rowp, col);
    agg_gather_kernel<<<dim3(G, 8), 256, 0, stream>>>(bufB, rowp, col, (int*)bufA, K1);
    conv_gemm_kernel<<<cdiv(NT1, 64), 128, 0, stream>>>((const int*)bufA, bufB, Wrel2, Wroot2, b2, bufA, NT1);
    score_kernel<<<cdiv(NT1 * 64, 256), 256, 0, stream>>>(bufA, pw2, score, NT1);
    topk_kernel<<<G, 512, 0, stream>>>(score, K1, K2, perm, inv);
    gather_pool_kernel<<<cdiv(NT2 * 32, 256), 256, 0, stream>>>(bufA, score, perm, bufB, NT2);
    remap_kernel<<<cdiv(NE, 256), 256, 0, stream>>>(cs, cd, inv);
    readout_kernel<<<G, 512, 0, stream>>>(bufB, z, K2);

    // ---- layer 3 ----
    build_csr_kernel<<<G, 256, 0, stream>>>(cs, cd, K2, rowp, col);
    agg_gather_kernel<<<dim3(G, 8), 256, 0, stream>>>(bufB, rowp, col, (int*)bufA, K2);
    conv_gemm_kernel<<<cdiv(NT2, 64), 128, 0, stream>>>((const int*)bufA, bufB, Wrel3, Wroot3, b3, bufA, NT2);
    score_kernel<<<cdiv(NT2 * 64, 256), 256, 0, stream>>>(bufA, pw3, score, NT2);
    topk_kernel<<<G, 512, 0, stream>>>(score, K2, K3, perm, inv);
    gather_pool_kernel<<<cdiv(NT3 * 32, 256), 256, 0, stream>>>(bufA, score, perm, bufB, NT3);
    readout_kernel<<<G, 512, 0, stream>>>(bufB, z, K3);

    // ---- head ----
    fc_kernel<<<cdiv(G * 128, 256), 256, 0, stream>>>(z, lin1w, lin1b, f1, G, 256, 128);
    bn_relu_kernel<<<1, 128, 0, stream>>>(f1, bn1g, bn1b, G, 128);
    fc_kernel<<<cdiv(G * 64, 256), 256, 0, stream>>>(f1, lin2w, lin2b, f2, G, 128, 64);
    bn_relu_kernel<<<1, 64, 0, stream>>>(f2, bn2g, bn2b, G, 64);
    head_kernel<<<1, 256, 0, stream>>>(f2, lin3w, lin3b, (float*)d_out);
}

// Round 9
// 777.302 us; speedup vs baseline: 1.1290x; 1.1290x over previous
//
#include <hip/hip_runtime.h>
#include <math.h>

#define G 200
#define N0 512
#define NE 614400          // G*N0*6
#define EPG 3072           // edges per graph (slot-stable across layers)
#define K1 410
#define K2 328
#define K3 263
#define H 128
#define NT0 102400         // G*N0
#define NT1 82000          // G*K1
#define NT2 65600          // G*K2
#define NT3 52600          // G*K3

// fixed-point scales for deterministic integer aggregation
#define SCALE1 1048576.0f        // 2^20, layer-1 features (|x| <= ~6)
#define INV1   (1.0f / 1048576.0f)
#define SCALE2 262144.0f         // 2^18, layers 2/3 (messages <= ~300, agg <= ~8000)
#define INV2   (1.0f / 262144.0f)

#define DEAD 0xFFFFu
#define RPS (N0 + 1)             // rowptr stride per graph

static inline int cdiv(int a, int b) { return (a + b - 1) / b; }

// ---------------- layer 1 ----------------
__global__ void init_edges_kernel(const int* __restrict__ ei, int* __restrict__ cs, int* __restrict__ cd) {
    int e = blockIdx.x * blockDim.x + threadIdx.x;
    if (e >= NE) return;
    cs[e] = ei[e];
    cd[e] = ei[NE + e];
}

// per-graph LDS aggregation of the 6 input features (stride-8 padded rows).
// edges staged once into LDS (ushort2 local ids) -> inner loop is pure LDS.
// int fixed-point LDS atomics -> deterministic. Writes every output element.
__global__ __launch_bounds__(256) void agg6_lds_kernel(
    const float* __restrict__ x, const int* __restrict__ ei, int* __restrict__ agg) {
    __shared__ float xs[N0 * 8];
    __shared__ int   ag[N0 * 8];
    __shared__ ushort2 eloc[EPG];
    const int g = blockIdx.x;
    const int t = threadIdx.x;
    const int base = g * N0;
    const int e0 = g * EPG;
    for (int i = t; i < N0 * 8; i += 256) {
        int m = i >> 3, j = i & 7;
        xs[i] = (j < 6) ? x[(size_t)(base + m) * 6 + j] : 0.f;
        ag[i] = 0;
    }
    for (int i = t; i < EPG; i += 256) {
        eloc[i] = make_ushort2((unsigned short)(ei[e0 + i] - base),
                               (unsigned short)(ei[NE + e0 + i] - base));
    }
    __syncthreads();
    const int sub = t >> 3;   // 32 subgroups of 8 lanes; 32 edges per iteration
    const int f = t & 7;
#pragma unroll 4
    for (int e = sub; e < EPG; e += 32) {
        ushort2 p = eloc[e];
        if (f < 6) {
            float v = xs[p.x * 8 + f];
            atomicAdd(&ag[p.y * 8 + f], __float2int_rn(v * SCALE1));
        }
    }
    __syncthreads();
    for (int i = t; i < N0 * 6; i += 256) {
        int m = i / 6, j = i - m * 6;
        agg[(size_t)(base + m) * 6 + j] = ag[m * 8 + j];
    }
}

// 4 outputs per thread + FUSED score: the 32 threads of a node shfl-reduce
// their partial dot with pw (fixed order -> deterministic).
__global__ void conv1_kernel(const float* __restrict__ x, const int* __restrict__ agg6,
                             const float* __restrict__ Wrel, const float* __restrict__ Wroot,
                             const float* __restrict__ b, const float* __restrict__ pw,
                             float* __restrict__ h, float* __restrict__ score) {
    int idx = blockIdx.x * blockDim.x + threadIdx.x;
    if (idx >= NT0 * 32) return;
    int node = idx >> 5, o4 = (idx & 31) * 4;
    float a[6], xv[6];
#pragma unroll
    for (int f = 0; f < 6; f++) {
        a[f] = (float)agg6[node * 6 + f] * INV1;
        xv[f] = x[node * 6 + f];
    }
    float4 r;
    float* rp = (float*)&r;
    float d = 0.f, n2 = 0.f;
#pragma unroll
    for (int j = 0; j < 4; j++) {
        int o = o4 + j;
        float acc = b[o];
#pragma unroll
        for (int f = 0; f < 6; f++)
            acc += a[f] * Wrel[o * 6 + f] + xv[f] * Wroot[o * 6 + f];
        float hv = fmaxf(acc, 0.f);
        rp[j] = hv;
        float wv = pw[o];
        d = fmaf(hv, wv, d);
        n2 = fmaf(wv, wv, n2);
    }
    *(float4*)(h + (size_t)node * H + o4) = r;
#pragma unroll
    for (int s = 1; s < 32; s <<= 1) {
        d += __shfl_xor(d, s);
        n2 += __shfl_xor(n2, s);
    }
    if ((idx & 31) == 0) score[node] = tanhf(d / sqrtf(n2));
}

// ---------------- top-k / pooling ----------------
// one block (512 threads) per graph; register bitonic sort (descending,
// index-tiebreak = stable like jax.lax.top_k). Strides <64 via __shfl_xor
// (intra-wave), strides >=64 via LDS (6 of 45 stages). Writes perm + inv.
__global__ __launch_bounds__(512) void topk_kernel(const float* __restrict__ score, int n, int k,
                                                   int* __restrict__ perm, int* __restrict__ inv) {
    __shared__ float sv[512];
    __shared__ int si[512];
    const int g = blockIdx.x;
    const int t = threadIdx.x;
    float v = (t < n) ? score[g * n + t] : -INFINITY;
    int idx = t;
    for (int size = 2; size <= 512; size <<= 1) {
        const bool desc = ((t & size) == 0);
        for (int stride = size >> 1; stride > 0; stride >>= 1) {
            float pv; int pi;
            if (stride >= 64) {
                sv[t] = v; si[t] = idx;
                __syncthreads();
                pv = sv[t ^ stride]; pi = si[t ^ stride];
                __syncthreads();
            } else {
                pv = __shfl_xor(v, stride);
                pi = __shfl_xor(idx, stride);
            }
            const bool left = ((t & stride) == 0);
            const bool want_max = (desc == left);
            // total order: higher value first; equal values -> smaller index first
            const bool A = (v > pv) || (v == pv && idx < pi);
            if (want_max != A) { v = pv; idx = pi; }
        }
    }
    if (t < n) inv[g * n + t] = -1;
    __syncthreads();
    if (t < k) {
        perm[g * k + t] = g * n + idx;
        inv[g * n + idx] = g * k + t;
    }
}

__global__ void gather_pool_kernel(const float* __restrict__ h, const float* __restrict__ score,
                                   const int* __restrict__ perm, float* __restrict__ out, int nNew) {
    int idx = blockIdx.x * blockDim.x + threadIdx.x;
    int nn = idx >> 5;
    if (nn >= nNew) return;
    int fq = (idx & 31) * 4;
    int old = perm[nn];
    float s = score[old];
    float4 v = *(const float4*)(h + (size_t)old * H + fq);
    v.x *= s; v.y *= s; v.z *= s; v.w *= s;
    *(float4*)(out + (size_t)nn * H + fq) = v;
}

__global__ void remap_kernel(int* __restrict__ cs, int* __restrict__ cd, const int* __restrict__ inv) {
    int e = blockIdx.x * blockDim.x + threadIdx.x;
    if (e >= NE) return;
    int s = cs[e];
    if (s < 0) return;
    int d = cd[e];
    int ns = inv[s], nd = inv[d];
    if (ns < 0 || nd < 0) { cs[e] = -1; }
    else { cs[e] = ns; cd[e] = nd; }
}

// one block (512 threads) per graph; 4-way partitioned j-loop, LDS combine.
// deterministic: fixed partition of the k-sum.
__global__ __launch_bounds__(512) void readout_kernel(const float* __restrict__ h,
                                                      float* __restrict__ z, int k) {
    __shared__ float smax[4][128];
    __shared__ float ssum[4][128];
    const int g = blockIdx.x;
    const int t = threadIdx.x;
    const int f = t & 127;
    const int part = t >> 7;
    const float* p = h + (size_t)g * k * H + f;
    float mx = -INFINITY, sm = 0.f;
    for (int j = part; j < k; j += 4) {
        float v = p[(size_t)j * H];
        mx = fmaxf(mx, v);
        sm += v;
    }
    smax[part][f] = mx;
    ssum[part][f] = sm;
    __syncthreads();
    if (t < 128) {
        float m0 = fmaxf(fmaxf(smax[0][t], smax[1][t]), fmaxf(smax[2][t], smax[3][t]));
        float s0 = (ssum[0][t] + ssum[1][t]) + (ssum[2][t] + ssum[3][t]);
        z[g * 256 + t] += m0;
        z[g * 256 + 128 + t] += s0 / (float)k;
    }
}

// ---------------- CSR build (layers 2/3) ----------------
// one block per graph. Deterministic rowptr (atomic counts + scan); col
// placement order is scheduling-dependent but consumers sum INTs -> invariant.
__global__ __launch_bounds__(256) void build_csr_kernel(
    const int* __restrict__ cs, const int* __restrict__ cd, int n,
    int* __restrict__ rowptr, unsigned short* __restrict__ col) {
    __shared__ ushort2 eloc[EPG];
    __shared__ int cnt[N0];
    __shared__ int basep[N0];
    __shared__ int wsum[4];
    const int g = blockIdx.x;
    const int t = threadIdx.x;
    const int base = g * n;
    const int e0 = g * EPG;
    for (int i = t; i < n; i += 256) cnt[i] = 0;
    __syncthreads();
    for (int i = t; i < EPG; i += 256) {
        int s = cs[e0 + i];
        if (s < 0) {
            eloc[i] = make_ushort2(DEAD, DEAD);
        } else {
            ushort2 p = make_ushort2((unsigned short)(s - base),
                                     (unsigned short)(cd[e0 + i] - base));
            eloc[i] = p;
            atomicAdd(&cnt[p.y], 1);
        }
    }
    __syncthreads();
    // exclusive scan of cnt[0..n) : 2 elements per thread + shfl wave scan
    const int i0 = 2 * t, i1 = 2 * t + 1;
    const int a = (i0 < n) ? cnt[i0] : 0;
    const int b = (i1 < n) ? cnt[i1] : 0;
    const int p = a + b;
    const int lane = t & 63, w = t >> 6;
    int xv = p;
#pragma unroll
    for (int o = 1; o < 64; o <<= 1) {
        int y = __shfl_up(xv, o);
        if (lane >= o) xv += y;
    }
    if (lane == 63) wsum[w] = xv;
    __syncthreads();
    int woff = 0;
    for (int ww = 0; ww < w; ww++) woff += wsum[ww];
    const int incl = xv + woff;
    const int excl = incl - p;
    if (i0 < n) { basep[i0] = excl;     cnt[i0] = 0; rowptr[g * RPS + i0] = excl; }
    if (i1 < n) { basep[i1] = excl + a; cnt[i1] = 0; rowptr[g * RPS + i1] = excl + a; }
    if (t == 255) rowptr[g * RPS + n] = incl;   // total live edges
    __syncthreads();
    for (int i = t; i < EPG; i += 256) {
        ushort2 pe = eloc[i];
        if (pe.x != DEAD) {
            int pos = basep[pe.y] + atomicAdd(&cnt[pe.y], 1);
            col[e0 + pos] = pe.x;
        }
    }
}

// ---------------- layers 2/3 aggregation: CSR gather, no atomics ----------
// per-(graph, 16-feature-slice). h slice staged pre-quantized to int in LDS;
// each 16-lane subgroup sums its node's neighbors with register int adds.
// Deterministic: int addition is order-invariant.
__global__ __launch_bounds__(256) void agg_gather_kernel(
    const float* __restrict__ h, const int* __restrict__ rowptr,
    const unsigned short* __restrict__ col, int* __restrict__ agg, int n) {
    __shared__ int hsq[K1 * 16];
    __shared__ unsigned short colL[EPG];
    __shared__ int rp[N0 + 1];
    const int g = blockIdx.x;
    const int fq = blockIdx.y * 16;
    const int t = threadIdx.x;
    const int base = g * n;
    const int e0 = g * EPG;
    const int nf4 = n * 4;
    for (int i = t; i < nf4; i += 256) {
        int m = i >> 2, j = (i & 3) * 4;
        float4 v = *(const float4*)(h + (size_t)(base + m) * H + fq + j);
        int4 q;
        q.x = __float2int_rn(v.x * SCALE2);
        q.y = __float2int_rn(v.y * SCALE2);
        q.z = __float2int_rn(v.z * SCALE2);
        q.w = __float2int_rn(v.w * SCALE2);
        *(int4*)(hsq + m * 16 + j) = q;
    }
    {   // stage col as packed uints (coalesced)
        const unsigned int* src = (const unsigned int*)(col + e0);
        unsigned int* dst = (unsigned int*)colL;
        for (int i = t; i < EPG / 2; i += 256) dst[i] = src[i];
    }
    for (int i = t; i <= n; i += 256) rp[i] = rowptr[g * RPS + i];
    __syncthreads();
    const int sub = t >> 4;   // 16 subgroups of 16 lanes
    const int f = t & 15;
    for (int m = sub; m < n; m += 16) {
        int r0 = rp[m], r1 = rp[m + 1];
        int acc = 0;
        for (int r = r0; r < r1; r++) {
            int c = colL[r];
            acc += hsq[c * 16 + f];
        }
        agg[(size_t)(base + m) * H + fq + f] = acc;
    }
}

// out[i][o] = relu( sum_k agg[i][k]*Wrel[o][k] + sum_k hin[i][k]*Wroot[o][k] + b[o] )
// R7-proven config: 64x128 tile, 256 threads, 4x8 micro-tile, o4-split B cols
// (conflict-free), Bs padded 132. FUSED score epilogue: 16 tx-threads hold a
// row's 128 cols -> shfl_xor reduce (fixed order, deterministic).
// agg is int32 fixed-point, converted inline. out aliases agg (in-place safe).
// Per-output K order unchanged (kc asc, kk asc) -> bit-identical h.
__global__ __launch_bounds__(256) void conv_gemm_kernel(
    const int* __restrict__ agg, const float* __restrict__ hin,
    const float* __restrict__ Wrel, const float* __restrict__ Wroot,
    const float* __restrict__ bias, const float* __restrict__ pw,
    float* __restrict__ out, float* __restrict__ score, int M) {
    __shared__ float As[32][68];
    __shared__ float Bs[32][132];
    const int t = threadIdx.x;
    const int row0 = blockIdx.x * 64;
    const int tx = t & 15;
    const int ty = t >> 4;
    const int o4 = tx * 4;       // cols [o4,o4+4) and [64+o4,64+o4+4)
    const int r4 = ty * 4;

    float acc[4][8];
#pragma unroll
    for (int i = 0; i < 4; i++)
#pragma unroll
        for (int j = 0; j < 8; j++) acc[i][j] = 0.f;

#pragma unroll 1
    for (int kc = 0; kc < 256; kc += 32) {
        const float* Wsrc = (kc < 128) ? (Wrel + kc) : (Wroot + (kc - 128));
#pragma unroll
        for (int i = 0; i < 2; i++) {
            int li = t + i * 256;        // 0..511
            int r = li >> 3, q = li & 7; // r 0..63, q 0..7
            int grow = row0 + r;
            float4 v = make_float4(0.f, 0.f, 0.f, 0.f);
            if (grow < M) {
                if (kc < 128) {
                    int4 iv = *(const int4*)(agg + (size_t)grow * H + kc + q * 4);
                    v.x = (float)iv.x * INV2;
                    v.y = (float)iv.y * INV2;
                    v.z = (float)iv.z * INV2;
                    v.w = (float)iv.w * INV2;
                } else {
                    v = *(const float4*)(hin + (size_t)grow * H + (kc - 128) + q * 4);
                }
            }
            As[q * 4 + 0][r] = v.x;
            As[q * 4 + 1][r] = v.y;
            As[q * 4 + 2][r] = v.z;
            As[q * 4 + 3][r] = v.w;
        }
#pragma unroll
        for (int i = 0; i < 4; i++) {
            int li = t + i * 256;
            int o = li >> 3, q = li & 7;
            float4 v = *(const float4*)(Wsrc + (size_t)o * H + q * 4);
            Bs[q * 4 + 0][o] = v.x;
            Bs[q * 4 + 1][o] = v.y;
            Bs[q * 4 + 2][o] = v.z;
            Bs[q * 4 + 3][o] = v.w;
        }
        __syncthreads();
#pragma unroll
        for (int kk = 0; kk < 32; kk++) {
            const float4 a0 = *(const float4*)&As[kk][r4];
            const float4 b0 = *(const float4*)&Bs[kk][o4];
            const float4 b1 = *(const float4*)&Bs[kk][64 + o4];
            float av[4] = {a0.x, a0.y, a0.z, a0.w};
            float bv[8] = {b0.x, b0.y, b0.z, b0.w, b1.x, b1.y, b1.z, b1.w};
#pragma unroll
            for (int ii = 0; ii < 4; ii++)
#pragma unroll
                for (int jj = 0; jj < 8; jj++)
                    acc[ii][jj] = fmaf(av[ii], bv[jj], acc[ii][jj]);
        }
        __syncthreads();
    }

    // fused-score weights for this thread's 8 columns
    float wv[8];
#pragma unroll
    for (int j = 0; j < 4; j++) { wv[j] = pw[o4 + j]; wv[4 + j] = pw[64 + o4 + j]; }
    float n2 = 0.f;
#pragma unroll
    for (int j = 0; j < 8; j++) n2 = fmaf(wv[j], wv[j], n2);
#pragma unroll
    for (int s = 1; s < 16; s <<= 1) n2 += __shfl_xor(n2, s);
    const float rnorm = 1.0f / sqrtf(n2);

#pragma unroll
    for (int ii = 0; ii < 4; ii++) {
        int grow = row0 + r4 + ii;
        float4 o0, o1;
        o0.x = fmaxf(acc[ii][0] + bias[o4 + 0], 0.f);
        o0.y = fmaxf(acc[ii][1] + bias[o4 + 1], 0.f);
        o0.z = fmaxf(acc[ii][2] + bias[o4 + 2], 0.f);
        o0.w = fmaxf(acc[ii][3] + bias[o4 + 3], 0.f);
        o1.x = fmaxf(acc[ii][4] + bias[64 + o4 + 0], 0.f);
        o1.y = fmaxf(acc[ii][5] + bias[64 + o4 + 1], 0.f);
        o1.z = fmaxf(acc[ii][6] + bias[64 + o4 + 2], 0.f);
        o1.w = fmaxf(acc[ii][7] + bias[64 + o4 + 3], 0.f);
        float d = 0.f;
        d = fmaf(o0.x, wv[0], d); d = fmaf(o0.y, wv[1], d);
        d = fmaf(o0.z, wv[2], d); d = fmaf(o0.w, wv[3], d);
        d = fmaf(o1.x, wv[4], d); d = fmaf(o1.y, wv[5], d);
        d = fmaf(o1.z, wv[6], d); d = fmaf(o1.w, wv[7], d);
#pragma unroll
        for (int s = 1; s < 16; s <<= 1) d += __shfl_xor(d, s);
        if (grow < M) {
            *(float4*)(out + (size_t)grow * H + o4) = o0;
            *(float4*)(out + (size_t)grow * H + 64 + o4) = o1;
            if (tx == 0) score[grow] = tanhf(d * rnorm);
        }
    }
}

// ---------------- head ----------------
__global__ void fc_kernel(const float* __restrict__ in, const float* __restrict__ W,
                          const float* __restrict__ b, float* __restrict__ out,
                          int Gn, int Kdim, int Odim) {
    int idx = blockIdx.x * blockDim.x + threadIdx.x;
    if (idx >= Gn * Odim) return;
    int g = idx / Odim, o = idx % Odim;
    float acc = b[o];
    for (int k = 0; k < Kdim; k++) acc += in[g * Kdim + k] * W[o * Kdim + k];
    out[idx] = acc;
}

__global__ void bn_relu_kernel(float* __restrict__ x, const float* __restrict__ gam,
                               const float* __restrict__ bet, int Gn, int Odim) {
    int o = threadIdx.x;
    if (o >= Odim) return;
    float m = 0.f, m2 = 0.f;
    for (int g = 0; g < Gn; g++) {
        float v = x[g * Odim + o];
        m += v;
        m2 += v * v;
    }
    m /= (float)Gn;
    float var = m2 / (float)Gn - m * m;
    float inv = 1.0f / sqrtf(var + 1e-5f);
    float ga = gam[o], be = bet[o];
    for (int g = 0; g < Gn; g++) {
        float v = (x[g * Odim + o] - m) * inv * ga + be;
        x[g * Odim + o] = fmaxf(v, 0.f);
    }
}

__global__ void head_kernel(const float* __restrict__ fc2, const float* __restrict__ W,
                            const float* __restrict__ b, float* __restrict__ out) {
    int g = blockIdx.x * blockDim.x + threadIdx.x;
    if (g >= G) return;
    float l0 = b[0], l1 = b[1];
    for (int k = 0; k < 64; k++) {
        float v = fc2[g * 64 + k];
        l0 += v * W[k];
        l1 += v * W[64 + k];
    }
    float mx = fmaxf(l0, l1);
    float e0 = expf(l0 - mx), e1 = expf(l1 - mx);
    float s = e0 + e1;
    out[g * 2 + 0] = e0 / s;
    out[g * 2 + 1] = e1 / s;
}

extern "C" void kernel_launch(void* const* d_in, const int* in_sizes, int n_in,
                              void* d_out, int out_size, void* d_ws, size_t ws_size,
                              hipStream_t stream) {
    (void)in_sizes; (void)n_in; (void)out_size; (void)ws_size;

    const float* x      = (const float*)d_in[0];
    const int*   ei     = (const int*)d_in[1];
    const float* Wrel1  = (const float*)d_in[2];
    const float* Wroot1 = (const float*)d_in[3];
    const float* b1     = (const float*)d_in[4];
    const float* Wrel2  = (const float*)d_in[5];
    const float* Wroot2 = (const float*)d_in[6];
    const float* b2     = (const float*)d_in[7];
    const float* Wrel3  = (const float*)d_in[8];
    const float* Wroot3 = (const float*)d_in[9];
    const float* b3     = (const float*)d_in[10];
    const float* pw1    = (const float*)d_in[11];
    const float* pw2    = (const float*)d_in[12];
    const float* pw3    = (const float*)d_in[13];
    const float* lin1w  = (const float*)d_in[14];
    const float* lin1b  = (const float*)d_in[15];
    const float* lin2w  = (const float*)d_in[16];
    const float* lin2b  = (const float*)d_in[17];
    const float* lin3w  = (const float*)d_in[18];
    const float* lin3b  = (const float*)d_in[19];
    const float* bn1g   = (const float*)d_in[20];
    const float* bn1b   = (const float*)d_in[21];
    const float* bn2g   = (const float*)d_in[22];
    const float* bn2b   = (const float*)d_in[23];

    float* bufA  = (float*)d_ws;                  // NT0*H floats
    float* bufB  = bufA + (size_t)NT0 * H;        // NT1*H floats (also agg6 scratch)
    float* score = bufB + (size_t)NT1 * H;        // NT0
    int*   perm  = (int*)(score + NT0);           // NT1
    int*   inv   = perm + NT1;                    // NT0
    int*   cs    = inv + NT0;                     // NE
    int*   cd    = cs + NE;                       // NE
    float* z     = (float*)(cd + NE);             // G*256
    float* f1    = z + G * 256;                   // G*128
    float* f2    = f1 + G * H;                    // G*64
    int*   rowp  = (int*)(f2 + G * 64);           // G*RPS ints
    unsigned short* col = (unsigned short*)(rowp + G * RPS);   // NE ushorts

    // ---- init ----
    hipMemsetAsync(z, 0, (size_t)G * 256 * sizeof(float), stream);
    init_edges_kernel<<<cdiv(NE, 256), 256, 0, stream>>>(ei, cs, cd);

    // ---- layer 1 ----
    agg6_lds_kernel<<<G, 256, 0, stream>>>(x, ei, (int*)bufB);
    conv1_kernel<<<cdiv(NT0 * 32, 256), 256, 0, stream>>>(x, (const int*)bufB, Wrel1, Wroot1, b1, pw1, bufA, score);
    topk_kernel<<<G, 512, 0, stream>>>(score, N0, K1, perm, inv);
    gather_pool_kernel<<<cdiv(NT1 * 32, 256), 256, 0, stream>>>(bufA, score, perm, bufB, NT1);
    remap_kernel<<<cdiv(NE, 256), 256, 0, stream>>>(cs, cd, inv);
    readout_kernel<<<G, 512, 0, stream>>>(bufB, z, K1);

    // ---- layer 2 ----
    build_csr_kernel<<<G, 256, 0, stream>>>(cs, cd, K1, rowp, col);
    agg_gather_kernel<<<dim3(G, 8), 256, 0, stream>>>(bufB, rowp, col, (int*)bufA, K1);
    conv_gemm_kernel<<<cdiv(NT1, 64), 256, 0, stream>>>((const int*)bufA, bufB, Wrel2, Wroot2, b2, pw2, bufA, score, NT1);
    topk_kernel<<<G, 512, 0, stream>>>(score, K1, K2, perm, inv);
    gather_pool_kernel<<<cdiv(NT2 * 32, 256), 256, 0, stream>>>(bufA, score, perm, bufB, NT2);
    remap_kernel<<<cdiv(NE, 256), 256, 0, stream>>>(cs, cd, inv);
    readout_kernel<<<G, 512, 0, stream>>>(bufB, z, K2);

    // ---- layer 3 ----
    build_csr_kernel<<<G, 256, 0, stream>>>(cs, cd, K2, rowp, col);
    agg_gather_kernel<<<dim3(G, 8), 256, 0, stream>>>(bufB, rowp, col, (int*)bufA, K2);
    conv_gemm_kernel<<<cdiv(NT2, 64), 256, 0, stream>>>((const int*)bufA, bufB, Wrel3, Wroot3, b3, pw3, bufA, score, NT2);
    topk_kernel<<<G, 512, 0, stream>>>(score, K2, K3, perm, inv);
    gather_pool_kernel<<<cdiv(NT3 * 32, 256), 256, 0, stream>>>(bufA, score, perm, bufB, NT3);
    readout_kernel<<<G, 512, 0, stream>>>(bufB, z, K3);

    // ---- head ----
    fc_kernel<<<cdiv(G * 128, 256), 256, 0, stream>>>(z, lin1w, lin1b, f1, G, 256, 128);
    bn_relu_kernel<<<1, 128, 0, stream>>>(f1, bn1g, bn1b, G, 128);
    fc_kernel<<<cdiv(G * 64, 256), 256, 0, stream>>>(f1, lin2w, lin2b, f2, G, 128, 64);
    bn_relu_kernel<<<1, 64, 0, stream>>>(f2, bn2g, bn2b, G, 64);
    head_kernel<<<1, 256, 0, stream>>>(f2, lin3w, lin3b, (float*)d_out);
}

// Round 10
// 697.822 us; speedup vs baseline: 1.2576x; 1.1139x over previous
//
#include <hip/hip_runtime.h>
#include <math.h>

#define G 200
#define N0 512
#define NE 614400          // G*N0*6
#define EPG 3072           // edges per graph (slot-stable across layers)
#define K1 410
#define K2 328
#define K3 263
#define H 128
#define NT0 102400         // G*N0
#define NT1 82000          // G*K1
#define NT2 65600          // G*K2
#define NT3 52600          // G*K3

// fixed-point scales for deterministic integer aggregation
#define SCALE1 1048576.0f        // 2^20, layer-1 features (|x| <= ~6)
#define INV1   (1.0f / 1048576.0f)
#define SCALE2 262144.0f         // 2^18, layers 2/3 (messages <= ~300, agg <= ~8000)
#define INV2   (1.0f / 262144.0f)

#define DEAD 0xFFFFu
#define RPS (N0 + 1)             // rowptr stride per graph

static inline int cdiv(int a, int b) { return (a + b - 1) / b; }

// ---------------- layer 1 ----------------
__global__ void init_edges_kernel(const int* __restrict__ ei, int* __restrict__ cs, int* __restrict__ cd) {
    int e = blockIdx.x * blockDim.x + threadIdx.x;
    if (e >= NE) return;
    cs[e] = ei[e];
    cd[e] = ei[NE + e];
}

// per-graph LDS aggregation of the 6 input features (stride-8 padded rows).
// edges staged once into LDS (ushort2 local ids) -> inner loop is pure LDS.
// int fixed-point LDS atomics -> deterministic. Writes every output element.
__global__ __launch_bounds__(256) void agg6_lds_kernel(
    const float* __restrict__ x, const int* __restrict__ ei, int* __restrict__ agg) {
    __shared__ float xs[N0 * 8];
    __shared__ int   ag[N0 * 8];
    __shared__ ushort2 eloc[EPG];
    const int g = blockIdx.x;
    const int t = threadIdx.x;
    const int base = g * N0;
    const int e0 = g * EPG;
    for (int i = t; i < N0 * 8; i += 256) {
        int m = i >> 3, j = i & 7;
        xs[i] = (j < 6) ? x[(size_t)(base + m) * 6 + j] : 0.f;
        ag[i] = 0;
    }
    for (int i = t; i < EPG; i += 256) {
        eloc[i] = make_ushort2((unsigned short)(ei[e0 + i] - base),
                               (unsigned short)(ei[NE + e0 + i] - base));
    }
    __syncthreads();
    const int sub = t >> 3;   // 32 subgroups of 8 lanes; 32 edges per iteration
    const int f = t & 7;
#pragma unroll 4
    for (int e = sub; e < EPG; e += 32) {
        ushort2 p = eloc[e];
        if (f < 6) {
            float v = xs[p.x * 8 + f];
            atomicAdd(&ag[p.y * 8 + f], __float2int_rn(v * SCALE1));
        }
    }
    __syncthreads();
    for (int i = t; i < N0 * 6; i += 256) {
        int m = i / 6, j = i - m * 6;
        agg[(size_t)(base + m) * 6 + j] = ag[m * 8 + j];
    }
}

// 4 outputs per thread + FUSED score: the 32 threads of a node shfl-reduce
// their partial dot with pw (fixed order -> deterministic).
__global__ void conv1_kernel(const float* __restrict__ x, const int* __restrict__ agg6,
                             const float* __restrict__ Wrel, const float* __restrict__ Wroot,
                             const float* __restrict__ b, const float* __restrict__ pw,
                             float* __restrict__ h, float* __restrict__ score) {
    int idx = blockIdx.x * blockDim.x + threadIdx.x;
    if (idx >= NT0 * 32) return;
    int node = idx >> 5, o4 = (idx & 31) * 4;
    float a[6], xv[6];
#pragma unroll
    for (int f = 0; f < 6; f++) {
        a[f] = (float)agg6[node * 6 + f] * INV1;
        xv[f] = x[node * 6 + f];
    }
    float4 r;
    float* rp = (float*)&r;
    float d = 0.f, n2 = 0.f;
#pragma unroll
    for (int j = 0; j < 4; j++) {
        int o = o4 + j;
        float acc = b[o];
#pragma unroll
        for (int f = 0; f < 6; f++)
            acc += a[f] * Wrel[o * 6 + f] + xv[f] * Wroot[o * 6 + f];
        float hv = fmaxf(acc, 0.f);
        rp[j] = hv;
        float wv = pw[o];
        d = fmaf(hv, wv, d);
        n2 = fmaf(wv, wv, n2);
    }
    *(float4*)(h + (size_t)node * H + o4) = r;
#pragma unroll
    for (int s = 1; s < 32; s <<= 1) {
        d += __shfl_xor(d, s);
        n2 += __shfl_xor(n2, s);
    }
    if ((idx & 31) == 0) score[node] = tanhf(d / sqrtf(n2));
}

// ---------------- FUSED topk + gather/gate + readout ----------------
// one block (512 threads) per graph. Register bitonic sort (descending,
// index-tiebreak); sorted (score,idx) kept in LDS. Then each thread gathers
// h[si[j]]*sv[j] for j = part (mod 4), writes pooled hout, and accumulates
// readout max/sum in the SAME order as the old standalone readout kernel
// -> bit-identical z and pooled h. 4-deep unrolled loads for latency hiding.
__global__ __launch_bounds__(512) void topk_pool_kernel(
    const float* __restrict__ h, const float* __restrict__ score,
    int n, int k, int* __restrict__ inv,
    float* __restrict__ hout, float* __restrict__ z) {
    __shared__ float sv[512];
    __shared__ int si[512];
    __shared__ float smax[4][128];
    __shared__ float ssum[4][128];
    const int g = blockIdx.x;
    const int t = threadIdx.x;
    float v = (t < n) ? score[g * n + t] : -INFINITY;
    int idx = t;
    for (int size = 2; size <= 512; size <<= 1) {
        const bool desc = ((t & size) == 0);
        for (int stride = size >> 1; stride > 0; stride >>= 1) {
            float pv; int pi;
            if (stride >= 64) {
                sv[t] = v; si[t] = idx;
                __syncthreads();
                pv = sv[t ^ stride]; pi = si[t ^ stride];
                __syncthreads();
            } else {
                pv = __shfl_xor(v, stride);
                pi = __shfl_xor(idx, stride);
            }
            const bool left = ((t & stride) == 0);
            const bool want_max = (desc == left);
            const bool A = (v > pv) || (v == pv && idx < pi);
            if (want_max != A) { v = pv; idx = pi; }
        }
    }
    // publish sorted arrays; init inv
    sv[t] = v; si[t] = idx;
    if (t < n) inv[g * n + t] = -1;
    __syncthreads();
    if (t < k) inv[g * n + idx] = g * k + t;

    // gather + gate + readout
    const int f = t & 127;
    const int part = t >> 7;
    const float* hbase = h + (size_t)g * n * H + f;
    float* obase = hout + (size_t)g * k * H + f;
    float mx = -INFINITY, sm = 0.f;
    int j = part;
    for (; j + 12 < k; j += 16) {
        int r0 = si[j], r1 = si[j + 4], r2 = si[j + 8], r3 = si[j + 12];
        float s0 = sv[j], s1 = sv[j + 4], s2 = sv[j + 8], s3 = sv[j + 12];
        float a0 = hbase[(size_t)r0 * H];
        float a1 = hbase[(size_t)r1 * H];
        float a2 = hbase[(size_t)r2 * H];
        float a3 = hbase[(size_t)r3 * H];
        float v0 = a0 * s0, v1 = a1 * s1, v2 = a2 * s2, v3 = a3 * s3;
        obase[(size_t)j * H] = v0;
        obase[(size_t)(j + 4) * H] = v1;
        obase[(size_t)(j + 8) * H] = v2;
        obase[(size_t)(j + 12) * H] = v3;
        mx = fmaxf(mx, v0); sm += v0;
        mx = fmaxf(mx, v1); sm += v1;
        mx = fmaxf(mx, v2); sm += v2;
        mx = fmaxf(mx, v3); sm += v3;
    }
    for (; j < k; j += 4) {
        float vv = hbase[(size_t)si[j] * H] * sv[j];
        obase[(size_t)j * H] = vv;
        mx = fmaxf(mx, vv); sm += vv;
    }
    smax[part][f] = mx;
    ssum[part][f] = sm;
    __syncthreads();
    if (t < 128) {
        float m0 = fmaxf(fmaxf(smax[0][t], smax[1][t]), fmaxf(smax[2][t], smax[3][t]));
        float s0 = (ssum[0][t] + ssum[1][t]) + (ssum[2][t] + ssum[3][t]);
        z[g * 256 + t] += m0;
        z[g * 256 + 128 + t] += s0 / (float)k;
    }
}

// ---------------- CSR build + inline remap (layers 2/3) ----------------
// one block per graph. Applies inv to the edge list inline (and writes back
// the remapped list for the next layer). Deterministic rowptr (atomic counts
// + scan); col placement order is scheduling-dependent but consumers sum
// INTs -> invariant. n = node count AFTER pooling.
__global__ __launch_bounds__(256) void build_csr_kernel(
    int* __restrict__ cs, int* __restrict__ cd, const int* __restrict__ inv, int n,
    int* __restrict__ rowptr, unsigned short* __restrict__ col) {
    __shared__ ushort2 eloc[EPG];
    __shared__ int cnt[N0];
    __shared__ int basep[N0];
    __shared__ int wsum[4];
    const int g = blockIdx.x;
    const int t = threadIdx.x;
    const int base = g * n;
    const int e0 = g * EPG;
    for (int i = t; i < n; i += 256) cnt[i] = 0;
    __syncthreads();
    for (int i = t; i < EPG; i += 256) {
        int s = cs[e0 + i];
        ushort2 p = make_ushort2(DEAD, DEAD);
        if (s >= 0) {
            int ns = inv[s], nd = inv[cd[e0 + i]];
            if (ns < 0 || nd < 0) {
                cs[e0 + i] = -1;
            } else {
                cs[e0 + i] = ns;
                cd[e0 + i] = nd;
                p = make_ushort2((unsigned short)(ns - base), (unsigned short)(nd - base));
                atomicAdd(&cnt[p.y], 1);
            }
        }
        eloc[i] = p;
    }
    __syncthreads();
    // exclusive scan of cnt[0..n) : 2 elements per thread + shfl wave scan
    const int i0 = 2 * t, i1 = 2 * t + 1;
    const int a = (i0 < n) ? cnt[i0] : 0;
    const int b = (i1 < n) ? cnt[i1] : 0;
    const int p = a + b;
    const int lane = t & 63, w = t >> 6;
    int xv = p;
#pragma unroll
    for (int o = 1; o < 64; o <<= 1) {
        int y = __shfl_up(xv, o);
        if (lane >= o) xv += y;
    }
    if (lane == 63) wsum[w] = xv;
    __syncthreads();
    int woff = 0;
    for (int ww = 0; ww < w; ww++) woff += wsum[ww];
    const int incl = xv + woff;
    const int excl = incl - p;
    if (i0 < n) { basep[i0] = excl;     cnt[i0] = 0; rowptr[g * RPS + i0] = excl; }
    if (i1 < n) { basep[i1] = excl + a; cnt[i1] = 0; rowptr[g * RPS + i1] = excl + a; }
    if (t == 255) rowptr[g * RPS + n] = incl;   // total live edges
    __syncthreads();
    for (int i = t; i < EPG; i += 256) {
        ushort2 pe = eloc[i];
        if (pe.x != DEAD) {
            int pos = basep[pe.y] + atomicAdd(&cnt[pe.y], 1);
            col[e0 + pos] = pe.x;
        }
    }
}

// ---------------- layers 2/3 aggregation: CSR gather, no atomics ----------
// per-(graph, 16-feature-slice). h slice staged pre-quantized to int in LDS;
// each 16-lane subgroup sums its node's neighbors with register int adds.
// Deterministic: int addition is order-invariant.
__global__ __launch_bounds__(256) void agg_gather_kernel(
    const float* __restrict__ h, const int* __restrict__ rowptr,
    const unsigned short* __restrict__ col, int* __restrict__ agg, int n) {
    __shared__ int hsq[K1 * 16];
    __shared__ unsigned short colL[EPG];
    __shared__ int rp[N0 + 1];
    const int g = blockIdx.x;
    const int fq = blockIdx.y * 16;
    const int t = threadIdx.x;
    const int base = g * n;
    const int e0 = g * EPG;
    const int nf4 = n * 4;
    for (int i = t; i < nf4; i += 256) {
        int m = i >> 2, j = (i & 3) * 4;
        float4 v = *(const float4*)(h + (size_t)(base + m) * H + fq + j);
        int4 q;
        q.x = __float2int_rn(v.x * SCALE2);
        q.y = __float2int_rn(v.y * SCALE2);
        q.z = __float2int_rn(v.z * SCALE2);
        q.w = __float2int_rn(v.w * SCALE2);
        *(int4*)(hsq + m * 16 + j) = q;
    }
    {   // stage col as packed uints (coalesced)
        const unsigned int* src = (const unsigned int*)(col + e0);
        unsigned int* dst = (unsigned int*)colL;
        for (int i = t; i < EPG / 2; i += 256) dst[i] = src[i];
    }
    for (int i = t; i <= n; i += 256) rp[i] = rowptr[g * RPS + i];
    __syncthreads();
    const int sub = t >> 4;   // 16 subgroups of 16 lanes
    const int f = t & 15;
    for (int m = sub; m < n; m += 16) {
        int r0 = rp[m], r1 = rp[m + 1];
        int acc = 0;
        for (int r = r0; r < r1; r++) {
            int c = colL[r];
            acc += hsq[c * 16 + f];
        }
        agg[(size_t)(base + m) * H + fq + f] = acc;
    }
}

// out[i][o] = relu( sum_k agg[i][k]*Wrel[o][k] + sum_k hin[i][k]*Wroot[o][k] + b[o] )
// R7-proven config: 64x128 tile, 256 threads, 4x8 micro-tile, o4-split B cols
// (conflict-free), Bs padded 132. FUSED score epilogue: 16 tx-threads hold a
// row's 128 cols -> shfl_xor reduce (fixed order, deterministic).
// agg is int32 fixed-point, converted inline. out aliases agg (in-place safe).
// Per-output K order unchanged (kc asc, kk asc) -> bit-identical h.
__global__ __launch_bounds__(256) void conv_gemm_kernel(
    const int* __restrict__ agg, const float* __restrict__ hin,
    const float* __restrict__ Wrel, const float* __restrict__ Wroot,
    const float* __restrict__ bias, const float* __restrict__ pw,
    float* __restrict__ out, float* __restrict__ score, int M) {
    __shared__ float As[32][68];
    __shared__ float Bs[32][132];
    const int t = threadIdx.x;
    const int row0 = blockIdx.x * 64;
    const int tx = t & 15;
    const int ty = t >> 4;
    const int o4 = tx * 4;       // cols [o4,o4+4) and [64+o4,64+o4+4)
    const int r4 = ty * 4;

    float acc[4][8];
#pragma unroll
    for (int i = 0; i < 4; i++)
#pragma unroll
        for (int j = 0; j < 8; j++) acc[i][j] = 0.f;

#pragma unroll 1
    for (int kc = 0; kc < 256; kc += 32) {
        const float* Wsrc = (kc < 128) ? (Wrel + kc) : (Wroot + (kc - 128));
#pragma unroll
        for (int i = 0; i < 2; i++) {
            int li = t + i * 256;        // 0..511
            int r = li >> 3, q = li & 7; // r 0..63, q 0..7
            int grow = row0 + r;
            float4 v = make_float4(0.f, 0.f, 0.f, 0.f);
            if (grow < M) {
                if (kc < 128) {
                    int4 iv = *(const int4*)(agg + (size_t)grow * H + kc + q * 4);
                    v.x = (float)iv.x * INV2;
                    v.y = (float)iv.y * INV2;
                    v.z = (float)iv.z * INV2;
                    v.w = (float)iv.w * INV2;
                } else {
                    v = *(const float4*)(hin + (size_t)grow * H + (kc - 128) + q * 4);
                }
            }
            As[q * 4 + 0][r] = v.x;
            As[q * 4 + 1][r] = v.y;
            As[q * 4 + 2][r] = v.z;
            As[q * 4 + 3][r] = v.w;
        }
#pragma unroll
        for (int i = 0; i < 4; i++) {
            int li = t + i * 256;
            int o = li >> 3, q = li & 7;
            float4 v = *(const float4*)(Wsrc + (size_t)o * H + q * 4);
            Bs[q * 4 + 0][o] = v.x;
            Bs[q * 4 + 1][o] = v.y;
            Bs[q * 4 + 2][o] = v.z;
            Bs[q * 4 + 3][o] = v.w;
        }
        __syncthreads();
#pragma unroll
        for (int kk = 0; kk < 32; kk++) {
            const float4 a0 = *(const float4*)&As[kk][r4];
            const float4 b0 = *(const float4*)&Bs[kk][o4];
            const float4 b1 = *(const float4*)&Bs[kk][64 + o4];
            float av[4] = {a0.x, a0.y, a0.z, a0.w};
            float bv[8] = {b0.x, b0.y, b0.z, b0.w, b1.x, b1.y, b1.z, b1.w};
#pragma unroll
            for (int ii = 0; ii < 4; ii++)
#pragma unroll
                for (int jj = 0; jj < 8; jj++)
                    acc[ii][jj] = fmaf(av[ii], bv[jj], acc[ii][jj]);
        }
        __syncthreads();
    }

    // fused-score weights for this thread's 8 columns
    float wv[8];
#pragma unroll
    for (int j = 0; j < 4; j++) { wv[j] = pw[o4 + j]; wv[4 + j] = pw[64 + o4 + j]; }
    float n2 = 0.f;
#pragma unroll
    for (int j = 0; j < 8; j++) n2 = fmaf(wv[j], wv[j], n2);
#pragma unroll
    for (int s = 1; s < 16; s <<= 1) n2 += __shfl_xor(n2, s);
    const float rnorm = 1.0f / sqrtf(n2);

#pragma unroll
    for (int ii = 0; ii < 4; ii++) {
        int grow = row0 + r4 + ii;
        float4 o0, o1;
        o0.x = fmaxf(acc[ii][0] + bias[o4 + 0], 0.f);
        o0.y = fmaxf(acc[ii][1] + bias[o4 + 1], 0.f);
        o0.z = fmaxf(acc[ii][2] + bias[o4 + 2], 0.f);
        o0.w = fmaxf(acc[ii][3] + bias[o4 + 3], 0.f);
        o1.x = fmaxf(acc[ii][4] + bias[64 + o4 + 0], 0.f);
        o1.y = fmaxf(acc[ii][5] + bias[64 + o4 + 1], 0.f);
        o1.z = fmaxf(acc[ii][6] + bias[64 + o4 + 2], 0.f);
        o1.w = fmaxf(acc[ii][7] + bias[64 + o4 + 3], 0.f);
        float d = 0.f;
        d = fmaf(o0.x, wv[0], d); d = fmaf(o0.y, wv[1], d);
        d = fmaf(o0.z, wv[2], d); d = fmaf(o0.w, wv[3], d);
        d = fmaf(o1.x, wv[4], d); d = fmaf(o1.y, wv[5], d);
        d = fmaf(o1.z, wv[6], d); d = fmaf(o1.w, wv[7], d);
#pragma unroll
        for (int s = 1; s < 16; s <<= 1) d += __shfl_xor(d, s);
        if (grow < M) {
            *(float4*)(out + (size_t)grow * H + o4) = o0;
            *(float4*)(out + (size_t)grow * H + 64 + o4) = o1;
            if (tx == 0) score[grow] = tanhf(d * rnorm);
        }
    }
}

// ---------------- head ----------------
__global__ void fc_kernel(const float* __restrict__ in, const float* __restrict__ W,
                          const float* __restrict__ b, float* __restrict__ out,
                          int Gn, int Kdim, int Odim) {
    int idx = blockIdx.x * blockDim.x + threadIdx.x;
    if (idx >= Gn * Odim) return;
    int g = idx / Odim, o = idx % Odim;
    float acc = b[o];
    for (int k = 0; k < Kdim; k++) acc += in[g * Kdim + k] * W[o * Kdim + k];
    out[idx] = acc;
}

__global__ void bn_relu_kernel(float* __restrict__ x, const float* __restrict__ gam,
                               const float* __restrict__ bet, int Gn, int Odim) {
    int o = threadIdx.x;
    if (o >= Odim) return;
    float m = 0.f, m2 = 0.f;
    for (int g = 0; g < Gn; g++) {
        float v = x[g * Odim + o];
        m += v;
        m2 += v * v;
    }
    m /= (float)Gn;
    float var = m2 / (float)Gn - m * m;
    float inv = 1.0f / sqrtf(var + 1e-5f);
    float ga = gam[o], be = bet[o];
    for (int g = 0; g < Gn; g++) {
        float v = (x[g * Odim + o] - m) * inv * ga + be;
        x[g * Odim + o] = fmaxf(v, 0.f);
    }
}

__global__ void head_kernel(const float* __restrict__ fc2, const float* __restrict__ W,
                            const float* __restrict__ b, float* __restrict__ out) {
    int g = blockIdx.x * blockDim.x + threadIdx.x;
    if (g >= G) return;
    float l0 = b[0], l1 = b[1];
    for (int k = 0; k < 64; k++) {
        float v = fc2[g * 64 + k];
        l0 += v * W[k];
        l1 += v * W[64 + k];
    }
    float mx = fmaxf(l0, l1);
    float e0 = expf(l0 - mx), e1 = expf(l1 - mx);
    float s = e0 + e1;
    out[g * 2 + 0] = e0 / s;
    out[g * 2 + 1] = e1 / s;
}

extern "C" void kernel_launch(void* const* d_in, const int* in_sizes, int n_in,
                              void* d_out, int out_size, void* d_ws, size_t ws_size,
                              hipStream_t stream) {
    (void)in_sizes; (void)n_in; (void)out_size; (void)ws_size;

    const float* x      = (const float*)d_in[0];
    const int*   ei     = (const int*)d_in[1];
    const float* Wrel1  = (const float*)d_in[2];
    const float* Wroot1 = (const float*)d_in[3];
    const float* b1     = (const float*)d_in[4];
    const float* Wrel2  = (const float*)d_in[5];
    const float* Wroot2 = (const float*)d_in[6];
    const float* b2     = (const float*)d_in[7];
    const float* Wrel3  = (const float*)d_in[8];
    const float* Wroot3 = (const float*)d_in[9];
    const float* b3     = (const float*)d_in[10];
    const float* pw1    = (const float*)d_in[11];
    const float* pw2    = (const float*)d_in[12];
    const float* pw3    = (const float*)d_in[13];
    const float* lin1w  = (const float*)d_in[14];
    const float* lin1b  = (const float*)d_in[15];
    const float* lin2w  = (const float*)d_in[16];
    const float* lin2b  = (const float*)d_in[17];
    const float* lin3w  = (const float*)d_in[18];
    const float* lin3b  = (const float*)d_in[19];
    const float* bn1g   = (const float*)d_in[20];
    const float* bn1b   = (const float*)d_in[21];
    const float* bn2g   = (const float*)d_in[22];
    const float* bn2b   = (const float*)d_in[23];

    float* bufA  = (float*)d_ws;                  // NT0*H floats
    float* bufB  = bufA + (size_t)NT0 * H;        // NT1*H floats (also agg6 scratch)
    float* score = bufB + (size_t)NT1 * H;        // NT0
    int*   perm  = (int*)(score + NT0);           // NT1 (unused, layout kept)
    int*   inv   = perm + NT1;                    // NT0
    int*   cs    = inv + NT0;                     // NE
    int*   cd    = cs + NE;                       // NE
    float* z     = (float*)(cd + NE);             // G*256
    float* f1    = z + G * 256;                   // G*128
    float* f2    = f1 + G * H;                    // G*64
    int*   rowp  = (int*)(f2 + G * 64);           // G*RPS ints
    unsigned short* col = (unsigned short*)(rowp + G * RPS);   // NE ushorts

    // ---- init ----
    hipMemsetAsync(z, 0, (size_t)G * 256 * sizeof(float), stream);
    init_edges_kernel<<<cdiv(NE, 256), 256, 0, stream>>>(ei, cs, cd);

    // ---- layer 1 ----
    agg6_lds_kernel<<<G, 256, 0, stream>>>(x, ei, (int*)bufB);
    conv1_kernel<<<cdiv(NT0 * 32, 256), 256, 0, stream>>>(x, (const int*)bufB, Wrel1, Wroot1, b1, pw1, bufA, score);
    topk_pool_kernel<<<G, 512, 0, stream>>>(bufA, score, N0, K1, inv, bufB, z);

    // ---- layer 2 ----
    build_csr_kernel<<<G, 256, 0, stream>>>(cs, cd, inv, K1, rowp, col);
    agg_gather_kernel<<<dim3(G, 8), 256, 0, stream>>>(bufB, rowp, col, (int*)bufA, K1);
    conv_gemm_kernel<<<cdiv(NT1, 64), 256, 0, stream>>>((const int*)bufA, bufB, Wrel2, Wroot2, b2, pw2, bufA, score, NT1);
    topk_pool_kernel<<<G, 512, 0, stream>>>(bufA, score, K1, K2, inv, bufB, z);

    // ---- layer 3 ----
    build_csr_kernel<<<G, 256, 0, stream>>>(cs, cd, inv, K2, rowp, col);
    agg_gather_kernel<<<dim3(G, 8), 256, 0, stream>>>(bufB, rowp, col, (int*)bufA, K2);
    conv_gemm_kernel<<<cdiv(NT2, 64), 256, 0, stream>>>((const int*)bufA, bufB, Wrel3, Wroot3, b3, pw3, bufA, score, NT2);
    topk_pool_kernel<<<G, 512, 0, stream>>>(bufA, score, K2, K3, inv, bufB, z);

    // ---- head ----
    fc_kernel<<<cdiv(G * 128, 256), 256, 0, stream>>>(z, lin1w, lin1b, f1, G, 256, 128);
    bn_relu_kernel<<<1, 128, 0, stream>>>(f1, bn1g, bn1b, G, 128);
    fc_kernel<<<cdiv(G * 64, 256), 256, 0, stream>>>(f1, lin2w, lin2b, f2, G, 128, 64);
    bn_relu_kernel<<<1, 64, 0, stream>>>(f2, bn2g, bn2b, G, 64);
    head_kernel<<<1, 256, 0, stream>>>(f2, lin3w, lin3b, (float*)d_out);
}

// Round 11
// 679.820 us; speedup vs baseline: 1.2909x; 1.0265x over previous
//
#include <hip/hip_runtime.h>
#include <math.h>

#define G 200
#define N0 512
#define NE 614400          // G*N0*6
#define EPG 3072           // edges per graph (slot-stable across layers)
#define K1 410
#define K2 328
#define K3 263
#define H 128
#define NT0 102400         // G*N0
#define NT1 82000          // G*K1
#define NT2 65600          // G*K2
#define NT3 52600          // G*K3

// fixed-point scales for deterministic integer aggregation
#define SCALE1 1048576.0f        // 2^20, layer-1 features (|x| <= ~6)
#define INV1   (1.0f / 1048576.0f)
#define SCALE2 262144.0f         // 2^18, layers 2/3 (messages <= ~300, agg <= ~8000)
#define INV2   (1.0f / 262144.0f)

#define DEAD 0xFFFFu
#define RPS (N0 + 1)             // rowptr stride per graph

static inline int cdiv(int a, int b) { return (a + b - 1) / b; }

// ---------------- layer 1 ----------------
// per-graph LDS aggregation of the 6 input features (stride-8 padded rows).
// edges staged once into LDS (ushort2 local ids) -> inner loop is pure LDS.
// int fixed-point LDS atomics -> deterministic. Writes every output element.
__global__ __launch_bounds__(256) void agg6_lds_kernel(
    const float* __restrict__ x, const int* __restrict__ ei, int* __restrict__ agg) {
    __shared__ float xs[N0 * 8];
    __shared__ int   ag[N0 * 8];
    __shared__ ushort2 eloc[EPG];
    const int g = blockIdx.x;
    const int t = threadIdx.x;
    const int base = g * N0;
    const int e0 = g * EPG;
    for (int i = t; i < N0 * 8; i += 256) {
        int m = i >> 3, j = i & 7;
        xs[i] = (j < 6) ? x[(size_t)(base + m) * 6 + j] : 0.f;
        ag[i] = 0;
    }
    for (int i = t; i < EPG; i += 256) {
        eloc[i] = make_ushort2((unsigned short)(ei[e0 + i] - base),
                               (unsigned short)(ei[NE + e0 + i] - base));
    }
    __syncthreads();
    const int sub = t >> 3;   // 32 subgroups of 8 lanes; 32 edges per iteration
    const int f = t & 7;
#pragma unroll 4
    for (int e = sub; e < EPG; e += 32) {
        ushort2 p = eloc[e];
        if (f < 6) {
            float v = xs[p.x * 8 + f];
            atomicAdd(&ag[p.y * 8 + f], __float2int_rn(v * SCALE1));
        }
    }
    __syncthreads();
    for (int i = t; i < N0 * 6; i += 256) {
        int m = i / 6, j = i - m * 6;
        agg[(size_t)(base + m) * 6 + j] = ag[m * 8 + j];
    }
}

// 4 outputs per thread, vectorized loads (W rows for 4 outputs = 24 contiguous
// floats -> 6 float4; x/agg6 via float2/int2). Per-output FMA order identical
// to the scalar version -> bit-exact h. FUSED score via 32-lane shfl reduce.
__global__ void conv1_kernel(const float* __restrict__ x, const int* __restrict__ agg6,
                             const float* __restrict__ Wrel, const float* __restrict__ Wroot,
                             const float* __restrict__ b, const float* __restrict__ pw,
                             float* __restrict__ h, float* __restrict__ score) {
    int idx = blockIdx.x * blockDim.x + threadIdx.x;
    if (idx >= NT0 * 32) return;
    int node = idx >> 5, o4 = (idx & 31) * 4;

    float2 x01 = *(const float2*)(x + (size_t)node * 6);
    float2 x23 = *(const float2*)(x + (size_t)node * 6 + 2);
    float2 x45 = *(const float2*)(x + (size_t)node * 6 + 4);
    int2 g01 = *(const int2*)(agg6 + (size_t)node * 6);
    int2 g23 = *(const int2*)(agg6 + (size_t)node * 6 + 2);
    int2 g45 = *(const int2*)(agg6 + (size_t)node * 6 + 4);
    float xv[6] = {x01.x, x01.y, x23.x, x23.y, x45.x, x45.y};
    float a[6] = {(float)g01.x * INV1, (float)g01.y * INV1,
                  (float)g23.x * INV1, (float)g23.y * INV1,
                  (float)g45.x * INV1, (float)g45.y * INV1};

    float4 wr4[6], wo4[6];
#pragma unroll
    for (int i = 0; i < 6; i++) {
        wr4[i] = *(const float4*)(Wrel + (size_t)o4 * 6 + i * 4);
        wo4[i] = *(const float4*)(Wroot + (size_t)o4 * 6 + i * 4);
    }
    const float* wr = (const float*)wr4;
    const float* wo = (const float*)wo4;
    float4 bb = *(const float4*)(b + o4);
    float4 pwv = *(const float4*)(pw + o4);
    const float* bp = (const float*)&bb;
    const float* pp = (const float*)&pwv;

    float4 r;
    float* rp = (float*)&r;
    float d = 0.f, n2 = 0.f;
#pragma unroll
    for (int j = 0; j < 4; j++) {
        float acc = bp[j];
#pragma unroll
        for (int f = 0; f < 6; f++)
            acc += a[f] * wr[j * 6 + f] + xv[f] * wo[j * 6 + f];
        float hv = fmaxf(acc, 0.f);
        rp[j] = hv;
        float wv = pp[j];
        d = fmaf(hv, wv, d);
        n2 = fmaf(wv, wv, n2);
    }
    *(float4*)(h + (size_t)node * H + o4) = r;
#pragma unroll
    for (int s = 1; s < 32; s <<= 1) {
        d += __shfl_xor(d, s);
        n2 += __shfl_xor(n2, s);
    }
    if ((idx & 31) == 0) score[node] = tanhf(d / sqrtf(n2));
}

// ---------------- FUSED topk + gather/gate + readout ----------------
// one block (512 threads) per graph. Register bitonic sort (descending,
// index-tiebreak); sorted (score,idx) kept in LDS. Then each thread gathers
// h[si[j]]*sv[j] for j = part (mod 4), writes pooled hout, and accumulates
// readout max/sum in the SAME order as the old standalone readout kernel
// -> bit-identical z and pooled h. 4-deep unrolled loads for latency hiding.
__global__ __launch_bounds__(512) void topk_pool_kernel(
    const float* __restrict__ h, const float* __restrict__ score,
    int n, int k, int* __restrict__ inv,
    float* __restrict__ hout, float* __restrict__ z) {
    __shared__ float sv[512];
    __shared__ int si[512];
    __shared__ float smax[4][128];
    __shared__ float ssum[4][128];
    const int g = blockIdx.x;
    const int t = threadIdx.x;
    float v = (t < n) ? score[g * n + t] : -INFINITY;
    int idx = t;
    for (int size = 2; size <= 512; size <<= 1) {
        const bool desc = ((t & size) == 0);
        for (int stride = size >> 1; stride > 0; stride >>= 1) {
            float pv; int pi;
            if (stride >= 64) {
                sv[t] = v; si[t] = idx;
                __syncthreads();
                pv = sv[t ^ stride]; pi = si[t ^ stride];
                __syncthreads();
            } else {
                pv = __shfl_xor(v, stride);
                pi = __shfl_xor(idx, stride);
            }
            const bool left = ((t & stride) == 0);
            const bool want_max = (desc == left);
            const bool A = (v > pv) || (v == pv && idx < pi);
            if (want_max != A) { v = pv; idx = pi; }
        }
    }
    // publish sorted arrays; init inv
    sv[t] = v; si[t] = idx;
    if (t < n) inv[g * n + t] = -1;
    __syncthreads();
    if (t < k) inv[g * n + idx] = g * k + t;

    // gather + gate + readout
    const int f = t & 127;
    const int part = t >> 7;
    const float* hbase = h + (size_t)g * n * H + f;
    float* obase = hout + (size_t)g * k * H + f;
    float mx = -INFINITY, sm = 0.f;
    int j = part;
    for (; j + 12 < k; j += 16) {
        int r0 = si[j], r1 = si[j + 4], r2 = si[j + 8], r3 = si[j + 12];
        float s0 = sv[j], s1 = sv[j + 4], s2 = sv[j + 8], s3 = sv[j + 12];
        float a0 = hbase[(size_t)r0 * H];
        float a1 = hbase[(size_t)r1 * H];
        float a2 = hbase[(size_t)r2 * H];
        float a3 = hbase[(size_t)r3 * H];
        float v0 = a0 * s0, v1 = a1 * s1, v2 = a2 * s2, v3 = a3 * s3;
        obase[(size_t)j * H] = v0;
        obase[(size_t)(j + 4) * H] = v1;
        obase[(size_t)(j + 8) * H] = v2;
        obase[(size_t)(j + 12) * H] = v3;
        mx = fmaxf(mx, v0); sm += v0;
        mx = fmaxf(mx, v1); sm += v1;
        mx = fmaxf(mx, v2); sm += v2;
        mx = fmaxf(mx, v3); sm += v3;
    }
    for (; j < k; j += 4) {
        float vv = hbase[(size_t)si[j] * H] * sv[j];
        obase[(size_t)j * H] = vv;
        mx = fmaxf(mx, vv); sm += vv;
    }
    smax[part][f] = mx;
    ssum[part][f] = sm;
    __syncthreads();
    if (t < 128) {
        float m0 = fmaxf(fmaxf(smax[0][t], smax[1][t]), fmaxf(smax[2][t], smax[3][t]));
        float s0 = (ssum[0][t] + ssum[1][t]) + (ssum[2][t] + ssum[3][t]);
        z[g * 256 + t] += m0;
        z[g * 256 + 128 + t] += s0 / (float)k;
    }
}

// ---------------- CSR build + inline remap (layers 2/3) ----------------
// one block per graph. Reads the source edge list (ei for layer 2, cs/cd for
// layer 3), applies inv inline, writes remapped list to out_s/out_d for the
// next layer. Deterministic rowptr (atomic counts + scan); col placement
// order is scheduling-dependent but consumers sum INTs -> invariant.
__global__ __launch_bounds__(256) void build_csr_kernel(
    const int* __restrict__ src_s, const int* __restrict__ src_d,
    int* __restrict__ out_s, int* __restrict__ out_d,
    const int* __restrict__ inv, int n,
    int* __restrict__ rowptr, unsigned short* __restrict__ col) {
    __shared__ ushort2 eloc[EPG];
    __shared__ int cnt[N0];
    __shared__ int basep[N0];
    __shared__ int wsum[4];
    const int g = blockIdx.x;
    const int t = threadIdx.x;
    const int base = g * n;
    const int e0 = g * EPG;
    for (int i = t; i < n; i += 256) cnt[i] = 0;
    __syncthreads();
    for (int i = t; i < EPG; i += 256) {
        int s = src_s[e0 + i];
        ushort2 p = make_ushort2(DEAD, DEAD);
        if (s >= 0) {
            int ns = inv[s], nd = inv[src_d[e0 + i]];
            if (ns < 0 || nd < 0) {
                out_s[e0 + i] = -1;
            } else {
                out_s[e0 + i] = ns;
                out_d[e0 + i] = nd;
                p = make_ushort2((unsigned short)(ns - base), (unsigned short)(nd - base));
                atomicAdd(&cnt[p.y], 1);
            }
        } else {
            out_s[e0 + i] = -1;
        }
        eloc[i] = p;
    }
    __syncthreads();
    // exclusive scan of cnt[0..n) : 2 elements per thread + shfl wave scan
    const int i0 = 2 * t, i1 = 2 * t + 1;
    const int a = (i0 < n) ? cnt[i0] : 0;
    const int b = (i1 < n) ? cnt[i1] : 0;
    const int p = a + b;
    const int lane = t & 63, w = t >> 6;
    int xv = p;
#pragma unroll
    for (int o = 1; o < 64; o <<= 1) {
        int y = __shfl_up(xv, o);
        if (lane >= o) xv += y;
    }
    if (lane == 63) wsum[w] = xv;
    __syncthreads();
    int woff = 0;
    for (int ww = 0; ww < w; ww++) woff += wsum[ww];
    const int incl = xv + woff;
    const int excl = incl - p;
    if (i0 < n) { basep[i0] = excl;     cnt[i0] = 0; rowptr[g * RPS + i0] = excl; }
    if (i1 < n) { basep[i1] = excl + a; cnt[i1] = 0; rowptr[g * RPS + i1] = excl + a; }
    if (t == 255) rowptr[g * RPS + n] = incl;   // total live edges
    __syncthreads();
    for (int i = t; i < EPG; i += 256) {
        ushort2 pe = eloc[i];
        if (pe.x != DEAD) {
            int pos = basep[pe.y] + atomicAdd(&cnt[pe.y], 1);
            col[e0 + pos] = pe.x;
        }
    }
}

// ---------------- layers 2/3 aggregation: CSR gather, no atomics ----------
// per-(graph, 16-feature-slice). h slice staged pre-quantized to int in LDS;
// each 16-lane subgroup sums its node's neighbors with register int adds,
// 4-way unrolled (4 independent hsq loads in flight; colL reads are
// subgroup-broadcast). Int addition order-invariant -> deterministic.
__global__ __launch_bounds__(256) void agg_gather_kernel(
    const float* __restrict__ h, const int* __restrict__ rowptr,
    const unsigned short* __restrict__ col, int* __restrict__ agg, int n) {
    __shared__ int hsq[K1 * 16];
    __shared__ unsigned short colL[EPG];
    __shared__ int rp[N0 + 1];
    const int g = blockIdx.x;
    const int fq = blockIdx.y * 16;
    const int t = threadIdx.x;
    const int base = g * n;
    const int e0 = g * EPG;
    const int nf4 = n * 4;
    for (int i = t; i < nf4; i += 256) {
        int m = i >> 2, j = (i & 3) * 4;
        float4 v = *(const float4*)(h + (size_t)(base + m) * H + fq + j);
        int4 q;
        q.x = __float2int_rn(v.x * SCALE2);
        q.y = __float2int_rn(v.y * SCALE2);
        q.z = __float2int_rn(v.z * SCALE2);
        q.w = __float2int_rn(v.w * SCALE2);
        *(int4*)(hsq + m * 16 + j) = q;
    }
    {   // stage col as packed uints (coalesced)
        const unsigned int* src = (const unsigned int*)(col + e0);
        unsigned int* dst = (unsigned int*)colL;
        for (int i = t; i < EPG / 2; i += 256) dst[i] = src[i];
    }
    for (int i = t; i <= n; i += 256) rp[i] = rowptr[g * RPS + i];
    __syncthreads();
    const int sub = t >> 4;   // 16 subgroups of 16 lanes
    const int f = t & 15;
    for (int m = sub; m < n; m += 16) {
        int r0 = rp[m], r1 = rp[m + 1];
        int acc = 0;
        int r = r0;
        for (; r + 3 < r1; r += 4) {
            int c0 = colL[r], c1 = colL[r + 1], c2 = colL[r + 2], c3 = colL[r + 3];
            int a0 = hsq[c0 * 16 + f];
            int a1 = hsq[c1 * 16 + f];
            int a2 = hsq[c2 * 16 + f];
            int a3 = hsq[c3 * 16 + f];
            acc += (a0 + a1) + (a2 + a3);
        }
        for (; r < r1; r++) acc += hsq[colL[r] * 16 + f];
        agg[(size_t)(base + m) * H + fq + f] = acc;
    }
}

// out[i][o] = relu( sum_k agg[i][k]*Wrel[o][k] + sum_k hin[i][k]*Wroot[o][k] + b[o] )
// R7-proven config: 64x128 tile, 256 threads, 4x8 micro-tile, o4-split B cols
// (conflict-free), Bs padded 132. FUSED score epilogue: 16 tx-threads hold a
// row's 128 cols -> shfl_xor reduce (fixed order, deterministic).
// agg is int32 fixed-point, converted inline. out aliases agg (in-place safe).
// Per-output K order unchanged (kc asc, kk asc) -> bit-identical h.
__global__ __launch_bounds__(256) void conv_gemm_kernel(
    const int* __restrict__ agg, const float* __restrict__ hin,
    const float* __restrict__ Wrel, const float* __restrict__ Wroot,
    const float* __restrict__ bias, const float* __restrict__ pw,
    float* __restrict__ out, float* __restrict__ score, int M) {
    __shared__ float As[32][68];
    __shared__ float Bs[32][132];
    const int t = threadIdx.x;
    const int row0 = blockIdx.x * 64;
    const int tx = t & 15;
    const int ty = t >> 4;
    const int o4 = tx * 4;       // cols [o4,o4+4) and [64+o4,64+o4+4)
    const int r4 = ty * 4;

    float acc[4][8];
#pragma unroll
    for (int i = 0; i < 4; i++)
#pragma unroll
        for (int j = 0; j < 8; j++) acc[i][j] = 0.f;

#pragma unroll 1
    for (int kc = 0; kc < 256; kc += 32) {
        const float* Wsrc = (kc < 128) ? (Wrel + kc) : (Wroot + (kc - 128));
#pragma unroll
        for (int i = 0; i < 2; i++) {
            int li = t + i * 256;        // 0..511
            int r = li >> 3, q = li & 7; // r 0..63, q 0..7
            int grow = row0 + r;
            float4 v = make_float4(0.f, 0.f, 0.f, 0.f);
            if (grow < M) {
                if (kc < 128) {
                    int4 iv = *(const int4*)(agg + (size_t)grow * H + kc + q * 4);
                    v.x = (float)iv.x * INV2;
                    v.y = (float)iv.y * INV2;
                    v.z = (float)iv.z * INV2;
                    v.w = (float)iv.w * INV2;
                } else {
                    v = *(const float4*)(hin + (size_t)grow * H + (kc - 128) + q * 4);
                }
            }
            As[q * 4 + 0][r] = v.x;
            As[q * 4 + 1][r] = v.y;
            As[q * 4 + 2][r] = v.z;
            As[q * 4 + 3][r] = v.w;
        }
#pragma unroll
        for (int i = 0; i < 4; i++) {
            int li = t + i * 256;
            int o = li >> 3, q = li & 7;
            float4 v = *(const float4*)(Wsrc + (size_t)o * H + q * 4);
            Bs[q * 4 + 0][o] = v.x;
            Bs[q * 4 + 1][o] = v.y;
            Bs[q * 4 + 2][o] = v.z;
            Bs[q * 4 + 3][o] = v.w;
        }
        __syncthreads();
#pragma unroll
        for (int kk = 0; kk < 32; kk++) {
            const float4 a0 = *(const float4*)&As[kk][r4];
            const float4 b0 = *(const float4*)&Bs[kk][o4];
            const float4 b1 = *(const float4*)&Bs[kk][64 + o4];
            float av[4] = {a0.x, a0.y, a0.z, a0.w};
            float bv[8] = {b0.x, b0.y, b0.z, b0.w, b1.x, b1.y, b1.z, b1.w};
#pragma unroll
            for (int ii = 0; ii < 4; ii++)
#pragma unroll
                for (int jj = 0; jj < 8; jj++)
                    acc[ii][jj] = fmaf(av[ii], bv[jj], acc[ii][jj]);
        }
        __syncthreads();
    }

    // fused-score weights for this thread's 8 columns
    float wv[8];
#pragma unroll
    for (int j = 0; j < 4; j++) { wv[j] = pw[o4 + j]; wv[4 + j] = pw[64 + o4 + j]; }
    float n2 = 0.f;
#pragma unroll
    for (int j = 0; j < 8; j++) n2 = fmaf(wv[j], wv[j], n2);
#pragma unroll
    for (int s = 1; s < 16; s <<= 1) n2 += __shfl_xor(n2, s);
    const float rnorm = 1.0f / sqrtf(n2);

#pragma unroll
    for (int ii = 0; ii < 4; ii++) {
        int grow = row0 + r4 + ii;
        float4 o0, o1;
        o0.x = fmaxf(acc[ii][0] + bias[o4 + 0], 0.f);
        o0.y = fmaxf(acc[ii][1] + bias[o4 + 1], 0.f);
        o0.z = fmaxf(acc[ii][2] + bias[o4 + 2], 0.f);
        o0.w = fmaxf(acc[ii][3] + bias[o4 + 3], 0.f);
        o1.x = fmaxf(acc[ii][4] + bias[64 + o4 + 0], 0.f);
        o1.y = fmaxf(acc[ii][5] + bias[64 + o4 + 1], 0.f);
        o1.z = fmaxf(acc[ii][6] + bias[64 + o4 + 2], 0.f);
        o1.w = fmaxf(acc[ii][7] + bias[64 + o4 + 3], 0.f);
        float d = 0.f;
        d = fmaf(o0.x, wv[0], d); d = fmaf(o0.y, wv[1], d);
        d = fmaf(o0.z, wv[2], d); d = fmaf(o0.w, wv[3], d);
        d = fmaf(o1.x, wv[4], d); d = fmaf(o1.y, wv[5], d);
        d = fmaf(o1.z, wv[6], d); d = fmaf(o1.w, wv[7], d);
#pragma unroll
        for (int s = 1; s < 16; s <<= 1) d += __shfl_xor(d, s);
        if (grow < M) {
            *(float4*)(out + (size_t)grow * H + o4) = o0;
            *(float4*)(out + (size_t)grow * H + 64 + o4) = o1;
            if (tx == 0) score[grow] = tanhf(d * rnorm);
        }
    }
}

// ---------------- head ----------------
__global__ void fc_kernel(const float* __restrict__ in, const float* __restrict__ W,
                          const float* __restrict__ b, float* __restrict__ out,
                          int Gn, int Kdim, int Odim) {
    int idx = blockIdx.x * blockDim.x + threadIdx.x;
    if (idx >= Gn * Odim) return;
    int g = idx / Odim, o = idx % Odim;
    float acc = b[o];
    for (int k = 0; k < Kdim; k++) acc += in[g * Kdim + k] * W[o * Kdim + k];
    out[idx] = acc;
}

__global__ void bn_relu_kernel(float* __restrict__ x, const float* __restrict__ gam,
                               const float* __restrict__ bet, int Gn, int Odim) {
    int o = threadIdx.x;
    if (o >= Odim) return;
    float m = 0.f, m2 = 0.f;
    for (int g = 0; g < Gn; g++) {
        float v = x[g * Odim + o];
        m += v;
        m2 += v * v;
    }
    m /= (float)Gn;
    float var = m2 / (float)Gn - m * m;
    float inv = 1.0f / sqrtf(var + 1e-5f);
    float ga = gam[o], be = bet[o];
    for (int g = 0; g < Gn; g++) {
        float v = (x[g * Odim + o] - m) * inv * ga + be;
        x[g * Odim + o] = fmaxf(v, 0.f);
    }
}

__global__ void head_kernel(const float* __restrict__ fc2, const float* __restrict__ W,
                            const float* __restrict__ b, float* __restrict__ out) {
    int g = blockIdx.x * blockDim.x + threadIdx.x;
    if (g >= G) return;
    float l0 = b[0], l1 = b[1];
    for (int k = 0; k < 64; k++) {
        float v = fc2[g * 64 + k];
        l0 += v * W[k];
        l1 += v * W[64 + k];
    }
    float mx = fmaxf(l0, l1);
    float e0 = expf(l0 - mx), e1 = expf(l1 - mx);
    float s = e0 + e1;
    out[g * 2 + 0] = e0 / s;
    out[g * 2 + 1] = e1 / s;
}

extern "C" void kernel_launch(void* const* d_in, const int* in_sizes, int n_in,
                              void* d_out, int out_size, void* d_ws, size_t ws_size,
                              hipStream_t stream) {
    (void)in_sizes; (void)n_in; (void)out_size; (void)ws_size;

    const float* x      = (const float*)d_in[0];
    const int*   ei     = (const int*)d_in[1];
    const float* Wrel1  = (const float*)d_in[2];
    const float* Wroot1 = (const float*)d_in[3];
    const float* b1     = (const float*)d_in[4];
    const float* Wrel2  = (const float*)d_in[5];
    const float* Wroot2 = (const float*)d_in[6];
    const float* b2     = (const float*)d_in[7];
    const float* Wrel3  = (const float*)d_in[8];
    const float* Wroot3 = (const float*)d_in[9];
    const float* b3     = (const float*)d_in[10];
    const float* pw1    = (const float*)d_in[11];
    const float* pw2    = (const float*)d_in[12];
    const float* pw3    = (const float*)d_in[13];
    const float* lin1w  = (const float*)d_in[14];
    const float* lin1b  = (const float*)d_in[15];
    const float* lin2w  = (const float*)d_in[16];
    const float* lin2b  = (const float*)d_in[17];
    const float* lin3w  = (const float*)d_in[18];
    const float* lin3b  = (const float*)d_in[19];
    const float* bn1g   = (const float*)d_in[20];
    const float* bn1b   = (const float*)d_in[21];
    const float* bn2g   = (const float*)d_in[22];
    const float* bn2b   = (const float*)d_in[23];

    float* bufA  = (float*)d_ws;                  // NT0*H floats
    float* bufB  = bufA + (size_t)NT0 * H;        // NT1*H floats (also agg6 scratch)
    float* score = bufB + (size_t)NT1 * H;        // NT0
    int*   perm  = (int*)(score + NT0);           // NT1 (unused, layout kept)
    int*   inv   = perm + NT1;                    // NT0
    int*   cs    = inv + NT0;                     // NE
    int*   cd    = cs + NE;                       // NE
    float* z     = (float*)(cd + NE);             // G*256
    float* f1    = z + G * 256;                   // G*128
    float* f2    = f1 + G * H;                    // G*64
    int*   rowp  = (int*)(f2 + G * 64);           // G*RPS ints
    unsigned short* col = (unsigned short*)(rowp + G * RPS);   // NE ushorts

    // ---- init ----
    hipMemsetAsync(z, 0, (size_t)G * 256 * sizeof(float), stream);

    // ---- layer 1 ----
    agg6_lds_kernel<<<G, 256, 0, stream>>>(x, ei, (int*)bufB);
    conv1_kernel<<<cdiv(NT0 * 32, 256), 256, 0, stream>>>(x, (const int*)bufB, Wrel1, Wroot1, b1, pw1, bufA, score);
    topk_pool_kernel<<<G, 512, 0, stream>>>(bufA, score, N0, K1, inv, bufB, z);

    // ---- layer 2 ----
    build_csr_kernel<<<G, 256, 0, stream>>>(ei, ei + NE, cs, cd, inv, K1, rowp, col);
    agg_gather_kernel<<<dim3(G, 8), 256, 0, stream>>>(bufB, rowp, col, (int*)bufA, K1);
    conv_gemm_kernel<<<cdiv(NT1, 64), 256, 0, stream>>>((const int*)bufA, bufB, Wrel2, Wroot2, b2, pw2, bufA, score, NT1);
    topk_pool_kernel<<<G, 512, 0, stream>>>(bufA, score, K1, K2, inv, bufB, z);

    // ---- layer 3 ----
    build_csr_kernel<<<G, 256, 0, stream>>>(cs, cd, cs, cd, inv, K2, rowp, col);
    agg_gather_kernel<<<dim3(G, 8), 256, 0, stream>>>(bufB, rowp, col, (int*)bufA, K2);
    conv_gemm_kernel<<<cdiv(NT2, 64), 256, 0, stream>>>((const int*)bufA, bufB, Wrel3, Wroot3, b3, pw3, bufA, score, NT2);
    topk_pool_kernel<<<G, 512, 0, stream>>>(bufA, score, K2, K3, inv, bufB, z);

    // ---- head ----
    fc_kernel<<<cdiv(G * 128, 256), 256, 0, stream>>>(z, lin1w, lin1b, f1, G, 256, 128);
    bn_relu_kernel<<<1, 128, 0, stream>>>(f1, bn1g, bn1b, G, 128);
    fc_kernel<<<cdiv(G * 64, 256), 256, 0, stream>>>(f1, lin2w, lin2b, f2, G, 128, 64);
    bn_relu_kernel<<<1, 64, 0, stream>>>(f2, bn2g, bn2b, G, 64);
    head_kernel<<<1, 256, 0, stream>>>(f2, lin3w, lin3b, (float*)d_out);
}

// Round 12
// 495.753 us; speedup vs baseline: 1.7702x; 1.3713x over previous
//
#include <hip/hip_runtime.h>
#include <math.h>

#define G 200
#define N0 512
#define NE 614400          // G*N0*6
#define EPG 3072           // edges per graph (slot-stable across layers)
#define K1 410
#define K2 328
#define K3 263
#define H 128
#define NT0 102400         // G*N0
#define NT1 82000          // G*K1
#define NT2 65600          // G*K2
#define NT3 52600          // G*K3

// fixed-point scales for deterministic integer aggregation
#define SCALE1 1048576.0f        // 2^20, layer-1 features (|x| <= ~6)
#define INV1   (1.0f / 1048576.0f)
#define SCALE2 262144.0f         // 2^18, layers 2/3 (messages <= ~300, agg <= ~8000)
#define INV2   (1.0f / 262144.0f)

#define DEAD 0xFFFFu
#define RPS (N0 + 1)             // rowptr stride per graph

static inline int cdiv(int a, int b) { return (a + b - 1) / b; }

// ---------------- layer 1: FUSED agg6 + conv1 + score ----------------
// one block per graph. Edge-staged int-atomic aggregation (deterministic)
// stays in LDS; conv1 reads agg+x from LDS (no global agg round-trip).
// Per-output FMA order identical to the standalone conv1 -> bit-identical h.
__global__ __launch_bounds__(256) void agg6_conv1_kernel(
    const float* __restrict__ x, const int* __restrict__ ei,
    const float* __restrict__ Wrel, const float* __restrict__ Wroot,
    const float* __restrict__ b, const float* __restrict__ pw,
    float* __restrict__ h, float* __restrict__ score) {
    __shared__ float xs[N0 * 8];
    __shared__ int   ag[N0 * 8];
    __shared__ ushort2 eloc[EPG];
    __shared__ float wrelL[768], wrootL[768], bL[128], pwL[128];
    const int g = blockIdx.x;
    const int t = threadIdx.x;
    const int base = g * N0;
    const int e0 = g * EPG;
    for (int i = t; i < N0 * 8; i += 256) {
        int m = i >> 3, j = i & 7;
        xs[i] = (j < 6) ? x[(size_t)(base + m) * 6 + j] : 0.f;
        ag[i] = 0;
    }
    for (int i = t; i < EPG; i += 256) {
        eloc[i] = make_ushort2((unsigned short)(ei[e0 + i] - base),
                               (unsigned short)(ei[NE + e0 + i] - base));
    }
    for (int i = t; i < 768; i += 256) { wrelL[i] = Wrel[i]; wrootL[i] = Wroot[i]; }
    if (t < 128) { bL[t] = b[t]; pwL[t] = pw[t]; }
    __syncthreads();
    const int sub8 = t >> 3;   // 32 subgroups of 8 lanes
    const int f8 = t & 7;
#pragma unroll 4
    for (int e = sub8; e < EPG; e += 32) {
        ushort2 p = eloc[e];
        if (f8 < 6) {
            float v = xs[p.x * 8 + f8];
            atomicAdd(&ag[p.y * 8 + f8], __float2int_rn(v * SCALE1));
        }
    }
    __syncthreads();
    // conv + score: 8 nodes per round, 32 lanes per node (o4 = lane*4)
    const int nsub = t >> 5;
    const int lane = t & 31;
    const int o4 = lane * 4;
    for (int m = nsub; m < N0; m += 8) {
        float a[6], xv[6];
#pragma unroll
        for (int f = 0; f < 6; f++) {
            a[f] = (float)ag[m * 8 + f] * INV1;
            xv[f] = xs[m * 8 + f];
        }
        float4 r; float* rp = (float*)&r;
        float d = 0.f, n2 = 0.f;
#pragma unroll
        for (int j = 0; j < 4; j++) {
            int o = o4 + j;
            float acc = bL[o];
#pragma unroll
            for (int f = 0; f < 6; f++)
                acc += a[f] * wrelL[o * 6 + f] + xv[f] * wrootL[o * 6 + f];
            float hv = fmaxf(acc, 0.f);
            rp[j] = hv;
            float wv = pwL[o];
            d = fmaf(hv, wv, d);
            n2 = fmaf(wv, wv, n2);
        }
        *(float4*)(h + (size_t)(base + m) * H + o4) = r;
#pragma unroll
        for (int s = 1; s < 32; s <<= 1) {
            d += __shfl_xor(d, s);
            n2 += __shfl_xor(n2, s);
        }
        if (lane == 0) score[base + m] = tanhf(d / sqrtf(n2));
    }
}

// ------- FUSED topk + gather/gate + readout + CSR-build/remap -------
// one block (512 threads) per graph. Register bitonic sort (descending,
// index-tiebreak). Local ranks invL come straight from the sorted order, so
// no global inv array exists. Gather/readout accumulate in the same order as
// before -> bit-identical z and pooled h. CSR phase (do_csr): remap edge
// list via invL, deterministic rowptr (atomic counts + scan), scatter col
// (order nondeterministic; consumers sum ints -> invariant).
__global__ __launch_bounds__(512) void topk_pool_kernel(
    const float* __restrict__ h, const float* __restrict__ score,
    int n, int k, float* __restrict__ hout, float* __restrict__ z, int zstore,
    const int* __restrict__ src_s, const int* __restrict__ src_d,
    int* __restrict__ out_s, int* __restrict__ out_d,
    int* __restrict__ rowptr, unsigned short* __restrict__ col, int do_csr) {
    __shared__ float sv[512];
    __shared__ int si[512];
    __shared__ int invL[512];
    __shared__ float smax[4][128];
    __shared__ float ssum[4][128];
    __shared__ ushort2 eloc[EPG];
    __shared__ int cnt[512];
    __shared__ int basep[512];
    __shared__ int wsum[8];
    const int g = blockIdx.x;
    const int t = threadIdx.x;
    float v = (t < n) ? score[g * n + t] : -INFINITY;
    int idx = t;
    for (int size = 2; size <= 512; size <<= 1) {
        const bool desc = ((t & size) == 0);
        for (int stride = size >> 1; stride > 0; stride >>= 1) {
            float pv; int pi;
            if (stride >= 64) {
                sv[t] = v; si[t] = idx;
                __syncthreads();
                pv = sv[t ^ stride]; pi = si[t ^ stride];
                __syncthreads();
            } else {
                pv = __shfl_xor(v, stride);
                pi = __shfl_xor(idx, stride);
            }
            const bool left = ((t & stride) == 0);
            const bool want_max = (desc == left);
            const bool A = (v > pv) || (v == pv && idx < pi);
            if (want_max != A) { v = pv; idx = pi; }
        }
    }
    sv[t] = v; si[t] = idx; invL[t] = -1;
    __syncthreads();
    if (t < k) invL[idx] = t;     // rank of kept node (idx == si[t] here)

    // gather + gate + readout (reads sv/si only)
    const int f = t & 127;
    const int part = t >> 7;
    const float* hbase = h + (size_t)g * n * H + f;
    float* obase = hout + (size_t)g * k * H + f;
    float mx = -INFINITY, sm = 0.f;
    int j = part;
    for (; j + 12 < k; j += 16) {
        int r0 = si[j], r1 = si[j + 4], r2 = si[j + 8], r3 = si[j + 12];
        float s0 = sv[j], s1 = sv[j + 4], s2 = sv[j + 8], s3 = sv[j + 12];
        float a0 = hbase[(size_t)r0 * H];
        float a1 = hbase[(size_t)r1 * H];
        float a2 = hbase[(size_t)r2 * H];
        float a3 = hbase[(size_t)r3 * H];
        float v0 = a0 * s0, v1 = a1 * s1, v2 = a2 * s2, v3 = a3 * s3;
        obase[(size_t)j * H] = v0;
        obase[(size_t)(j + 4) * H] = v1;
        obase[(size_t)(j + 8) * H] = v2;
        obase[(size_t)(j + 12) * H] = v3;
        mx = fmaxf(mx, v0); sm += v0;
        mx = fmaxf(mx, v1); sm += v1;
        mx = fmaxf(mx, v2); sm += v2;
        mx = fmaxf(mx, v3); sm += v3;
    }
    for (; j < k; j += 4) {
        float vv = hbase[(size_t)si[j] * H] * sv[j];
        obase[(size_t)j * H] = vv;
        mx = fmaxf(mx, vv); sm += vv;
    }
    smax[part][f] = mx;
    ssum[part][f] = sm;
    if (t < n) cnt[t] = 0;
    __syncthreads();
    if (t < 128) {
        float m0 = fmaxf(fmaxf(smax[0][t], smax[1][t]), fmaxf(smax[2][t], smax[3][t]));
        float s0 = (ssum[0][t] + ssum[1][t]) + (ssum[2][t] + ssum[3][t]);
        if (zstore) {
            z[g * 256 + t] = m0;
            z[g * 256 + 128 + t] = s0 / (float)k;
        } else {
            z[g * 256 + t] += m0;
            z[g * 256 + 128 + t] += s0 / (float)k;
        }
    }
    if (!do_csr) return;

    // ---- CSR build + inline remap for the next layer ----
    const int basen = g * n;
    const int gk = g * k;
    const int e0 = g * EPG;
    for (int i = t; i < EPG; i += 512) {
        int s = src_s[e0 + i];
        ushort2 p = make_ushort2(DEAD, DEAD);
        if (s >= 0) {
            int ls = invL[s - basen];
            int ld = invL[src_d[e0 + i] - basen];
            if (ls < 0 || ld < 0) {
                out_s[e0 + i] = -1;
            } else {
                out_s[e0 + i] = gk + ls;
                out_d[e0 + i] = gk + ld;
                p = make_ushort2((unsigned short)ls, (unsigned short)ld);
                atomicAdd(&cnt[ld], 1);
            }
        } else {
            out_s[e0 + i] = -1;
        }
        eloc[i] = p;
    }
    __syncthreads();
    // exclusive scan of cnt[0..n): one element per thread, shfl wave scan
    const int a = (t < n) ? cnt[t] : 0;
    const int lane = t & 63, w = t >> 6;
    int xv = a;
#pragma unroll
    for (int o = 1; o < 64; o <<= 1) {
        int y = __shfl_up(xv, o);
        if (lane >= o) xv += y;
    }
    if (lane == 63) wsum[w] = xv;
    __syncthreads();
    int woff = 0;
    for (int ww = 0; ww < w; ww++) woff += wsum[ww];
    const int incl = xv + woff;
    const int excl = incl - a;
    if (t < n) { basep[t] = excl; cnt[t] = 0; rowptr[g * RPS + t] = excl; }
    if (t == 511) rowptr[g * RPS + n] = incl;   // total live edges
    __syncthreads();
    for (int i = t; i < EPG; i += 512) {
        ushort2 pe = eloc[i];
        if (pe.x != DEAD) {
            int pos = basep[pe.y] + atomicAdd(&cnt[pe.y], 1);
            col[e0 + pos] = pe.x;
        }
    }
}

// ---------------- layers 2/3 aggregation: CSR gather, no atomics ----------
// per-(graph, 16-feature-slice). h slice staged pre-quantized to int in LDS;
// each 16-lane subgroup sums its node's neighbors with register int adds,
// 4-way unrolled. Int addition order-invariant -> deterministic.
__global__ __launch_bounds__(256) void agg_gather_kernel(
    const float* __restrict__ h, const int* __restrict__ rowptr,
    const unsigned short* __restrict__ col, int* __restrict__ agg, int n) {
    __shared__ int hsq[K1 * 16];
    __shared__ unsigned short colL[EPG];
    __shared__ int rp[N0 + 1];
    const int g = blockIdx.x;
    const int fq = blockIdx.y * 16;
    const int t = threadIdx.x;
    const int base = g * n;
    const int e0 = g * EPG;
    const int nf4 = n * 4;
    for (int i = t; i < nf4; i += 256) {
        int m = i >> 2, j = (i & 3) * 4;
        float4 v = *(const float4*)(h + (size_t)(base + m) * H + fq + j);
        int4 q;
        q.x = __float2int_rn(v.x * SCALE2);
        q.y = __float2int_rn(v.y * SCALE2);
        q.z = __float2int_rn(v.z * SCALE2);
        q.w = __float2int_rn(v.w * SCALE2);
        *(int4*)(hsq + m * 16 + j) = q;
    }
    {   // stage col as packed uints (coalesced)
        const unsigned int* src = (const unsigned int*)(col + e0);
        unsigned int* dst = (unsigned int*)colL;
        for (int i = t; i < EPG / 2; i += 256) dst[i] = src[i];
    }
    for (int i = t; i <= n; i += 256) rp[i] = rowptr[g * RPS + i];
    __syncthreads();
    const int sub = t >> 4;   // 16 subgroups of 16 lanes
    const int f = t & 15;
    for (int m = sub; m < n; m += 16) {
        int r0 = rp[m], r1 = rp[m + 1];
        int acc = 0;
        int r = r0;
        for (; r + 3 < r1; r += 4) {
            int c0 = colL[r], c1 = colL[r + 1], c2 = colL[r + 2], c3 = colL[r + 3];
            int a0 = hsq[c0 * 16 + f];
            int a1 = hsq[c1 * 16 + f];
            int a2 = hsq[c2 * 16 + f];
            int a3 = hsq[c3 * 16 + f];
            acc += (a0 + a1) + (a2 + a3);
        }
        for (; r < r1; r++) acc += hsq[colL[r] * 16 + f];
        agg[(size_t)(base + m) * H + fq + f] = acc;
    }
}

// out[i][o] = relu( sum_k agg[i][k]*Wrel[o][k] + sum_k hin[i][k]*Wroot[o][k] + b[o] )
// R7-proven config: 64x128 tile, 256 threads, 4x8 micro-tile, o4-split B cols
// (conflict-free), Bs padded 132. FUSED score epilogue via shfl_xor.
// agg is int32 fixed-point, converted inline. out aliases agg (in-place safe).
// Per-output K order unchanged (kc asc, kk asc) -> bit-identical h.
__global__ __launch_bounds__(256) void conv_gemm_kernel(
    const int* __restrict__ agg, const float* __restrict__ hin,
    const float* __restrict__ Wrel, const float* __restrict__ Wroot,
    const float* __restrict__ bias, const float* __restrict__ pw,
    float* __restrict__ out, float* __restrict__ score, int M) {
    __shared__ float As[32][68];
    __shared__ float Bs[32][132];
    const int t = threadIdx.x;
    const int row0 = blockIdx.x * 64;
    const int tx = t & 15;
    const int ty = t >> 4;
    const int o4 = tx * 4;       // cols [o4,o4+4) and [64+o4,64+o4+4)
    const int r4 = ty * 4;

    float acc[4][8];
#pragma unroll
    for (int i = 0; i < 4; i++)
#pragma unroll
        for (int j = 0; j < 8; j++) acc[i][j] = 0.f;

#pragma unroll 1
    for (int kc = 0; kc < 256; kc += 32) {
        const float* Wsrc = (kc < 128) ? (Wrel + kc) : (Wroot + (kc - 128));
#pragma unroll
        for (int i = 0; i < 2; i++) {
            int li = t + i * 256;        // 0..511
            int r = li >> 3, q = li & 7; // r 0..63, q 0..7
            int grow = row0 + r;
            float4 v = make_float4(0.f, 0.f, 0.f, 0.f);
            if (grow < M) {
                if (kc < 128) {
                    int4 iv = *(const int4*)(agg + (size_t)grow * H + kc + q * 4);
                    v.x = (float)iv.x * INV2;
                    v.y = (float)iv.y * INV2;
                    v.z = (float)iv.z * INV2;
                    v.w = (float)iv.w * INV2;
                } else {
                    v = *(const float4*)(hin + (size_t)grow * H + (kc - 128) + q * 4);
                }
            }
            As[q * 4 + 0][r] = v.x;
            As[q * 4 + 1][r] = v.y;
            As[q * 4 + 2][r] = v.z;
            As[q * 4 + 3][r] = v.w;
        }
#pragma unroll
        for (int i = 0; i < 4; i++) {
            int li = t + i * 256;
            int o = li >> 3, q = li & 7;
            float4 v = *(const float4*)(Wsrc + (size_t)o * H + q * 4);
            Bs[q * 4 + 0][o] = v.x;
            Bs[q * 4 + 1][o] = v.y;
            Bs[q * 4 + 2][o] = v.z;
            Bs[q * 4 + 3][o] = v.w;
        }
        __syncthreads();
#pragma unroll
        for (int kk = 0; kk < 32; kk++) {
            const float4 a0 = *(const float4*)&As[kk][r4];
            const float4 b0 = *(const float4*)&Bs[kk][o4];
            const float4 b1 = *(const float4*)&Bs[kk][64 + o4];
            float av[4] = {a0.x, a0.y, a0.z, a0.w};
            float bv[8] = {b0.x, b0.y, b0.z, b0.w, b1.x, b1.y, b1.z, b1.w};
#pragma unroll
            for (int ii = 0; ii < 4; ii++)
#pragma unroll
                for (int jj = 0; jj < 8; jj++)
                    acc[ii][jj] = fmaf(av[ii], bv[jj], acc[ii][jj]);
        }
        __syncthreads();
    }

    // fused-score weights for this thread's 8 columns
    float wv[8];
#pragma unroll
    for (int j = 0; j < 4; j++) { wv[j] = pw[o4 + j]; wv[4 + j] = pw[64 + o4 + j]; }
    float n2 = 0.f;
#pragma unroll
    for (int j = 0; j < 8; j++) n2 = fmaf(wv[j], wv[j], n2);
#pragma unroll
    for (int s = 1; s < 16; s <<= 1) n2 += __shfl_xor(n2, s);
    const float rnorm = 1.0f / sqrtf(n2);

#pragma unroll
    for (int ii = 0; ii < 4; ii++) {
        int grow = row0 + r4 + ii;
        float4 o0, o1;
        o0.x = fmaxf(acc[ii][0] + bias[o4 + 0], 0.f);
        o0.y = fmaxf(acc[ii][1] + bias[o4 + 1], 0.f);
        o0.z = fmaxf(acc[ii][2] + bias[o4 + 2], 0.f);
        o0.w = fmaxf(acc[ii][3] + bias[o4 + 3], 0.f);
        o1.x = fmaxf(acc[ii][4] + bias[64 + o4 + 0], 0.f);
        o1.y = fmaxf(acc[ii][5] + bias[64 + o4 + 1], 0.f);
        o1.z = fmaxf(acc[ii][6] + bias[64 + o4 + 2], 0.f);
        o1.w = fmaxf(acc[ii][7] + bias[64 + o4 + 3], 0.f);
        float d = 0.f;
        d = fmaf(o0.x, wv[0], d); d = fmaf(o0.y, wv[1], d);
        d = fmaf(o0.z, wv[2], d); d = fmaf(o0.w, wv[3], d);
        d = fmaf(o1.x, wv[4], d); d = fmaf(o1.y, wv[5], d);
        d = fmaf(o1.z, wv[6], d); d = fmaf(o1.w, wv[7], d);
#pragma unroll
        for (int s = 1; s < 16; s <<= 1) d += __shfl_xor(d, s);
        if (grow < M) {
            *(float4*)(out + (size_t)grow * H + o4) = o0;
            *(float4*)(out + (size_t)grow * H + 64 + o4) = o1;
            if (tx == 0) score[grow] = tanhf(d * rnorm);
        }
    }
}

// ---------------- head: FUSED fc + batchnorm + relu ----------------
// one block per output column o. Thread t<G computes the fc dot for sample t
// (k ascending, same order as before); BN stats via fixed LDS tree
// (deterministic). out[t*Odim + o] = relu(bn(v)).
__global__ __launch_bounds__(256) void fc_bn_kernel(
    const float* __restrict__ in, const float* __restrict__ W,
    const float* __restrict__ bias, const float* __restrict__ gam,
    const float* __restrict__ bet, float* __restrict__ out, int Kdim, int Odim) {
    __shared__ float wL[256];
    __shared__ float red[256];
    const int o = blockIdx.x;
    const int t = threadIdx.x;
    for (int i = t; i < Kdim; i += 256) wL[i] = W[(size_t)o * Kdim + i];
    __syncthreads();
    float v = 0.f;
    if (t < G) {
        v = bias[o];
        const float* row = in + (size_t)t * Kdim;
        for (int kk = 0; kk < Kdim; kk++) v += row[kk] * wL[kk];
    }
    red[t] = (t < G) ? v : 0.f;
    __syncthreads();
    for (int s = 128; s > 0; s >>= 1) {
        if (t < s) red[t] += red[t + s];
        __syncthreads();
    }
    float m = red[0] / (float)G;
    __syncthreads();
    red[t] = (t < G) ? v * v : 0.f;
    __syncthreads();
    for (int s = 128; s > 0; s >>= 1) {
        if (t < s) red[t] += red[t + s];
        __syncthreads();
    }
    float var = red[0] / (float)G - m * m;
    float invs = 1.0f / sqrtf(var + 1e-5f);
    if (t < G) out[(size_t)t * Odim + o] = fmaxf((v - m) * invs * gam[o] + bet[o], 0.f);
}

__global__ void head_kernel(const float* __restrict__ fc2, const float* __restrict__ W,
                            const float* __restrict__ b, float* __restrict__ out) {
    int g = blockIdx.x * blockDim.x + threadIdx.x;
    if (g >= G) return;
    float l0 = b[0], l1 = b[1];
    for (int k = 0; k < 64; k++) {
        float v = fc2[g * 64 + k];
        l0 += v * W[k];
        l1 += v * W[64 + k];
    }
    float mx = fmaxf(l0, l1);
    float e0 = expf(l0 - mx), e1 = expf(l1 - mx);
    float s = e0 + e1;
    out[g * 2 + 0] = e0 / s;
    out[g * 2 + 1] = e1 / s;
}

extern "C" void kernel_launch(void* const* d_in, const int* in_sizes, int n_in,
                              void* d_out, int out_size, void* d_ws, size_t ws_size,
                              hipStream_t stream) {
    (void)in_sizes; (void)n_in; (void)out_size; (void)ws_size;

    const float* x      = (const float*)d_in[0];
    const int*   ei     = (const int*)d_in[1];
    const float* Wrel1  = (const float*)d_in[2];
    const float* Wroot1 = (const float*)d_in[3];
    const float* b1     = (const float*)d_in[4];
    const float* Wrel2  = (const float*)d_in[5];
    const float* Wroot2 = (const float*)d_in[6];
    const float* b2     = (const float*)d_in[7];
    const float* Wrel3  = (const float*)d_in[8];
    const float* Wroot3 = (const float*)d_in[9];
    const float* b3     = (const float*)d_in[10];
    const float* pw1    = (const float*)d_in[11];
    const float* pw2    = (const float*)d_in[12];
    const float* pw3    = (const float*)d_in[13];
    const float* lin1w  = (const float*)d_in[14];
    const float* lin1b  = (const float*)d_in[15];
    const float* lin2w  = (const float*)d_in[16];
    const float* lin2b  = (const float*)d_in[17];
    const float* lin3w  = (const float*)d_in[18];
    const float* lin3b  = (const float*)d_in[19];
    const float* bn1g   = (const float*)d_in[20];
    const float* bn1b   = (const float*)d_in[21];
    const float* bn2g   = (const float*)d_in[22];
    const float* bn2b   = (const float*)d_in[23];

    float* bufA  = (float*)d_ws;                  // NT0*H floats
    float* bufB  = bufA + (size_t)NT0 * H;        // NT1*H floats
    float* score = bufB + (size_t)NT1 * H;        // NT0
    int*   cs    = (int*)(score + NT0);           // NE
    int*   cd    = cs + NE;                       // NE
    float* z     = (float*)(cd + NE);             // G*256
    float* f1    = z + G * 256;                   // G*128
    float* f2    = f1 + G * H;                    // G*64
    int*   rowp  = (int*)(f2 + G * 64);           // G*RPS ints
    unsigned short* col = (unsigned short*)(rowp + G * RPS);   // NE ushorts

    // ---- layer 1 ----
    agg6_conv1_kernel<<<G, 256, 0, stream>>>(x, ei, Wrel1, Wroot1, b1, pw1, bufA, score);
    topk_pool_kernel<<<G, 512, 0, stream>>>(bufA, score, N0, K1, bufB, z, 1,
                                            ei, ei + NE, cs, cd, rowp, col, 1);

    // ---- layer 2 ----
    agg_gather_kernel<<<dim3(G, 8), 256, 0, stream>>>(bufB, rowp, col, (int*)bufA, K1);
    conv_gemm_kernel<<<cdiv(NT1, 64), 256, 0, stream>>>((const int*)bufA, bufB, Wrel2, Wroot2, b2, pw2, bufA, score, NT1);
    topk_pool_kernel<<<G, 512, 0, stream>>>(bufA, score, K1, K2, bufB, z, 0,
                                            cs, cd, cs, cd, rowp, col, 1);

    // ---- layer 3 ----
    agg_gather_kernel<<<dim3(G, 8), 256, 0, stream>>>(bufB, rowp, col, (int*)bufA, K2);
    conv_gemm_kernel<<<cdiv(NT2, 64), 256, 0, stream>>>((const int*)bufA, bufB, Wrel3, Wroot3, b3, pw3, bufA, score, NT2);
    topk_pool_kernel<<<G, 512, 0, stream>>>(bufA, score, K2, K3, bufB, z, 0,
                                            cs, cd, cs, cd, rowp, col, 0);

    // ---- head ----
    fc_bn_kernel<<<128, 256, 0, stream>>>(z, lin1w, lin1b, bn1g, bn1b, f1, 256, 128);
    fc_bn_kernel<<<64, 256, 0, stream>>>(f1, lin2w, lin2b, bn2g, bn2b, f2, 128, 64);
    head_kernel<<<1, 256, 0, stream>>>(f2, lin3w, lin3b, (float*)d_out);
}

// Round 13
// 486.025 us; speedup vs baseline: 1.8056x; 1.0200x over previous
//
#include <hip/hip_runtime.h>
#include <math.h>

#define G 200
#define N0 512
#define NE 614400          // G*N0*6
#define EPG 3072           // edges per graph (slot-stable across layers)
#define K1 410
#define K2 328
#define K3 263
#define H 128
#define NT0 102400         // G*N0
#define NT1 82000          // G*K1
#define NT2 65600          // G*K2
#define NT3 52600          // G*K3

// fixed-point scales for deterministic integer aggregation
#define SCALE1 1048576.0f        // 2^20, layer-1 features (|x| <= ~6)
#define INV1   (1.0f / 1048576.0f)
#define SCALE2 262144.0f         // 2^18, layers 2/3 (messages <= ~300, agg <= ~8000)
#define INV2   (1.0f / 262144.0f)

#define DEAD 0xFFFFu
#define RPS (N0 + 1)             // rowptr stride per graph

static inline int cdiv(int a, int b) { return (a + b - 1) / b; }

// ---------------- layer 1: FUSED agg6 + conv1 + score ----------------
// one block per graph. Edge-staged int-atomic aggregation (deterministic)
// stays in LDS; conv1 reads agg+x from LDS (no global agg round-trip).
// Per-output FMA order identical to the standalone conv1 -> bit-identical h.
__global__ __launch_bounds__(256) void agg6_conv1_kernel(
    const float* __restrict__ x, const int* __restrict__ ei,
    const float* __restrict__ Wrel, const float* __restrict__ Wroot,
    const float* __restrict__ b, const float* __restrict__ pw,
    float* __restrict__ h, float* __restrict__ score) {
    __shared__ float xs[N0 * 8];
    __shared__ int   ag[N0 * 8];
    __shared__ ushort2 eloc[EPG];
    __shared__ float wrelL[768], wrootL[768], bL[128], pwL[128];
    const int g = blockIdx.x;
    const int t = threadIdx.x;
    const int base = g * N0;
    const int e0 = g * EPG;
    for (int i = t; i < N0 * 8; i += 256) {
        int m = i >> 3, j = i & 7;
        xs[i] = (j < 6) ? x[(size_t)(base + m) * 6 + j] : 0.f;
        ag[i] = 0;
    }
    for (int i = t; i < EPG; i += 256) {
        eloc[i] = make_ushort2((unsigned short)(ei[e0 + i] - base),
                               (unsigned short)(ei[NE + e0 + i] - base));
    }
    for (int i = t; i < 768; i += 256) { wrelL[i] = Wrel[i]; wrootL[i] = Wroot[i]; }
    if (t < 128) { bL[t] = b[t]; pwL[t] = pw[t]; }
    __syncthreads();
    const int sub8 = t >> 3;   // 32 subgroups of 8 lanes
    const int f8 = t & 7;
#pragma unroll 4
    for (int e = sub8; e < EPG; e += 32) {
        ushort2 p = eloc[e];
        if (f8 < 6) {
            float v = xs[p.x * 8 + f8];
            atomicAdd(&ag[p.y * 8 + f8], __float2int_rn(v * SCALE1));
        }
    }
    __syncthreads();
    // conv + score: 8 nodes per round, 32 lanes per node (o4 = lane*4)
    const int nsub = t >> 5;
    const int lane = t & 31;
    const int o4 = lane * 4;
    for (int m = nsub; m < N0; m += 8) {
        float a[6], xv[6];
#pragma unroll
        for (int f = 0; f < 6; f++) {
            a[f] = (float)ag[m * 8 + f] * INV1;
            xv[f] = xs[m * 8 + f];
        }
        float4 r; float* rp = (float*)&r;
        float d = 0.f, n2 = 0.f;
#pragma unroll
        for (int j = 0; j < 4; j++) {
            int o = o4 + j;
            float acc = bL[o];
#pragma unroll
            for (int f = 0; f < 6; f++)
                acc += a[f] * wrelL[o * 6 + f] + xv[f] * wrootL[o * 6 + f];
            float hv = fmaxf(acc, 0.f);
            rp[j] = hv;
            float wv = pwL[o];
            d = fmaf(hv, wv, d);
            n2 = fmaf(wv, wv, n2);
        }
        *(float4*)(h + (size_t)(base + m) * H + o4) = r;
#pragma unroll
        for (int s = 1; s < 32; s <<= 1) {
            d += __shfl_xor(d, s);
            n2 += __shfl_xor(n2, s);
        }
        if (lane == 0) score[base + m] = tanhf(d / sqrtf(n2));
    }
}

// ------- FUSED topk + gather/gate + readout + CSR-build/remap -------
// one block (512 threads) per graph. Register bitonic sort (descending,
// index-tiebreak). Local ranks invL come straight from the sorted order, so
// no global inv array exists. Gather/readout accumulate in the same order as
// before -> bit-identical z and pooled h. CSR phase (do_csr): remap edge
// list via invL, deterministic rowptr (atomic counts + scan), scatter col
// (order nondeterministic; consumers sum ints -> invariant).
__global__ __launch_bounds__(512) void topk_pool_kernel(
    const float* __restrict__ h, const float* __restrict__ score,
    int n, int k, float* __restrict__ hout, float* __restrict__ z, int zstore,
    const int* __restrict__ src_s, const int* __restrict__ src_d,
    int* __restrict__ out_s, int* __restrict__ out_d,
    int* __restrict__ rowptr, unsigned short* __restrict__ col, int do_csr) {
    __shared__ float sv[512];
    __shared__ int si[512];
    __shared__ int invL[512];
    __shared__ float smax[4][128];
    __shared__ float ssum[4][128];
    __shared__ ushort2 eloc[EPG];
    __shared__ int cnt[512];
    __shared__ int basep[512];
    __shared__ int wsum[8];
    const int g = blockIdx.x;
    const int t = threadIdx.x;
    float v = (t < n) ? score[g * n + t] : -INFINITY;
    int idx = t;
    for (int size = 2; size <= 512; size <<= 1) {
        const bool desc = ((t & size) == 0);
        for (int stride = size >> 1; stride > 0; stride >>= 1) {
            float pv; int pi;
            if (stride >= 64) {
                sv[t] = v; si[t] = idx;
                __syncthreads();
                pv = sv[t ^ stride]; pi = si[t ^ stride];
                __syncthreads();
            } else {
                pv = __shfl_xor(v, stride);
                pi = __shfl_xor(idx, stride);
            }
            const bool left = ((t & stride) == 0);
            const bool want_max = (desc == left);
            const bool A = (v > pv) || (v == pv && idx < pi);
            if (want_max != A) { v = pv; idx = pi; }
        }
    }
    sv[t] = v; si[t] = idx; invL[t] = -1;
    __syncthreads();
    if (t < k) invL[idx] = t;     // rank of kept node (idx == si[t] here)

    // gather + gate + readout (reads sv/si only)
    const int f = t & 127;
    const int part = t >> 7;
    const float* hbase = h + (size_t)g * n * H + f;
    float* obase = hout + (size_t)g * k * H + f;
    float mx = -INFINITY, sm = 0.f;
    int j = part;
    for (; j + 12 < k; j += 16) {
        int r0 = si[j], r1 = si[j + 4], r2 = si[j + 8], r3 = si[j + 12];
        float s0 = sv[j], s1 = sv[j + 4], s2 = sv[j + 8], s3 = sv[j + 12];
        float a0 = hbase[(size_t)r0 * H];
        float a1 = hbase[(size_t)r1 * H];
        float a2 = hbase[(size_t)r2 * H];
        float a3 = hbase[(size_t)r3 * H];
        float v0 = a0 * s0, v1 = a1 * s1, v2 = a2 * s2, v3 = a3 * s3;
        obase[(size_t)j * H] = v0;
        obase[(size_t)(j + 4) * H] = v1;
        obase[(size_t)(j + 8) * H] = v2;
        obase[(size_t)(j + 12) * H] = v3;
        mx = fmaxf(mx, v0); sm += v0;
        mx = fmaxf(mx, v1); sm += v1;
        mx = fmaxf(mx, v2); sm += v2;
        mx = fmaxf(mx, v3); sm += v3;
    }
    for (; j < k; j += 4) {
        float vv = hbase[(size_t)si[j] * H] * sv[j];
        obase[(size_t)j * H] = vv;
        mx = fmaxf(mx, vv); sm += vv;
    }
    smax[part][f] = mx;
    ssum[part][f] = sm;
    if (t < n) cnt[t] = 0;
    __syncthreads();
    if (t < 128) {
        float m0 = fmaxf(fmaxf(smax[0][t], smax[1][t]), fmaxf(smax[2][t], smax[3][t]));
        float s0 = (ssum[0][t] + ssum[1][t]) + (ssum[2][t] + ssum[3][t]);
        if (zstore) {
            z[g * 256 + t] = m0;
            z[g * 256 + 128 + t] = s0 / (float)k;
        } else {
            z[g * 256 + t] += m0;
            z[g * 256 + 128 + t] += s0 / (float)k;
        }
    }
    if (!do_csr) return;

    // ---- CSR build + inline remap for the next layer ----
    const int basen = g * n;
    const int gk = g * k;
    const int e0 = g * EPG;
    for (int i = t; i < EPG; i += 512) {
        int s = src_s[e0 + i];
        ushort2 p = make_ushort2(DEAD, DEAD);
        if (s >= 0) {
            int ls = invL[s - basen];
            int ld = invL[src_d[e0 + i] - basen];
            if (ls < 0 || ld < 0) {
                out_s[e0 + i] = -1;
            } else {
                out_s[e0 + i] = gk + ls;
                out_d[e0 + i] = gk + ld;
                p = make_ushort2((unsigned short)ls, (unsigned short)ld);
                atomicAdd(&cnt[ld], 1);
            }
        } else {
            out_s[e0 + i] = -1;
        }
        eloc[i] = p;
    }
    __syncthreads();
    // exclusive scan of cnt[0..n): one element per thread, shfl wave scan
    const int a = (t < n) ? cnt[t] : 0;
    const int lane = t & 63, w = t >> 6;
    int xv = a;
#pragma unroll
    for (int o = 1; o < 64; o <<= 1) {
        int y = __shfl_up(xv, o);
        if (lane >= o) xv += y;
    }
    if (lane == 63) wsum[w] = xv;
    __syncthreads();
    int woff = 0;
    for (int ww = 0; ww < w; ww++) woff += wsum[ww];
    const int incl = xv + woff;
    const int excl = incl - a;
    if (t < n) { basep[t] = excl; cnt[t] = 0; rowptr[g * RPS + t] = excl; }
    if (t == 511) rowptr[g * RPS + n] = incl;   // total live edges
    __syncthreads();
    for (int i = t; i < EPG; i += 512) {
        ushort2 pe = eloc[i];
        if (pe.x != DEAD) {
            int pos = basep[pe.y] + atomicAdd(&cnt[pe.y], 1);
            col[e0 + pos] = pe.x;
        }
    }
}

// ---------------- layers 2/3 aggregation: CSR gather, no atomics ----------
// per-(graph, 16-feature-slice), 512 threads (32 subgroups of 16 lanes) for
// latency hiding. h slice staged pre-quantized to int in LDS; each subgroup
// sums its node's neighbors with register int adds, 4-way unrolled.
// Int addition order-invariant -> deterministic.
__global__ __launch_bounds__(512) void agg_gather_kernel(
    const float* __restrict__ h, const int* __restrict__ rowptr,
    const unsigned short* __restrict__ col, int* __restrict__ agg, int n) {
    __shared__ int hsq[K1 * 16];
    __shared__ unsigned short colL[EPG];
    __shared__ int rp[N0 + 1];
    const int g = blockIdx.x;
    const int fq = blockIdx.y * 16;
    const int t = threadIdx.x;
    const int base = g * n;
    const int e0 = g * EPG;
    const int nf4 = n * 4;
    for (int i = t; i < nf4; i += 512) {
        int m = i >> 2, j = (i & 3) * 4;
        float4 v = *(const float4*)(h + (size_t)(base + m) * H + fq + j);
        int4 q;
        q.x = __float2int_rn(v.x * SCALE2);
        q.y = __float2int_rn(v.y * SCALE2);
        q.z = __float2int_rn(v.z * SCALE2);
        q.w = __float2int_rn(v.w * SCALE2);
        *(int4*)(hsq + m * 16 + j) = q;
    }
    {   // stage col as packed uints (coalesced)
        const unsigned int* src = (const unsigned int*)(col + e0);
        unsigned int* dst = (unsigned int*)colL;
        for (int i = t; i < EPG / 2; i += 512) dst[i] = src[i];
    }
    for (int i = t; i <= n; i += 512) rp[i] = rowptr[g * RPS + i];
    __syncthreads();
    const int sub = t >> 4;   // 32 subgroups of 16 lanes
    const int f = t & 15;
    for (int m = sub; m < n; m += 32) {
        int r0 = rp[m], r1 = rp[m + 1];
        int acc = 0;
        int r = r0;
        for (; r + 3 < r1; r += 4) {
            int c0 = colL[r], c1 = colL[r + 1], c2 = colL[r + 2], c3 = colL[r + 3];
            int a0 = hsq[c0 * 16 + f];
            int a1 = hsq[c1 * 16 + f];
            int a2 = hsq[c2 * 16 + f];
            int a3 = hsq[c3 * 16 + f];
            acc += (a0 + a1) + (a2 + a3);
        }
        for (; r < r1; r++) acc += hsq[colL[r] * 16 + f];
        agg[(size_t)(base + m) * H + fq + f] = acc;
    }
}

// out[i][o] = relu( sum_k agg[i][k]*Wrel[o][k] + sum_k hin[i][k]*Wroot[o][k] + b[o] )
// 64x128 tile, 256 threads, 4x8 micro-tile, o4-split B cols (conflict-free),
// Bs padded 132. REGISTER PREFETCH: chunk kc+1's global loads are issued
// right after the barrier and consumed only at the next LDS-write, so the
// 32-kk compute shadows the global latency (loads kept as raw int4; convert
// at write). Per-output K order unchanged (kc asc, kk asc) -> bit-identical.
// FUSED score epilogue via shfl_xor. out aliases agg (in-place safe).
__global__ __launch_bounds__(256) void conv_gemm_kernel(
    const int* __restrict__ agg, const float* __restrict__ hin,
    const float* __restrict__ Wrel, const float* __restrict__ Wroot,
    const float* __restrict__ bias, const float* __restrict__ pw,
    float* __restrict__ out, float* __restrict__ score, int M) {
    __shared__ float As[32][68];
    __shared__ float Bs[32][132];
    const int t = threadIdx.x;
    const int row0 = blockIdx.x * 64;
    const int tx = t & 15;
    const int ty = t >> 4;
    const int o4 = tx * 4;       // cols [o4,o4+4) and [64+o4,64+o4+4)
    const int r4 = ty * 4;

    float acc[4][8];
#pragma unroll
    for (int i = 0; i < 4; i++)
#pragma unroll
        for (int j = 0; j < 8; j++) acc[i][j] = 0.f;

    int4 ra[2];
    float4 rb[4];

    auto load_chunk = [&](int kc) {
#pragma unroll
        for (int i = 0; i < 2; i++) {
            int li = t + i * 256;
            int r = li >> 3, q = li & 7;
            int grow = row0 + r;
            int4 v = make_int4(0, 0, 0, 0);
            if (grow < M) {
                if (kc < 128) v = *(const int4*)(agg + (size_t)grow * H + kc + q * 4);
                else          v = *(const int4*)((const int*)hin + (size_t)grow * H + (kc - 128) + q * 4);
            }
            ra[i] = v;
        }
        const float* Wsrc = (kc < 128) ? (Wrel + kc) : (Wroot + (kc - 128));
#pragma unroll
        for (int i = 0; i < 4; i++) {
            int li = t + i * 256;
            int o = li >> 3, q = li & 7;
            rb[i] = *(const float4*)(Wsrc + (size_t)o * H + q * 4);
        }
    };

    load_chunk(0);

#pragma unroll 1
    for (int kc = 0; kc < 256; kc += 32) {
        // write prefetched chunk kc to LDS (convert ints here)
#pragma unroll
        for (int i = 0; i < 2; i++) {
            int li = t + i * 256;
            int r = li >> 3;
            int q = li & 7;
            float4 v;
            if (kc < 128) {
                v.x = (float)ra[i].x * INV2;
                v.y = (float)ra[i].y * INV2;
                v.z = (float)ra[i].z * INV2;
                v.w = (float)ra[i].w * INV2;
            } else {
                v = *(float4*)&ra[i];
            }
            As[q * 4 + 0][r] = v.x;
            As[q * 4 + 1][r] = v.y;
            As[q * 4 + 2][r] = v.z;
            As[q * 4 + 3][r] = v.w;
        }
#pragma unroll
        for (int i = 0; i < 4; i++) {
            int li = t + i * 256;
            int o = li >> 3, q = li & 7;
            Bs[q * 4 + 0][o] = rb[i].x;
            Bs[q * 4 + 1][o] = rb[i].y;
            Bs[q * 4 + 2][o] = rb[i].z;
            Bs[q * 4 + 3][o] = rb[i].w;
        }
        __syncthreads();
        if (kc + 32 < 256) load_chunk(kc + 32);   // loads overlap the compute below
#pragma unroll
        for (int kk = 0; kk < 32; kk++) {
            const float4 a0 = *(const float4*)&As[kk][r4];
            const float4 b0 = *(const float4*)&Bs[kk][o4];
            const float4 b1 = *(const float4*)&Bs[kk][64 + o4];
            float av[4] = {a0.x, a0.y, a0.z, a0.w};
            float bv[8] = {b0.x, b0.y, b0.z, b0.w, b1.x, b1.y, b1.z, b1.w};
#pragma unroll
            for (int ii = 0; ii < 4; ii++)
#pragma unroll
                for (int jj = 0; jj < 8; jj++)
                    acc[ii][jj] = fmaf(av[ii], bv[jj], acc[ii][jj]);
        }
        __syncthreads();
    }

    // fused-score weights for this thread's 8 columns
    float wv[8];
#pragma unroll
    for (int j = 0; j < 4; j++) { wv[j] = pw[o4 + j]; wv[4 + j] = pw[64 + o4 + j]; }
    float n2 = 0.f;
#pragma unroll
    for (int j = 0; j < 8; j++) n2 = fmaf(wv[j], wv[j], n2);
#pragma unroll
    for (int s = 1; s < 16; s <<= 1) n2 += __shfl_xor(n2, s);
    const float rnorm = 1.0f / sqrtf(n2);

#pragma unroll
    for (int ii = 0; ii < 4; ii++) {
        int grow = row0 + r4 + ii;
        float4 o0, o1;
        o0.x = fmaxf(acc[ii][0] + bias[o4 + 0], 0.f);
        o0.y = fmaxf(acc[ii][1] + bias[o4 + 1], 0.f);
        o0.z = fmaxf(acc[ii][2] + bias[o4 + 2], 0.f);
        o0.w = fmaxf(acc[ii][3] + bias[o4 + 3], 0.f);
        o1.x = fmaxf(acc[ii][4] + bias[64 + o4 + 0], 0.f);
        o1.y = fmaxf(acc[ii][5] + bias[64 + o4 + 1], 0.f);
        o1.z = fmaxf(acc[ii][6] + bias[64 + o4 + 2], 0.f);
        o1.w = fmaxf(acc[ii][7] + bias[64 + o4 + 3], 0.f);
        float d = 0.f;
        d = fmaf(o0.x, wv[0], d); d = fmaf(o0.y, wv[1], d);
        d = fmaf(o0.z, wv[2], d); d = fmaf(o0.w, wv[3], d);
        d = fmaf(o1.x, wv[4], d); d = fmaf(o1.y, wv[5], d);
        d = fmaf(o1.z, wv[6], d); d = fmaf(o1.w, wv[7], d);
#pragma unroll
        for (int s = 1; s < 16; s <<= 1) d += __shfl_xor(d, s);
        if (grow < M) {
            *(float4*)(out + (size_t)grow * H + o4) = o0;
            *(float4*)(out + (size_t)grow * H + 64 + o4) = o1;
            if (tx == 0) score[grow] = tanhf(d * rnorm);
        }
    }
}

// ---------------- head: FUSED fc + batchnorm + relu ----------------
// one block per output column o. Thread t<G computes the fc dot for sample t
// (k ascending, same order as before); BN stats via fixed LDS tree
// (deterministic). out[t*Odim + o] = relu(bn(v)).
__global__ __launch_bounds__(256) void fc_bn_kernel(
    const float* __restrict__ in, const float* __restrict__ W,
    const float* __restrict__ bias, const float* __restrict__ gam,
    const float* __restrict__ bet, float* __restrict__ out, int Kdim, int Odim) {
    __shared__ float wL[256];
    __shared__ float red[256];
    const int o = blockIdx.x;
    const int t = threadIdx.x;
    for (int i = t; i < Kdim; i += 256) wL[i] = W[(size_t)o * Kdim + i];
    __syncthreads();
    float v = 0.f;
    if (t < G) {
        v = bias[o];
        const float* row = in + (size_t)t * Kdim;
        for (int kk = 0; kk < Kdim; kk++) v += row[kk] * wL[kk];
    }
    red[t] = (t < G) ? v : 0.f;
    __syncthreads();
    for (int s = 128; s > 0; s >>= 1) {
        if (t < s) red[t] += red[t + s];
        __syncthreads();
    }
    float m = red[0] / (float)G;
    __syncthreads();
    red[t] = (t < G) ? v * v : 0.f;
    __syncthreads();
    for (int s = 128; s > 0; s >>= 1) {
        if (t < s) red[t] += red[t + s];
        __syncthreads();
    }
    float var = red[0] / (float)G - m * m;
    float invs = 1.0f / sqrtf(var + 1e-5f);
    if (t < G) out[(size_t)t * Odim + o] = fmaxf((v - m) * invs * gam[o] + bet[o], 0.f);
}

__global__ void head_kernel(const float* __restrict__ fc2, const float* __restrict__ W,
                            const float* __restrict__ b, float* __restrict__ out) {
    int g = blockIdx.x * blockDim.x + threadIdx.x;
    if (g >= G) return;
    float l0 = b[0], l1 = b[1];
    for (int k = 0; k < 64; k++) {
        float v = fc2[g * 64 + k];
        l0 += v * W[k];
        l1 += v * W[64 + k];
    }
    float mx = fmaxf(l0, l1);
    float e0 = expf(l0 - mx), e1 = expf(l1 - mx);
    float s = e0 + e1;
    out[g * 2 + 0] = e0 / s;
    out[g * 2 + 1] = e1 / s;
}

extern "C" void kernel_launch(void* const* d_in, const int* in_sizes, int n_in,
                              void* d_out, int out_size, void* d_ws, size_t ws_size,
                              hipStream_t stream) {
    (void)in_sizes; (void)n_in; (void)out_size; (void)ws_size;

    const float* x      = (const float*)d_in[0];
    const int*   ei     = (const int*)d_in[1];
    const float* Wrel1  = (const float*)d_in[2];
    const float* Wroot1 = (const float*)d_in[3];
    const float* b1     = (const float*)d_in[4];
    const float* Wrel2  = (const float*)d_in[5];
    const float* Wroot2 = (const float*)d_in[6];
    const float* b2     = (const float*)d_in[7];
    const float* Wrel3  = (const float*)d_in[8];
    const float* Wroot3 = (const float*)d_in[9];
    const float* b3     = (const float*)d_in[10];
    const float* pw1    = (const float*)d_in[11];
    const float* pw2    = (const float*)d_in[12];
    const float* pw3    = (const float*)d_in[13];
    const float* lin1w  = (const float*)d_in[14];
    const float* lin1b  = (const float*)d_in[15];
    const float* lin2w  = (const float*)d_in[16];
    const float* lin2b  = (const float*)d_in[17];
    const float* lin3w  = (const float*)d_in[18];
    const float* lin3b  = (const float*)d_in[19];
    const float* bn1g   = (const float*)d_in[20];
    const float* bn1b   = (const float*)d_in[21];
    const float* bn2g   = (const float*)d_in[22];
    const float* bn2b   = (const float*)d_in[23];

    float* bufA  = (float*)d_ws;                  // NT0*H floats
    float* bufB  = bufA + (size_t)NT0 * H;        // NT1*H floats
    float* score = bufB + (size_t)NT1 * H;        // NT0
    int*   cs    = (int*)(score + NT0);           // NE
    int*   cd    = cs + NE;                       // NE
    float* z     = (float*)(cd + NE);             // G*256
    float* f1    = z + G * 256;                   // G*128
    float* f2    = f1 + G * H;                    // G*64
    int*   rowp  = (int*)(f2 + G * 64);           // G*RPS ints
    unsigned short* col = (unsigned short*)(rowp + G * RPS);   // NE ushorts

    // ---- layer 1 ----
    agg6_conv1_kernel<<<G, 256, 0, stream>>>(x, ei, Wrel1, Wroot1, b1, pw1, bufA, score);
    topk_pool_kernel<<<G, 512, 0, stream>>>(bufA, score, N0, K1, bufB, z, 1,
                                            ei, ei + NE, cs, cd, rowp, col, 1);

    // ---- layer 2 ----
    agg_gather_kernel<<<dim3(G, 8), 512, 0, stream>>>(bufB, rowp, col, (int*)bufA, K1);
    conv_gemm_kernel<<<cdiv(NT1, 64), 256, 0, stream>>>((const int*)bufA, bufB, Wrel2, Wroot2, b2, pw2, bufA, score, NT1);
    topk_pool_kernel<<<G, 512, 0, stream>>>(bufA, score, K1, K2, bufB, z, 0,
                                            cs, cd, cs, cd, rowp, col, 1);

    // ---- layer 3 ----
    agg_gather_kernel<<<dim3(G, 8), 512, 0, stream>>>(bufB, rowp, col, (int*)bufA, K2);
    conv_gemm_kernel<<<cdiv(NT2, 64), 256, 0, stream>>>((const int*)bufA, bufB, Wrel3, Wroot3, b3, pw3, bufA, score, NT2);
    topk_pool_kernel<<<G, 512, 0, stream>>>(bufA, score, K2, K3, bufB, z, 0,
                                            cs, cd, cs, cd, rowp, col, 0);

    // ---- head ----
    fc_bn_kernel<<<128, 256, 0, stream>>>(z, lin1w, lin1b, bn1g, bn1b, f1, 256, 128);
    fc_bn_kernel<<<64, 256, 0, stream>>>(f1, lin2w, lin2b, bn2g, bn2b, f2, 128, 64);
    head_kernel<<<1, 256, 0, stream>>>(f2, lin3w, lin3b, (float*)d_out);
}

// Round 14
// 473.331 us; speedup vs baseline: 1.8541x; 1.0268x over previous
//
#include <hip/hip_runtime.h>
#include <math.h>

#define G 200
#define N0 512
#define NE 614400          // G*N0*6
#define EPG 3072           // edges per graph (slot-stable across layers)
#define K1 410
#define K2 328
#define K3 263
#define H 128
#define NT0 102400         // G*N0
#define NT1 82000          // G*K1
#define NT2 65600          // G*K2
#define NT3 52600          // G*K3

// fixed-point scales for deterministic integer aggregation
#define SCALE1 1048576.0f        // 2^20, layer-1 features (|x| <= ~6)
#define INV1   (1.0f / 1048576.0f)
#define SCALE2 262144.0f         // 2^18, layers 2/3 (messages <= ~300, agg <= ~8000)
#define INV2   (1.0f / 262144.0f)

#define DEAD 0xFFFFu
#define RPS (N0 + 1)             // rowptr stride per graph

static inline int cdiv(int a, int b) { return (a + b - 1) / b; }

// ---------------- layer 1: FUSED agg6 + conv1 + score ----------------
// one block per graph. Edge-staged int-atomic aggregation (deterministic)
// stays in LDS; conv1 reads agg+x from LDS (no global agg round-trip).
// Per-output FMA order identical to the standalone conv1 -> bit-identical h.
__global__ __launch_bounds__(256) void agg6_conv1_kernel(
    const float* __restrict__ x, const int* __restrict__ ei,
    const float* __restrict__ Wrel, const float* __restrict__ Wroot,
    const float* __restrict__ b, const float* __restrict__ pw,
    float* __restrict__ h, float* __restrict__ score) {
    __shared__ float xs[N0 * 8];
    __shared__ int   ag[N0 * 8];
    __shared__ ushort2 eloc[EPG];
    __shared__ float wrelL[768], wrootL[768], bL[128], pwL[128];
    const int g = blockIdx.x;
    const int t = threadIdx.x;
    const int base = g * N0;
    const int e0 = g * EPG;
    for (int i = t; i < N0 * 8; i += 256) {
        int m = i >> 3, j = i & 7;
        xs[i] = (j < 6) ? x[(size_t)(base + m) * 6 + j] : 0.f;
        ag[i] = 0;
    }
    for (int i = t; i < EPG; i += 256) {
        eloc[i] = make_ushort2((unsigned short)(ei[e0 + i] - base),
                               (unsigned short)(ei[NE + e0 + i] - base));
    }
    for (int i = t; i < 768; i += 256) { wrelL[i] = Wrel[i]; wrootL[i] = Wroot[i]; }
    if (t < 128) { bL[t] = b[t]; pwL[t] = pw[t]; }
    __syncthreads();
    const int sub8 = t >> 3;   // 32 subgroups of 8 lanes
    const int f8 = t & 7;
#pragma unroll 4
    for (int e = sub8; e < EPG; e += 32) {
        ushort2 p = eloc[e];
        if (f8 < 6) {
            float v = xs[p.x * 8 + f8];
            atomicAdd(&ag[p.y * 8 + f8], __float2int_rn(v * SCALE1));
        }
    }
    __syncthreads();
    // conv + score: 8 nodes per round, 32 lanes per node (o4 = lane*4)
    const int nsub = t >> 5;
    const int lane = t & 31;
    const int o4 = lane * 4;
    for (int m = nsub; m < N0; m += 8) {
        float a[6], xv[6];
#pragma unroll
        for (int f = 0; f < 6; f++) {
            a[f] = (float)ag[m * 8 + f] * INV1;
            xv[f] = xs[m * 8 + f];
        }
        float4 r; float* rp = (float*)&r;
        float d = 0.f, n2 = 0.f;
#pragma unroll
        for (int j = 0; j < 4; j++) {
            int o = o4 + j;
            float acc = bL[o];
#pragma unroll
            for (int f = 0; f < 6; f++)
                acc += a[f] * wrelL[o * 6 + f] + xv[f] * wrootL[o * 6 + f];
            float hv = fmaxf(acc, 0.f);
            rp[j] = hv;
            float wv = pwL[o];
            d = fmaf(hv, wv, d);
            n2 = fmaf(wv, wv, n2);
        }
        *(float4*)(h + (size_t)(base + m) * H + o4) = r;
#pragma unroll
        for (int s = 1; s < 32; s <<= 1) {
            d += __shfl_xor(d, s);
            n2 += __shfl_xor(n2, s);
        }
        if (lane == 0) score[base + m] = tanhf(d / sqrtf(n2));
    }
}

// ------- FUSED topk + gather/gate + readout + CSR-build/remap -------
// one block (512 threads) per graph. Register bitonic sort (descending,
// index-tiebreak). Local ranks invL come straight from the sorted order, so
// no global inv array exists. Gather/readout accumulate in the same order as
// before -> bit-identical z and pooled h. CSR phase (do_csr): remap edge
// list via invL, deterministic rowptr (atomic counts + scan), scatter col
// (order nondeterministic; consumers sum ints -> invariant).
__global__ __launch_bounds__(512) void topk_pool_kernel(
    const float* __restrict__ h, const float* __restrict__ score,
    int n, int k, float* __restrict__ hout, float* __restrict__ z, int zstore,
    const int* __restrict__ src_s, const int* __restrict__ src_d,
    int* __restrict__ out_s, int* __restrict__ out_d,
    int* __restrict__ rowptr, unsigned short* __restrict__ col, int do_csr) {
    __shared__ float sv[512];
    __shared__ int si[512];
    __shared__ int invL[512];
    __shared__ float smax[4][128];
    __shared__ float ssum[4][128];
    __shared__ ushort2 eloc[EPG];
    __shared__ int cnt[512];
    __shared__ int basep[512];
    __shared__ int wsum[8];
    const int g = blockIdx.x;
    const int t = threadIdx.x;
    float v = (t < n) ? score[g * n + t] : -INFINITY;
    int idx = t;
    for (int size = 2; size <= 512; size <<= 1) {
        const bool desc = ((t & size) == 0);
        for (int stride = size >> 1; stride > 0; stride >>= 1) {
            float pv; int pi;
            if (stride >= 64) {
                sv[t] = v; si[t] = idx;
                __syncthreads();
                pv = sv[t ^ stride]; pi = si[t ^ stride];
                __syncthreads();
            } else {
                pv = __shfl_xor(v, stride);
                pi = __shfl_xor(idx, stride);
            }
            const bool left = ((t & stride) == 0);
            const bool want_max = (desc == left);
            const bool A = (v > pv) || (v == pv && idx < pi);
            if (want_max != A) { v = pv; idx = pi; }
        }
    }
    sv[t] = v; si[t] = idx; invL[t] = -1;
    __syncthreads();
    if (t < k) invL[idx] = t;     // rank of kept node (idx == si[t] here)

    // gather + gate + readout (reads sv/si only)
    const int f = t & 127;
    const int part = t >> 7;
    const float* hbase = h + (size_t)g * n * H + f;
    float* obase = hout + (size_t)g * k * H + f;
    float mx = -INFINITY, sm = 0.f;
    int j = part;
    for (; j + 12 < k; j += 16) {
        int r0 = si[j], r1 = si[j + 4], r2 = si[j + 8], r3 = si[j + 12];
        float s0 = sv[j], s1 = sv[j + 4], s2 = sv[j + 8], s3 = sv[j + 12];
        float a0 = hbase[(size_t)r0 * H];
        float a1 = hbase[(size_t)r1 * H];
        float a2 = hbase[(size_t)r2 * H];
        float a3 = hbase[(size_t)r3 * H];
        float v0 = a0 * s0, v1 = a1 * s1, v2 = a2 * s2, v3 = a3 * s3;
        obase[(size_t)j * H] = v0;
        obase[(size_t)(j + 4) * H] = v1;
        obase[(size_t)(j + 8) * H] = v2;
        obase[(size_t)(j + 12) * H] = v3;
        mx = fmaxf(mx, v0); sm += v0;
        mx = fmaxf(mx, v1); sm += v1;
        mx = fmaxf(mx, v2); sm += v2;
        mx = fmaxf(mx, v3); sm += v3;
    }
    for (; j < k; j += 4) {
        float vv = hbase[(size_t)si[j] * H] * sv[j];
        obase[(size_t)j * H] = vv;
        mx = fmaxf(mx, vv); sm += vv;
    }
    smax[part][f] = mx;
    ssum[part][f] = sm;
    if (t < n) cnt[t] = 0;
    __syncthreads();
    if (t < 128) {
        float m0 = fmaxf(fmaxf(smax[0][t], smax[1][t]), fmaxf(smax[2][t], smax[3][t]));
        float s0 = (ssum[0][t] + ssum[1][t]) + (ssum[2][t] + ssum[3][t]);
        if (zstore) {
            z[g * 256 + t] = m0;
            z[g * 256 + 128 + t] = s0 / (float)k;
        } else {
            z[g * 256 + t] += m0;
            z[g * 256 + 128 + t] += s0 / (float)k;
        }
    }
    if (!do_csr) return;

    // ---- CSR build + inline remap for the next layer ----
    const int basen = g * n;
    const int gk = g * k;
    const int e0 = g * EPG;
    for (int i = t; i < EPG; i += 512) {
        int s = src_s[e0 + i];
        ushort2 p = make_ushort2(DEAD, DEAD);
        if (s >= 0) {
            int ls = invL[s - basen];
            int ld = invL[src_d[e0 + i] - basen];
            if (ls < 0 || ld < 0) {
                out_s[e0 + i] = -1;
            } else {
                out_s[e0 + i] = gk + ls;
                out_d[e0 + i] = gk + ld;
                p = make_ushort2((unsigned short)ls, (unsigned short)ld);
                atomicAdd(&cnt[ld], 1);
            }
        } else {
            out_s[e0 + i] = -1;
        }
        eloc[i] = p;
    }
    __syncthreads();
    // exclusive scan of cnt[0..n): one element per thread, shfl wave scan
    const int a = (t < n) ? cnt[t] : 0;
    const int lane = t & 63, w = t >> 6;
    int xv = a;
#pragma unroll
    for (int o = 1; o < 64; o <<= 1) {
        int y = __shfl_up(xv, o);
        if (lane >= o) xv += y;
    }
    if (lane == 63) wsum[w] = xv;
    __syncthreads();
    int woff = 0;
    for (int ww = 0; ww < w; ww++) woff += wsum[ww];
    const int incl = xv + woff;
    const int excl = incl - a;
    if (t < n) { basep[t] = excl; cnt[t] = 0; rowptr[g * RPS + t] = excl; }
    if (t == 511) rowptr[g * RPS + n] = incl;   // total live edges
    __syncthreads();
    for (int i = t; i < EPG; i += 512) {
        ushort2 pe = eloc[i];
        if (pe.x != DEAD) {
            int pos = basep[pe.y] + atomicAdd(&cnt[pe.y], 1);
            col[e0 + pos] = pe.x;
        }
    }
}

// ---------------- layers 2/3 aggregation: CSR gather, no atomics ----------
// per-(graph, 16-feature-slice), 512 threads (32 subgroups of 16 lanes) for
// latency hiding. h slice staged pre-quantized to int in LDS; each subgroup
// sums its node's neighbors with register int adds, 4-way unrolled.
// Int addition order-invariant -> deterministic.
__global__ __launch_bounds__(512) void agg_gather_kernel(
    const float* __restrict__ h, const int* __restrict__ rowptr,
    const unsigned short* __restrict__ col, int* __restrict__ agg, int n) {
    __shared__ int hsq[K1 * 16];
    __shared__ unsigned short colL[EPG];
    __shared__ int rp[N0 + 1];
    const int g = blockIdx.x;
    const int fq = blockIdx.y * 16;
    const int t = threadIdx.x;
    const int base = g * n;
    const int e0 = g * EPG;
    const int nf4 = n * 4;
    for (int i = t; i < nf4; i += 512) {
        int m = i >> 2, j = (i & 3) * 4;
        float4 v = *(const float4*)(h + (size_t)(base + m) * H + fq + j);
        int4 q;
        q.x = __float2int_rn(v.x * SCALE2);
        q.y = __float2int_rn(v.y * SCALE2);
        q.z = __float2int_rn(v.z * SCALE2);
        q.w = __float2int_rn(v.w * SCALE2);
        *(int4*)(hsq + m * 16 + j) = q;
    }
    {   // stage col as packed uints (coalesced)
        const unsigned int* src = (const unsigned int*)(col + e0);
        unsigned int* dst = (unsigned int*)colL;
        for (int i = t; i < EPG / 2; i += 512) dst[i] = src[i];
    }
    for (int i = t; i <= n; i += 512) rp[i] = rowptr[g * RPS + i];
    __syncthreads();
    const int sub = t >> 4;   // 32 subgroups of 16 lanes
    const int f = t & 15;
    for (int m = sub; m < n; m += 32) {
        int r0 = rp[m], r1 = rp[m + 1];
        int acc = 0;
        int r = r0;
        for (; r + 3 < r1; r += 4) {
            int c0 = colL[r], c1 = colL[r + 1], c2 = colL[r + 2], c3 = colL[r + 3];
            int a0 = hsq[c0 * 16 + f];
            int a1 = hsq[c1 * 16 + f];
            int a2 = hsq[c2 * 16 + f];
            int a3 = hsq[c3 * 16 + f];
            acc += (a0 + a1) + (a2 + a3);
        }
        for (; r < r1; r++) acc += hsq[colL[r] * 16 + f];
        agg[(size_t)(base + m) * H + fq + f] = acc;
    }
}

// out[i][o] = relu( sum_k agg[i][k]*Wrel[o][k] + sum_k hin[i][k]*Wroot[o][k] + b[o] )
// R12-proven config (48 VGPR, no prefetch — R13's register prefetch cost
// occupancy 33->22% and regressed): 64x128 tile, 256 threads, 4x8 micro-tile,
// o4-split B cols (conflict-free), Bs padded 132. FUSED score epilogue via
// shfl_xor (fixed order, deterministic). agg is int32 fixed-point, converted
// inline. out aliases agg (in-place safe). Per-output K order unchanged
// (kc asc, kk asc) -> bit-identical h.
__global__ __launch_bounds__(256) void conv_gemm_kernel(
    const int* __restrict__ agg, const float* __restrict__ hin,
    const float* __restrict__ Wrel, const float* __restrict__ Wroot,
    const float* __restrict__ bias, const float* __restrict__ pw,
    float* __restrict__ out, float* __restrict__ score, int M) {
    __shared__ float As[32][68];
    __shared__ float Bs[32][132];
    const int t = threadIdx.x;
    const int row0 = blockIdx.x * 64;
    const int tx = t & 15;
    const int ty = t >> 4;
    const int o4 = tx * 4;       // cols [o4,o4+4) and [64+o4,64+o4+4)
    const int r4 = ty * 4;

    float acc[4][8];
#pragma unroll
    for (int i = 0; i < 4; i++)
#pragma unroll
        for (int j = 0; j < 8; j++) acc[i][j] = 0.f;

#pragma unroll 1
    for (int kc = 0; kc < 256; kc += 32) {
        const float* Wsrc = (kc < 128) ? (Wrel + kc) : (Wroot + (kc - 128));
#pragma unroll
        for (int i = 0; i < 2; i++) {
            int li = t + i * 256;        // 0..511
            int r = li >> 3, q = li & 7; // r 0..63, q 0..7
            int grow = row0 + r;
            float4 v = make_float4(0.f, 0.f, 0.f, 0.f);
            if (grow < M) {
                if (kc < 128) {
                    int4 iv = *(const int4*)(agg + (size_t)grow * H + kc + q * 4);
                    v.x = (float)iv.x * INV2;
                    v.y = (float)iv.y * INV2;
                    v.z = (float)iv.z * INV2;
                    v.w = (float)iv.w * INV2;
                } else {
                    v = *(const float4*)(hin + (size_t)grow * H + (kc - 128) + q * 4);
                }
            }
            As[q * 4 + 0][r] = v.x;
            As[q * 4 + 1][r] = v.y;
            As[q * 4 + 2][r] = v.z;
            As[q * 4 + 3][r] = v.w;
        }
#pragma unroll
        for (int i = 0; i < 4; i++) {
            int li = t + i * 256;
            int o = li >> 3, q = li & 7;
            float4 v = *(const float4*)(Wsrc + (size_t)o * H + q * 4);
            Bs[q * 4 + 0][o] = v.x;
            Bs[q * 4 + 1][o] = v.y;
            Bs[q * 4 + 2][o] = v.z;
            Bs[q * 4 + 3][o] = v.w;
        }
        __syncthreads();
#pragma unroll
        for (int kk = 0; kk < 32; kk++) {
            const float4 a0 = *(const float4*)&As[kk][r4];
            const float4 b0 = *(const float4*)&Bs[kk][o4];
            const float4 b1 = *(const float4*)&Bs[kk][64 + o4];
            float av[4] = {a0.x, a0.y, a0.z, a0.w};
            float bv[8] = {b0.x, b0.y, b0.z, b0.w, b1.x, b1.y, b1.z, b1.w};
#pragma unroll
            for (int ii = 0; ii < 4; ii++)
#pragma unroll
                for (int jj = 0; jj < 8; jj++)
                    acc[ii][jj] = fmaf(av[ii], bv[jj], acc[ii][jj]);
        }
        __syncthreads();
    }

    // fused-score weights for this thread's 8 columns
    float wv[8];
#pragma unroll
    for (int j = 0; j < 4; j++) { wv[j] = pw[o4 + j]; wv[4 + j] = pw[64 + o4 + j]; }
    float n2 = 0.f;
#pragma unroll
    for (int j = 0; j < 8; j++) n2 = fmaf(wv[j], wv[j], n2);
#pragma unroll
    for (int s = 1; s < 16; s <<= 1) n2 += __shfl_xor(n2, s);
    const float rnorm = 1.0f / sqrtf(n2);

#pragma unroll
    for (int ii = 0; ii < 4; ii++) {
        int grow = row0 + r4 + ii;
        float4 o0, o1;
        o0.x = fmaxf(acc[ii][0] + bias[o4 + 0], 0.f);
        o0.y = fmaxf(acc[ii][1] + bias[o4 + 1], 0.f);
        o0.z = fmaxf(acc[ii][2] + bias[o4 + 2], 0.f);
        o0.w = fmaxf(acc[ii][3] + bias[o4 + 3], 0.f);
        o1.x = fmaxf(acc[ii][4] + bias[64 + o4 + 0], 0.f);
        o1.y = fmaxf(acc[ii][5] + bias[64 + o4 + 1], 0.f);
        o1.z = fmaxf(acc[ii][6] + bias[64 + o4 + 2], 0.f);
        o1.w = fmaxf(acc[ii][7] + bias[64 + o4 + 3], 0.f);
        float d = 0.f;
        d = fmaf(o0.x, wv[0], d); d = fmaf(o0.y, wv[1], d);
        d = fmaf(o0.z, wv[2], d); d = fmaf(o0.w, wv[3], d);
        d = fmaf(o1.x, wv[4], d); d = fmaf(o1.y, wv[5], d);
        d = fmaf(o1.z, wv[6], d); d = fmaf(o1.w, wv[7], d);
#pragma unroll
        for (int s = 1; s < 16; s <<= 1) d += __shfl_xor(d, s);
        if (grow < M) {
            *(float4*)(out + (size_t)grow * H + o4) = o0;
            *(float4*)(out + (size_t)grow * H + 64 + o4) = o1;
            if (tx == 0) score[grow] = tanhf(d * rnorm);
        }
    }
}

// ---------------- head: FUSED fc + batchnorm + relu ----------------
// one block per output column o. Thread t<G computes the fc dot for sample t
// (k ascending, same order as before); BN stats via fixed LDS tree
// (deterministic). out[t*Odim + o] = relu(bn(v)).
__global__ __launch_bounds__(256) void fc_bn_kernel(
    const float* __restrict__ in, const float* __restrict__ W,
    const float* __restrict__ bias, const float* __restrict__ gam,
    const float* __restrict__ bet, float* __restrict__ out, int Kdim, int Odim) {
    __shared__ float wL[256];
    __shared__ float red[256];
    const int o = blockIdx.x;
    const int t = threadIdx.x;
    for (int i = t; i < Kdim; i += 256) wL[i] = W[(size_t)o * Kdim + i];
    __syncthreads();
    float v = 0.f;
    if (t < G) {
        v = bias[o];
        const float* row = in + (size_t)t * Kdim;
        for (int kk = 0; kk < Kdim; kk++) v += row[kk] * wL[kk];
    }
    red[t] = (t < G) ? v : 0.f;
    __syncthreads();
    for (int s = 128; s > 0; s >>= 1) {
        if (t < s) red[t] += red[t + s];
        __syncthreads();
    }
    float m = red[0] / (float)G;
    __syncthreads();
    red[t] = (t < G) ? v * v : 0.f;
    __syncthreads();
    for (int s = 128; s > 0; s >>= 1) {
        if (t < s) red[t] += red[t + s];
        __syncthreads();
    }
    float var = red[0] / (float)G - m * m;
    float invs = 1.0f / sqrtf(var + 1e-5f);
    if (t < G) out[(size_t)t * Odim + o] = fmaxf((v - m) * invs * gam[o] + bet[o], 0.f);
}

__global__ void head_kernel(const float* __restrict__ fc2, const float* __restrict__ W,
                            const float* __restrict__ b, float* __restrict__ out) {
    int g = blockIdx.x * blockDim.x + threadIdx.x;
    if (g >= G) return;
    float l0 = b[0], l1 = b[1];
    for (int k = 0; k < 64; k++) {
        float v = fc2[g * 64 + k];
        l0 += v * W[k];
        l1 += v * W[64 + k];
    }
    float mx = fmaxf(l0, l1);
    float e0 = expf(l0 - mx), e1 = expf(l1 - mx);
    float s = e0 + e1;
    out[g * 2 + 0] = e0 / s;
    out[g * 2 + 1] = e1 / s;
}

extern "C" void kernel_launch(void* const* d_in, const int* in_sizes, int n_in,
                              void* d_out, int out_size, void* d_ws, size_t ws_size,
                              hipStream_t stream) {
    (void)in_sizes; (void)n_in; (void)out_size; (void)ws_size;

    const float* x      = (const float*)d_in[0];
    const int*   ei     = (const int*)d_in[1];
    const float* Wrel1  = (const float*)d_in[2];
    const float* Wroot1 = (const float*)d_in[3];
    const float* b1     = (const float*)d_in[4];
    const float* Wrel2  = (const float*)d_in[5];
    const float* Wroot2 = (const float*)d_in[6];
    const float* b2     = (const float*)d_in[7];
    const float* Wrel3  = (const float*)d_in[8];
    const float* Wroot3 = (const float*)d_in[9];
    const float* b3     = (const float*)d_in[10];
    const float* pw1    = (const float*)d_in[11];
    const float* pw2    = (const float*)d_in[12];
    const float* pw3    = (const float*)d_in[13];
    const float* lin1w  = (const float*)d_in[14];
    const float* lin1b  = (const float*)d_in[15];
    const float* lin2w  = (const float*)d_in[16];
    const float* lin2b  = (const float*)d_in[17];
    const float* lin3w  = (const float*)d_in[18];
    const float* lin3b  = (const float*)d_in[19];
    const float* bn1g   = (const float*)d_in[20];
    const float* bn1b   = (const float*)d_in[21];
    const float* bn2g   = (const float*)d_in[22];
    const float* bn2b   = (const float*)d_in[23];

    float* bufA  = (float*)d_ws;                  // NT0*H floats
    float* bufB  = bufA + (size_t)NT0 * H;        // NT1*H floats
    float* score = bufB + (size_t)NT1 * H;        // NT0
    int*   cs    = (int*)(score + NT0);           // NE
    int*   cd    = cs + NE;                       // NE
    float* z     = (float*)(cd + NE);             // G*256
    float* f1    = z + G * 256;                   // G*128
    float* f2    = f1 + G * H;                    // G*64
    int*   rowp  = (int*)(f2 + G * 64);           // G*RPS ints
    unsigned short* col = (unsigned short*)(rowp + G * RPS);   // NE ushorts

    // ---- layer 1 ----
    agg6_conv1_kernel<<<G, 256, 0, stream>>>(x, ei, Wrel1, Wroot1, b1, pw1, bufA, score);
    topk_pool_kernel<<<G, 512, 0, stream>>>(bufA, score, N0, K1, bufB, z, 1,
                                            ei, ei + NE, cs, cd, rowp, col, 1);

    // ---- layer 2 ----
    agg_gather_kernel<<<dim3(G, 8), 512, 0, stream>>>(bufB, rowp, col, (int*)bufA, K1);
    conv_gemm_kernel<<<cdiv(NT1, 64), 256, 0, stream>>>((const int*)bufA, bufB, Wrel2, Wroot2, b2, pw2, bufA, score, NT1);
    topk_pool_kernel<<<G, 512, 0, stream>>>(bufA, score, K1, K2, bufB, z, 0,
                                            cs, cd, cs, cd, rowp, col, 1);

    // ---- layer 3 ----
    agg_gather_kernel<<<dim3(G, 8), 512, 0, stream>>>(bufB, rowp, col, (int*)bufA, K2);
    conv_gemm_kernel<<<cdiv(NT2, 64), 256, 0, stream>>>((const int*)bufA, bufB, Wrel3, Wroot3, b3, pw3, bufA, score, NT2);
    topk_pool_kernel<<<G, 512, 0, stream>>>(bufA, score, K2, K3, bufB, z, 0,
                                            cs, cd, cs, cd, rowp, col, 0);

    // ---- head ----
    fc_bn_kernel<<<128, 256, 0, stream>>>(z, lin1w, lin1b, bn1g, bn1b, f1, 256, 128);
    fc_bn_kernel<<<64, 256, 0, stream>>>(f1, lin2w, lin2b, bn2g, bn2b, f2, 128, 64);
    head_kernel<<<1, 256, 0, stream>>>(f2, lin3w, lin3b, (float*)d_out);
}

// Round 16
// 446.129 us; speedup vs baseline: 1.9671x; 1.0610x over previous
//
#include <hip/hip_runtime.h>
#include <math.h>

#define G 200
#define N0 512
#define NE 614400          // G*N0*6
#define EPG 3072           // edges per graph (slot-stable across layers)
#define K1 410
#define K2 328
#define K3 263
#define H 128
#define NT0 102400         // G*N0
#define NT1 82000          // G*K1
#define NT2 65600          // G*K2
#define NT3 52600          // G*K3

// fixed-point scales for deterministic integer aggregation
#define SCALE1 1048576.0f        // 2^20, layer-1 features (|x| <= ~6)
#define INV1   (1.0f / 1048576.0f)
#define SCALE2 262144.0f         // 2^18, layers 2/3 (messages <= ~300, agg <= ~8000)
#define INV2   (1.0f / 262144.0f)

#define DEAD 0xFFFFu
#define RPS (N0 + 1)             // rowptr stride per graph

static inline int cdiv(int a, int b) { return (a + b - 1) / b; }

// ---------------- layer 1: FUSED agg6 + conv1 + score ----------------
// one block (512 threads) per graph: both serial phases (edge atomics, conv)
// halve vs 256 threads. Bit-identical to the 256-thread version: int atomics
// are order-invariant and the per-node FMA/lane structure is unchanged.
__global__ __launch_bounds__(512) void agg6_conv1_kernel(
    const float* __restrict__ x, const int* __restrict__ ei,
    const float* __restrict__ Wrel, const float* __restrict__ Wroot,
    const float* __restrict__ b, const float* __restrict__ pw,
    float* __restrict__ h, float* __restrict__ score) {
    __shared__ float xs[N0 * 8];
    __shared__ int   ag[N0 * 8];
    __shared__ ushort2 eloc[EPG];
    __shared__ float wrelL[768], wrootL[768], bL[128], pwL[128];
    const int g = blockIdx.x;
    const int t = threadIdx.x;
    const int base = g * N0;
    const int e0 = g * EPG;
    for (int i = t; i < N0 * 8; i += 512) {
        int m = i >> 3, j = i & 7;
        xs[i] = (j < 6) ? x[(size_t)(base + m) * 6 + j] : 0.f;
        ag[i] = 0;
    }
    for (int i = t; i < EPG; i += 512) {
        eloc[i] = make_ushort2((unsigned short)(ei[e0 + i] - base),
                               (unsigned short)(ei[NE + e0 + i] - base));
    }
    for (int i = t; i < 768; i += 512) { wrelL[i] = Wrel[i]; wrootL[i] = Wroot[i]; }
    if (t < 128) { bL[t] = b[t]; pwL[t] = pw[t]; }
    __syncthreads();
    const int sub8 = t >> 3;   // 64 subgroups of 8 lanes
    const int f8 = t & 7;
#pragma unroll 4
    for (int e = sub8; e < EPG; e += 64) {
        ushort2 p = eloc[e];
        if (f8 < 6) {
            float v = xs[p.x * 8 + f8];
            atomicAdd(&ag[p.y * 8 + f8], __float2int_rn(v * SCALE1));
        }
    }
    __syncthreads();
    // conv + score: 16 nodes per round, 32 lanes per node (o4 = lane*4)
    const int nsub = t >> 5;
    const int lane = t & 31;
    const int o4 = lane * 4;
    for (int m = nsub; m < N0; m += 16) {
        float a[6], xv[6];
#pragma unroll
        for (int f = 0; f < 6; f++) {
            a[f] = (float)ag[m * 8 + f] * INV1;
            xv[f] = xs[m * 8 + f];
        }
        float4 r; float* rp = (float*)&r;
        float d = 0.f, n2 = 0.f;
#pragma unroll
        for (int j = 0; j < 4; j++) {
            int o = o4 + j;
            float acc = bL[o];
#pragma unroll
            for (int f = 0; f < 6; f++)
                acc += a[f] * wrelL[o * 6 + f] + xv[f] * wrootL[o * 6 + f];
            float hv = fmaxf(acc, 0.f);
            rp[j] = hv;
            float wv = pwL[o];
            d = fmaf(hv, wv, d);
            n2 = fmaf(wv, wv, n2);
        }
        *(float4*)(h + (size_t)(base + m) * H + o4) = r;
#pragma unroll
        for (int s = 1; s < 32; s <<= 1) {
            d += __shfl_xor(d, s);
            n2 += __shfl_xor(n2, s);
        }
        if (lane == 0) score[base + m] = tanhf(d / sqrtf(n2));
    }
}

// ------- FUSED topk + gather/gate + readout + CSR-build/remap -------
// one block (512 threads) per graph. Register bitonic sort (descending,
// index-tiebreak). R14-PROVEN gather/readout (scalar mod-4 partition,
// smax[4][128]) — the R15 float4 rewrite caused post-timing divergence and
// is reverted. CSR phase (do_csr): remap edge list via invL, deterministic
// rowptr (atomic counts + scan), scatter col (order nondet; consumers sum
// ints -> invariant).
__global__ __launch_bounds__(512) void topk_pool_kernel(
    const float* __restrict__ h, const float* __restrict__ score,
    int n, int k, float* __restrict__ hout, float* __restrict__ z, int zstore,
    const int* __restrict__ src_s, const int* __restrict__ src_d,
    int* __restrict__ out_s, int* __restrict__ out_d,
    int* __restrict__ rowptr, unsigned short* __restrict__ col, int do_csr) {
    __shared__ float sv[512];
    __shared__ int si[512];
    __shared__ int invL[512];
    __shared__ float smax[4][128];
    __shared__ float ssum[4][128];
    __shared__ ushort2 eloc[EPG];
    __shared__ int cnt[512];
    __shared__ int basep[512];
    __shared__ int wsum[8];
    const int g = blockIdx.x;
    const int t = threadIdx.x;
    float v = (t < n) ? score[g * n + t] : -INFINITY;
    int idx = t;
    for (int size = 2; size <= 512; size <<= 1) {
        const bool desc = ((t & size) == 0);
        for (int stride = size >> 1; stride > 0; stride >>= 1) {
            float pv; int pi;
            if (stride >= 64) {
                sv[t] = v; si[t] = idx;
                __syncthreads();
                pv = sv[t ^ stride]; pi = si[t ^ stride];
                __syncthreads();
            } else {
                pv = __shfl_xor(v, stride);
                pi = __shfl_xor(idx, stride);
            }
            const bool left = ((t & stride) == 0);
            const bool want_max = (desc == left);
            const bool A = (v > pv) || (v == pv && idx < pi);
            if (want_max != A) { v = pv; idx = pi; }
        }
    }
    sv[t] = v; si[t] = idx; invL[t] = -1;
    __syncthreads();
    if (t < k) invL[idx] = t;     // rank of kept node (idx == si[t] here)

    // gather + gate + readout (reads sv/si only) — R14-proven path
    const int f = t & 127;
    const int part = t >> 7;
    const float* hbase = h + (size_t)g * n * H + f;
    float* obase = hout + (size_t)g * k * H + f;
    float mx = -INFINITY, sm = 0.f;
    int j = part;
    for (; j + 12 < k; j += 16) {
        int r0 = si[j], r1 = si[j + 4], r2 = si[j + 8], r3 = si[j + 12];
        float s0 = sv[j], s1 = sv[j + 4], s2 = sv[j + 8], s3 = sv[j + 12];
        float a0 = hbase[(size_t)r0 * H];
        float a1 = hbase[(size_t)r1 * H];
        float a2 = hbase[(size_t)r2 * H];
        float a3 = hbase[(size_t)r3 * H];
        float v0 = a0 * s0, v1 = a1 * s1, v2 = a2 * s2, v3 = a3 * s3;
        obase[(size_t)j * H] = v0;
        obase[(size_t)(j + 4) * H] = v1;
        obase[(size_t)(j + 8) * H] = v2;
        obase[(size_t)(j + 12) * H] = v3;
        mx = fmaxf(mx, v0); sm += v0;
        mx = fmaxf(mx, v1); sm += v1;
        mx = fmaxf(mx, v2); sm += v2;
        mx = fmaxf(mx, v3); sm += v3;
    }
    for (; j < k; j += 4) {
        float vv = hbase[(size_t)si[j] * H] * sv[j];
        obase[(size_t)j * H] = vv;
        mx = fmaxf(mx, vv); sm += vv;
    }
    smax[part][f] = mx;
    ssum[part][f] = sm;
    if (t < n) cnt[t] = 0;
    __syncthreads();
    if (t < 128) {
        float m0 = fmaxf(fmaxf(smax[0][t], smax[1][t]), fmaxf(smax[2][t], smax[3][t]));
        float s0 = (ssum[0][t] + ssum[1][t]) + (ssum[2][t] + ssum[3][t]);
        if (zstore) {
            z[g * 256 + t] = m0;
            z[g * 256 + 128 + t] = s0 / (float)k;
        } else {
            z[g * 256 + t] += m0;
            z[g * 256 + 128 + t] += s0 / (float)k;
        }
    }
    if (!do_csr) return;

    // ---- CSR build + inline remap for the next layer ----
    const int basen = g * n;
    const int gk = g * k;
    const int e0 = g * EPG;
    for (int i = t; i < EPG; i += 512) {
        int s = src_s[e0 + i];
        ushort2 p = make_ushort2(DEAD, DEAD);
        if (s >= 0) {
            int ls = invL[s - basen];
            int ld = invL[src_d[e0 + i] - basen];
            if (ls < 0 || ld < 0) {
                out_s[e0 + i] = -1;
            } else {
                out_s[e0 + i] = gk + ls;
                out_d[e0 + i] = gk + ld;
                p = make_ushort2((unsigned short)ls, (unsigned short)ld);
                atomicAdd(&cnt[ld], 1);
            }
        } else {
            out_s[e0 + i] = -1;
        }
        eloc[i] = p;
    }
    __syncthreads();
    // exclusive scan of cnt[0..n): one element per thread, shfl wave scan
    const int a = (t < n) ? cnt[t] : 0;
    const int lane = t & 63, w = t >> 6;
    int xv = a;
#pragma unroll
    for (int o = 1; o < 64; o <<= 1) {
        int y = __shfl_up(xv, o);
        if (lane >= o) xv += y;
    }
    if (lane == 63) wsum[w] = xv;
    __syncthreads();
    int woff = 0;
    for (int ww = 0; ww < w; ww++) woff += wsum[ww];
    const int incl = xv + woff;
    const int excl = incl - a;
    if (t < n) { basep[t] = excl; cnt[t] = 0; rowptr[g * RPS + t] = excl; }
    if (t == 511) rowptr[g * RPS + n] = incl;   // total live edges
    __syncthreads();
    for (int i = t; i < EPG; i += 512) {
        ushort2 pe = eloc[i];
        if (pe.x != DEAD) {
            int pos = basep[pe.y] + atomicAdd(&cnt[pe.y], 1);
            col[e0 + pos] = pe.x;
        }
    }
}

// ---------------- layers 2/3 aggregation: CSR gather, no atomics ----------
// per-(graph, 16-feature-slice), 512 threads (32 subgroups of 16 lanes) for
// latency hiding. h slice staged pre-quantized to int in LDS; each subgroup
// sums its node's neighbors with register int adds, 4-way unrolled.
// Int addition order-invariant -> deterministic.
__global__ __launch_bounds__(512) void agg_gather_kernel(
    const float* __restrict__ h, const int* __restrict__ rowptr,
    const unsigned short* __restrict__ col, int* __restrict__ agg, int n) {
    __shared__ int hsq[K1 * 16];
    __shared__ unsigned short colL[EPG];
    __shared__ int rp[N0 + 1];
    const int g = blockIdx.x;
    const int fq = blockIdx.y * 16;
    const int t = threadIdx.x;
    const int base = g * n;
    const int e0 = g * EPG;
    const int nf4 = n * 4;
    for (int i = t; i < nf4; i += 512) {
        int m = i >> 2, j = (i & 3) * 4;
        float4 v = *(const float4*)(h + (size_t)(base + m) * H + fq + j);
        int4 q;
        q.x = __float2int_rn(v.x * SCALE2);
        q.y = __float2int_rn(v.y * SCALE2);
        q.z = __float2int_rn(v.z * SCALE2);
        q.w = __float2int_rn(v.w * SCALE2);
        *(int4*)(hsq + m * 16 + j) = q;
    }
    {   // stage col as packed uints (coalesced)
        const unsigned int* src = (const unsigned int*)(col + e0);
        unsigned int* dst = (unsigned int*)colL;
        for (int i = t; i < EPG / 2; i += 512) dst[i] = src[i];
    }
    for (int i = t; i <= n; i += 512) rp[i] = rowptr[g * RPS + i];
    __syncthreads();
    const int sub = t >> 4;   // 32 subgroups of 16 lanes
    const int f = t & 15;
    for (int m = sub; m < n; m += 32) {
        int r0 = rp[m], r1 = rp[m + 1];
        int acc = 0;
        int r = r0;
        for (; r + 3 < r1; r += 4) {
            int c0 = colL[r], c1 = colL[r + 1], c2 = colL[r + 2], c3 = colL[r + 3];
            int a0 = hsq[c0 * 16 + f];
            int a1 = hsq[c1 * 16 + f];
            int a2 = hsq[c2 * 16 + f];
            int a3 = hsq[c3 * 16 + f];
            acc += (a0 + a1) + (a2 + a3);
        }
        for (; r < r1; r++) acc += hsq[colL[r] * 16 + f];
        agg[(size_t)(base + m) * H + fq + f] = acc;
    }
}

// out[i][o] = relu( sum_k agg[i][k]*Wrel[o][k] + sum_k hin[i][k]*Wroot[o][k] + b[o] )
// R12-proven config (48 VGPR, no prefetch): 64x128 tile, 256 threads, 4x8
// micro-tile, o4-split B cols (conflict-free), Bs padded 132. FUSED score
// epilogue via shfl_xor. agg is int32 fixed-point, converted inline. out
// aliases agg (in-place safe). K order (kc asc, kk asc) -> bit-identical h.
__global__ __launch_bounds__(256) void conv_gemm_kernel(
    const int* __restrict__ agg, const float* __restrict__ hin,
    const float* __restrict__ Wrel, const float* __restrict__ Wroot,
    const float* __restrict__ bias, const float* __restrict__ pw,
    float* __restrict__ out, float* __restrict__ score, int M) {
    __shared__ float As[32][68];
    __shared__ float Bs[32][132];
    const int t = threadIdx.x;
    const int row0 = blockIdx.x * 64;
    const int tx = t & 15;
    const int ty = t >> 4;
    const int o4 = tx * 4;       // cols [o4,o4+4) and [64+o4,64+o4+4)
    const int r4 = ty * 4;

    float acc[4][8];
#pragma unroll
    for (int i = 0; i < 4; i++)
#pragma unroll
        for (int j = 0; j < 8; j++) acc[i][j] = 0.f;

#pragma unroll 1
    for (int kc = 0; kc < 256; kc += 32) {
        const float* Wsrc = (kc < 128) ? (Wrel + kc) : (Wroot + (kc - 128));
#pragma unroll
        for (int i = 0; i < 2; i++) {
            int li = t + i * 256;        // 0..511
            int r = li >> 3, q = li & 7; // r 0..63, q 0..7
            int grow = row0 + r;
            float4 v = make_float4(0.f, 0.f, 0.f, 0.f);
            if (grow < M) {
                if (kc < 128) {
                    int4 iv = *(const int4*)(agg + (size_t)grow * H + kc + q * 4);
                    v.x = (float)iv.x * INV2;
                    v.y = (float)iv.y * INV2;
                    v.z = (float)iv.z * INV2;
                    v.w = (float)iv.w * INV2;
                } else {
                    v = *(const float4*)(hin + (size_t)grow * H + (kc - 128) + q * 4);
                }
            }
            As[q * 4 + 0][r] = v.x;
            As[q * 4 + 1][r] = v.y;
            As[q * 4 + 2][r] = v.z;
            As[q * 4 + 3][r] = v.w;
        }
#pragma unroll
        for (int i = 0; i < 4; i++) {
            int li = t + i * 256;
            int o = li >> 3, q = li & 7;
            float4 v = *(const float4*)(Wsrc + (size_t)o * H + q * 4);
            Bs[q * 4 + 0][o] = v.x;
            Bs[q * 4 + 1][o] = v.y;
            Bs[q * 4 + 2][o] = v.z;
            Bs[q * 4 + 3][o] = v.w;
        }
        __syncthreads();
#pragma unroll
        for (int kk = 0; kk < 32; kk++) {
            const float4 a0 = *(const float4*)&As[kk][r4];
            const float4 b0 = *(const float4*)&Bs[kk][o4];
            const float4 b1 = *(const float4*)&Bs[kk][64 + o4];
            float av[4] = {a0.x, a0.y, a0.z, a0.w};
            float bv[8] = {b0.x, b0.y, b0.z, b0.w, b1.x, b1.y, b1.z, b1.w};
#pragma unroll
            for (int ii = 0; ii < 4; ii++)
#pragma unroll
                for (int jj = 0; jj < 8; jj++)
                    acc[ii][jj] = fmaf(av[ii], bv[jj], acc[ii][jj]);
        }
        __syncthreads();
    }

    // fused-score weights for this thread's 8 columns
    float wv[8];
#pragma unroll
    for (int j = 0; j < 4; j++) { wv[j] = pw[o4 + j]; wv[4 + j] = pw[64 + o4 + j]; }
    float n2 = 0.f;
#pragma unroll
    for (int j = 0; j < 8; j++) n2 = fmaf(wv[j], wv[j], n2);
#pragma unroll
    for (int s = 1; s < 16; s <<= 1) n2 += __shfl_xor(n2, s);
    const float rnorm = 1.0f / sqrtf(n2);

#pragma unroll
    for (int ii = 0; ii < 4; ii++) {
        int grow = row0 + r4 + ii;
        float4 o0, o1;
        o0.x = fmaxf(acc[ii][0] + bias[o4 + 0], 0.f);
        o0.y = fmaxf(acc[ii][1] + bias[o4 + 1], 0.f);
        o0.z = fmaxf(acc[ii][2] + bias[o4 + 2], 0.f);
        o0.w = fmaxf(acc[ii][3] + bias[o4 + 3], 0.f);
        o1.x = fmaxf(acc[ii][4] + bias[64 + o4 + 0], 0.f);
        o1.y = fmaxf(acc[ii][5] + bias[64 + o4 + 1], 0.f);
        o1.z = fmaxf(acc[ii][6] + bias[64 + o4 + 2], 0.f);
        o1.w = fmaxf(acc[ii][7] + bias[64 + o4 + 3], 0.f);
        float d = 0.f;
        d = fmaf(o0.x, wv[0], d); d = fmaf(o0.y, wv[1], d);
        d = fmaf(o0.z, wv[2], d); d = fmaf(o0.w, wv[3], d);
        d = fmaf(o1.x, wv[4], d); d = fmaf(o1.y, wv[5], d);
        d = fmaf(o1.z, wv[6], d); d = fmaf(o1.w, wv[7], d);
#pragma unroll
        for (int s = 1; s < 16; s <<= 1) d += __shfl_xor(d, s);
        if (grow < M) {
            *(float4*)(out + (size_t)grow * H + o4) = o0;
            *(float4*)(out + (size_t)grow * H + 64 + o4) = o1;
            if (tx == 0) score[grow] = tanhf(d * rnorm);
        }
    }
}

// ---------------- head: FUSED fc + batchnorm + relu ----------------
// one block per output column o. Thread t<G computes the fc dot for sample t
// (k ascending); BN stats via fixed LDS tree (deterministic).
__global__ __launch_bounds__(256) void fc_bn_kernel(
    const float* __restrict__ in, const float* __restrict__ W,
    const float* __restrict__ bias, const float* __restrict__ gam,
    const float* __restrict__ bet, float* __restrict__ out, int Kdim, int Odim) {
    __shared__ float wL[256];
    __shared__ float red[256];
    const int o = blockIdx.x;
    const int t = threadIdx.x;
    for (int i = t; i < Kdim; i += 256) wL[i] = W[(size_t)o * Kdim + i];
    __syncthreads();
    float v = 0.f;
    if (t < G) {
        v = bias[o];
        const float* row = in + (size_t)t * Kdim;
        for (int kk = 0; kk < Kdim; kk++) v += row[kk] * wL[kk];
    }
    red[t] = (t < G) ? v : 0.f;
    __syncthreads();
    for (int s = 128; s > 0; s >>= 1) {
        if (t < s) red[t] += red[t + s];
        __syncthreads();
    }
    float m = red[0] / (float)G;
    __syncthreads();
    red[t] = (t < G) ? v * v : 0.f;
    __syncthreads();
    for (int s = 128; s > 0; s >>= 1) {
        if (t < s) red[t] += red[t + s];
        __syncthreads();
    }
    float var = red[0] / (float)G - m * m;
    float invs = 1.0f / sqrtf(var + 1e-5f);
    if (t < G) out[(size_t)t * Odim + o] = fmaxf((v - m) * invs * gam[o] + bet[o], 0.f);
}

__global__ void head_kernel(const float* __restrict__ fc2, const float* __restrict__ W,
                            const float* __restrict__ b, float* __restrict__ out) {
    int g = blockIdx.x * blockDim.x + threadIdx.x;
    if (g >= G) return;
    float l0 = b[0], l1 = b[1];
    for (int k = 0; k < 64; k++) {
        float v = fc2[g * 64 + k];
        l0 += v * W[k];
        l1 += v * W[64 + k];
    }
    float mx = fmaxf(l0, l1);
    float e0 = expf(l0 - mx), e1 = expf(l1 - mx);
    float s = e0 + e1;
    out[g * 2 + 0] = e0 / s;
    out[g * 2 + 1] = e1 / s;
}

extern "C" void kernel_launch(void* const* d_in, const int* in_sizes, int n_in,
                              void* d_out, int out_size, void* d_ws, size_t ws_size,
                              hipStream_t stream) {
    (void)in_sizes; (void)n_in; (void)out_size; (void)ws_size;

    const float* x      = (const float*)d_in[0];
    const int*   ei     = (const int*)d_in[1];
    const float* Wrel1  = (const float*)d_in[2];
    const float* Wroot1 = (const float*)d_in[3];
    const float* b1     = (const float*)d_in[4];
    const float* Wrel2  = (const float*)d_in[5];
    const float* Wroot2 = (const float*)d_in[6];
    const float* b2     = (const float*)d_in[7];
    const float* Wrel3  = (const float*)d_in[8];
    const float* Wroot3 = (const float*)d_in[9];
    const float* b3     = (const float*)d_in[10];
    const float* pw1    = (const float*)d_in[11];
    const float* pw2    = (const float*)d_in[12];
    const float* pw3    = (const float*)d_in[13];
    const float* lin1w  = (const float*)d_in[14];
    const float* lin1b  = (const float*)d_in[15];
    const float* lin2w  = (const float*)d_in[16];
    const float* lin2b  = (const float*)d_in[17];
    const float* lin3w  = (const float*)d_in[18];
    const float* lin3b  = (const float*)d_in[19];
    const float* bn1g   = (const float*)d_in[20];
    const float* bn1b   = (const float*)d_in[21];
    const float* bn2g   = (const float*)d_in[22];
    const float* bn2b   = (const float*)d_in[23];

    float* bufA  = (float*)d_ws;                  // NT0*H floats
    float* bufB  = bufA + (size_t)NT0 * H;        // NT1*H floats
    float* score = bufB + (size_t)NT1 * H;        // NT0
    int*   cs    = (int*)(score + NT0);           // NE
    int*   cd    = cs + NE;                       // NE
    float* z     = (float*)(cd + NE);             // G*256
    float* f1    = z + G * 256;                   // G*128
    float* f2    = f1 + G * H;                    // G*64
    int*   rowp  = (int*)(f2 + G * 64);           // G*RPS ints
    unsigned short* col = (unsigned short*)(rowp + G * RPS);   // NE ushorts

    // ---- layer 1 ----
    agg6_conv1_kernel<<<G, 512, 0, stream>>>(x, ei, Wrel1, Wroot1, b1, pw1, bufA, score);
    topk_pool_kernel<<<G, 512, 0, stream>>>(bufA, score, N0, K1, bufB, z, 1,
                                            ei, ei + NE, cs, cd, rowp, col, 1);

    // ---- layer 2 ----
    agg_gather_kernel<<<dim3(G, 8), 512, 0, stream>>>(bufB, rowp, col, (int*)bufA, K1);
    conv_gemm_kernel<<<cdiv(NT1, 64), 256, 0, stream>>>((const int*)bufA, bufB, Wrel2, Wroot2, b2, pw2, bufA, score, NT1);
    topk_pool_kernel<<<G, 512, 0, stream>>>(bufA, score, K1, K2, bufB, z, 0,
                                            cs, cd, cs, cd, rowp, col, 1);

    // ---- layer 3 ----
    agg_gather_kernel<<<dim3(G, 8), 512, 0, stream>>>(bufB, rowp, col, (int*)bufA, K2);
    conv_gemm_kernel<<<cdiv(NT2, 64), 256, 0, stream>>>((const int*)bufA, bufB, Wrel3, Wroot3, b3, pw3, bufA, score, NT2);
    topk_pool_kernel<<<G, 512, 0, stream>>>(bufA, score, K2, K3, bufB, z, 0,
                                            cs, cd, cs, cd, rowp, col, 0);

    // ---- head ----
    fc_bn_kernel<<<128, 256, 0, stream>>>(z, lin1w, lin1b, bn1g, bn1b, f1, 256, 128);
    fc_bn_kernel<<<64, 256, 0, stream>>>(f1, lin2w, lin2b, bn2g, bn2b, f2, 128, 64);
    head_kernel<<<1, 256, 0, stream>>>(f2, lin3w, lin3b, (float*)d_out);
}